// Round 1
// baseline (3314.966 us; speedup 1.0000x reference)
//
#include <hip/hip_runtime.h>
#include <cmath>

#define B_  2
#define L_  2048
#define D_  1024
#define H_  4
#define DK_ 256
#define NCH 64   // chunks of 32
#define CH_ 32

// ---------------------------------------------------------------- GEMM (f32)
// C[m][n] = sum_k A[m][k] * Bt[n][k]   (A: MxK row-major, Bt: NxK row-major)
// EPI: 0 = none, 1 = gelu(x + bias[n]) exact
#define GBM 128
#define GBN 64
#define GBK 16

template<int EPI>
__global__ __launch_bounds__(256)
void gemm_nt(const float* __restrict__ A, const float* __restrict__ Bt,
             const float* __restrict__ bias, float* __restrict__ C,
             int M, int N, int K) {
  __shared__ float As[GBK][GBM + 4];   // [k][m], stride 132 (16B-aligned rows)
  __shared__ float Bs[GBK][GBN + 4];   // [k][n], stride 68
  const int t  = threadIdx.x;
  const int tx = t & 15;               // n-dir
  const int ty = t >> 4;               // m-dir
  const int m0 = blockIdx.y * GBM;
  const int n0 = blockIdx.x * GBN;
  const int lk = t & 15;               // loader: k index
  const int lr = t >> 4;               // loader: row base

  float acc[8][4];
#pragma unroll
  for (int i = 0; i < 8; ++i)
#pragma unroll
    for (int j = 0; j < 4; ++j) acc[i][j] = 0.f;

  for (int k0 = 0; k0 < K; k0 += GBK) {
    __syncthreads();
#pragma unroll
    for (int i = 0; i < 8; ++i) {
      int row = lr + 16 * i;
      As[lk][row] = A[(size_t)(m0 + row) * K + k0 + lk];
    }
#pragma unroll
    for (int i = 0; i < 4; ++i) {
      int row = lr + 16 * i;
      Bs[lk][row] = Bt[(size_t)(n0 + row) * K + k0 + lk];
    }
    __syncthreads();
#pragma unroll
    for (int k = 0; k < GBK; ++k) {
      const float4 a0 = *reinterpret_cast<const float4*>(&As[k][ty * 8]);
      const float4 a1 = *reinterpret_cast<const float4*>(&As[k][ty * 8 + 4]);
      const float4 b0 = *reinterpret_cast<const float4*>(&Bs[k][tx * 4]);
      const float av[8] = {a0.x, a0.y, a0.z, a0.w, a1.x, a1.y, a1.z, a1.w};
      const float bv[4] = {b0.x, b0.y, b0.z, b0.w};
#pragma unroll
      for (int i = 0; i < 8; ++i)
#pragma unroll
        for (int j = 0; j < 4; ++j)
          acc[i][j] = fmaf(av[i], bv[j], acc[i][j]);
    }
  }
#pragma unroll
  for (int i = 0; i < 8; ++i) {
    int m = m0 + ty * 8 + i;
#pragma unroll
    for (int j = 0; j < 4; ++j) {
      int nn = n0 + tx * 4 + j;
      float x = acc[i][j];
      if (EPI == 1) {
        x += bias[nn];
        x = 0.5f * x * (1.f + erff(x * 0.70710678118654752f));
      }
      C[(size_t)m * N + nn] = x;
    }
  }
}

// -------------------------------------------- K2: conv(K=4)+SiLU, l2norm, beta
__global__ __launch_bounds__(256)
void k2_conv(const float* __restrict__ hs,
             const float* __restrict__ qlin, const float* __restrict__ klin,
             const float* __restrict__ vlin,
             const float* __restrict__ qw, const float* __restrict__ kw,
             const float* __restrict__ vw, const float* __restrict__ Wb,
             float* __restrict__ qn, float* __restrict__ kn,
             float* __restrict__ vpath, float* __restrict__ beta) {
  const int bid  = blockIdx.x;           // b*L + l
  const int b    = bid >> 11;
  const int l    = bid & 2047;
  const int t    = threadIdx.x;
  const int wv   = t >> 6;               // head
  const int lane = t & 63;
  const size_t row = (size_t)bid;

  __shared__ float s_red[4][4];

  // beta partial dots (full 1024-dim dot per head, block-wide)
  float pb[4] = {0.f, 0.f, 0.f, 0.f};
#pragma unroll
  for (int i = 0; i < 4; ++i) {
    int c = wv * 256 + lane + i * 64;
    float x = hs[row * 1024 + c];
    pb[0] += x * Wb[0 * 1024 + c];
    pb[1] += x * Wb[1 * 1024 + c];
    pb[2] += x * Wb[2 * 1024 + c];
    pb[3] += x * Wb[3 * 1024 + c];
  }
#pragma unroll
  for (int off = 32; off; off >>= 1) {
    pb[0] += __shfl_xor(pb[0], off);
    pb[1] += __shfl_xor(pb[1], off);
    pb[2] += __shfl_xor(pb[2], off);
    pb[3] += __shfl_xor(pb[3], off);
  }
  if (lane == 0) {
    s_red[0][wv] = pb[0]; s_red[1][wv] = pb[1];
    s_red[2][wv] = pb[2]; s_red[3][wv] = pb[3];
  }
  __syncthreads();

  // causal depthwise conv (taps 4) + SiLU
  float xq[4], xk[4], xv[4];
#pragma unroll
  for (int i = 0; i < 4; ++i) {
    int c = wv * 256 + lane + i * 64;
    float aq = 0.f, ak = 0.f, av = 0.f;
#pragma unroll
    for (int j = 0; j < 4; ++j) {
      int ls = l - 3 + j;
      if (ls >= 0) {
        size_t ro = (size_t)(b * 2048 + ls) * 1024 + c;
        aq = fmaf(qlin[ro], qw[c * 4 + j], aq);
        ak = fmaf(klin[ro], kw[c * 4 + j], ak);
        av = fmaf(vlin[ro], vw[c * 4 + j], av);
      }
    }
    xq[i] = aq / (1.f + expf(-aq));
    xk[i] = ak / (1.f + expf(-ak));
    xv[i] = av / (1.f + expf(-av));
  }

  // per-head l2 norms (wave == head)
  float sq = 0.f, sk = 0.f;
#pragma unroll
  for (int i = 0; i < 4; ++i) { sq += xq[i] * xq[i]; sk += xk[i] * xk[i]; }
#pragma unroll
  for (int off = 32; off; off >>= 1) {
    sq += __shfl_xor(sq, off);
    sk += __shfl_xor(sk, off);
  }
  float rq = rsqrtf(sq + 1e-6f);
  float rk = rsqrtf(sk + 1e-6f);
  float bsum = s_red[wv][0] + s_red[wv][1] + s_red[wv][2] + s_red[wv][3];
  float betaw = 1.f / (1.f + expf(-bsum));
  if (lane == 0) beta[(size_t)bid * 4 + wv] = betaw;

  const int chk = l >> 5, pos = l & 31;
  size_t cbase = ((size_t)((b * 4 + wv) * 64 + chk) * 32 + pos) * 256;
#pragma unroll
  for (int i = 0; i < 4; ++i) {
    int d = lane + i * 64;
    qn[cbase + d] = xq[i] * rq;
    kn[cbase + d] = xk[i] * rk;
    vpath[row * 1024 + wv * 256 + d] = xv[i];
  }
}

// -------------------- K3: per-chunk A, (I+A)^-1 transform, u=T@vb, w=T@kb, attn
__global__ __launch_bounds__(256)
void k3_chunk(const float* __restrict__ qn, const float* __restrict__ kn,
              const float* __restrict__ vpath, const float* __restrict__ beta,
              float* __restrict__ u, float* __restrict__ w,
              float* __restrict__ attn) {
  __shared__ float s_kn[32][257];
  __shared__ float s_kb[32][257];
  __shared__ float s_x[32][257];
  __shared__ float s_A[32][33];
  __shared__ float s_beta[32];
  const int bid = blockIdx.x;            // (b*H+h)*64 + ch
  const int bh = bid >> 6, chk = bid & 63;
  const int b = bh >> 2, h = bh & 3;
  const int t = threadIdx.x;
  const size_t base = (size_t)bid * 8192;

  if (t < 32)
    s_beta[t] = beta[((size_t)(b * 2048 + chk * 32 + t)) * 4 + h];
  for (int i = 0; i < 32; ++i) {
    int idx = t + i * 256;
    int r = idx >> 8, d = idx & 255;
    s_kn[r][d] = kn[base + idx];
    s_x[r][d]  = qn[base + idx];
  }
  __syncthreads();
  for (int i = 0; i < 32; ++i) {
    int idx = t + i * 256;
    int r = idx >> 8, d = idx & 255;
    s_kb[r][d] = s_kn[r][d] * s_beta[r];
  }
  __syncthreads();

  // A = -(kb @ kn^T) strictly-lower;  attn = tril(qn @ kn^T) incl diag
  {
    const int r = t & 31, cg = t >> 5;
    float accA[4] = {0.f, 0.f, 0.f, 0.f};
    float accT[4] = {0.f, 0.f, 0.f, 0.f};
    for (int d = 0; d < 256; ++d) {
      float kbr = s_kb[r][d];
      float qr  = s_x[r][d];
#pragma unroll
      for (int q = 0; q < 4; ++q) {
        float knc = s_kn[cg * 4 + q][d];
        accA[q] = fmaf(kbr, knc, accA[q]);
        accT[q] = fmaf(qr,  knc, accT[q]);
      }
    }
#pragma unroll
    for (int q = 0; q < 4; ++q) {
      int c = cg * 4 + q;
      s_A[r][c] = (r > c) ? -accA[q] : 0.f;
      attn[(size_t)bid * 1024 + r * 32 + c] = (r >= c) ? accT[q] : 0.f;
    }
  }
  __syncthreads();

  // iterative inversion: row i gets A[i,:i] += A[i,:] @ A[:,:i]
  for (int i = 1; i < 32; ++i) {
    float s = 0.f;
    if (t < i) {
      for (int j = 0; j < 32; ++j) s = fmaf(s_A[i][j], s_A[j][t], s);
    }
    __syncthreads();
    if (t < i) s_A[i][t] += s;
    __syncthreads();
  }

  // load vb = v * beta into s_x
  for (int i = 0; i < 32; ++i) {
    int idx = t + i * 256;
    int r = idx >> 8, d = idx & 255;
    s_x[r][d] = vpath[((size_t)(b * 2048 + chk * 32 + r)) * 1024 + h * 256 + d]
                * s_beta[r];
  }
  __syncthreads();

  // u = T @ vb ; w = T @ kb   (T = A + I, lower-triangular)
  {
    const int lane = t & 63, wvv = t >> 6;
    for (int rr = 0; rr < 8; ++rr) {
      int r = wvv * 8 + rr;
      float au[4] = {0.f, 0.f, 0.f, 0.f};
      float aw[4] = {0.f, 0.f, 0.f, 0.f};
      for (int j = 0; j <= r; ++j) {
        float tc = (j == r) ? 1.f : s_A[r][j];
#pragma unroll
        for (int dd = 0; dd < 4; ++dd) {
          au[dd] = fmaf(tc, s_x[j][lane + dd * 64], au[dd]);
          aw[dd] = fmaf(tc, s_kb[j][lane + dd * 64], aw[dd]);
        }
      }
#pragma unroll
      for (int dd = 0; dd < 4; ++dd) {
        int d = lane + dd * 64;
        u[base + r * 256 + d] = au[dd];
        w[base + r * 256 + d] = aw[dd];
      }
    }
  }
}

// ------------------------------- K4: serial chunk scan (8 heads x 16 col-blocks)
__global__ __launch_bounds__(256)
void k4_scan(const float* __restrict__ qn, const float* __restrict__ kn,
             const float* __restrict__ u, const float* __restrict__ w,
             const float* __restrict__ attn, float* __restrict__ delta) {
  __shared__ float s_w[32][257];
  __shared__ float s_k[32][257];
  __shared__ float s_q[32][257];
  __shared__ float s_S[16][257];   // S^T : [dv_local][dk]
  __shared__ float s_tmp[32][17];
  __shared__ float s_u[32][17];
  __shared__ float s_at[32][33];
  const int bid = blockIdx.x;
  const int bh = bid >> 4, cb = bid & 15;
  const int b = bh >> 2, h = bh & 3;
  const int c0 = cb * 16;
  const int t = threadIdx.x;

  for (int i = t; i < 16 * 257; i += 256) ((float*)s_S)[i] = 0.f;
  __syncthreads();

  for (int chk = 0; chk < 64; ++chk) {
    const size_t base = ((size_t)bh * 64 + chk) * 8192;
    for (int i = 0; i < 32; ++i) {
      int idx = t + i * 256;
      int r = idx >> 8, d = idx & 255;
      s_w[r][d] = w[base + idx];
      s_k[r][d] = kn[base + idx];
      s_q[r][d] = qn[base + idx];
    }
    {
      int idx = t * 2;
      int r = idx >> 4, c = idx & 15;
      s_u[r][c]     = u[base + r * 256 + c0 + c];
      s_u[r][c + 1] = u[base + r * 256 + c0 + c + 1];
    }
    for (int i = t; i < 1024; i += 256)
      s_at[i >> 5][i & 31] = attn[((size_t)bh * 64 + chk) * 1024 + i];
    __syncthreads();

    // tmp = u - w@S  (pre-update S);  o_qs = q@S
    const int r = t & 31, cp = t >> 5;
    float t0 = s_u[r][cp * 2], t1 = s_u[r][cp * 2 + 1];
    float o0 = 0.f, o1 = 0.f;
    for (int d = 0; d < 256; ++d) {
      float wv = s_w[r][d], qv = s_q[r][d];
      float sA = s_S[cp * 2][d], sB = s_S[cp * 2 + 1][d];
      t0 = fmaf(-wv, sA, t0);
      t1 = fmaf(-wv, sB, t1);
      o0 = fmaf(qv, sA, o0);
      o1 = fmaf(qv, sB, o1);
    }
    s_tmp[r][cp * 2] = t0;
    s_tmp[r][cp * 2 + 1] = t1;
    __syncthreads();

    // o += attn @ tmp ; write delta
    for (int j = 0; j < 32; ++j) {
      float a = s_at[r][j];
      o0 = fmaf(a, s_tmp[j][cp * 2], o0);
      o1 = fmaf(a, s_tmp[j][cp * 2 + 1], o1);
    }
    {
      int l = chk * 32 + r;
      size_t orow = ((size_t)(b * 2048 + l)) * 1024 + h * 256 + c0 + cp * 2;
      delta[orow] = o0;
      delta[orow + 1] = o1;
    }

    // S += k^T @ tmp
    {
      const int d = t;  // 0..255
      float accS[16];
#pragma unroll
      for (int c = 0; c < 16; ++c) accS[c] = 0.f;
      for (int rr = 0; rr < 32; ++rr) {
        float kv = s_k[rr][d];
#pragma unroll
        for (int c = 0; c < 16; ++c)
          accS[c] = fmaf(kv, s_tmp[rr][c], accS[c]);
      }
#pragma unroll
      for (int c = 0; c < 16; ++c) s_S[c][d] += accS[c];
    }
    __syncthreads();
  }
}

// ------------------------------------------------- K5: FIR short(3)/long(63)
__global__ __launch_bounds__(256)
void k5_fir(const float* __restrict__ vpath, const float* __restrict__ wsrt,
            const float* __restrict__ wlng, float* __restrict__ shortp,
            float* __restrict__ longp) {
  __shared__ float s_v[126][128];
  __shared__ float s_wl[63][128];
  __shared__ float s_ws[3][128];
  const int c0 = blockIdx.x * 128;
  const int l0 = blockIdx.y * 64;
  const int b  = blockIdx.z;
  const int t  = threadIdx.x;

  for (int i = 0; i < 63; ++i) {
    int idx = t + i * 256;   // 16128 elements
    int rr = idx >> 7, cc = idx & 127;
    int gl = l0 - 62 + rr;
    s_v[rr][cc] = (gl >= 0)
        ? vpath[((size_t)(b * 2048 + gl)) * 1024 + c0 + cc] : 0.f;
  }
  for (int i = t; i < 63 * 128; i += 256) {
    int cc = i / 63, j = i % 63;
    s_wl[j][cc] = wlng[(size_t)(c0 + cc) * 63 + j];
  }
  for (int i = t; i < 3 * 128; i += 256) {
    int cc = i / 3, j = i % 3;
    s_ws[j][cc] = wsrt[(size_t)(c0 + cc) * 3 + j];
  }
  __syncthreads();

  const int cc = t & 127, lh = t >> 7;
  for (int m = 0; m < 32; ++m) {
    int ll = lh * 32 + m;
    float accL = 0.f;
    for (int j = 0; j < 63; ++j)
      accL = fmaf(s_v[ll + j][cc], s_wl[j][cc], accL);
    float accS = 0.f;
#pragma unroll
    for (int j = 0; j < 3; ++j)
      accS = fmaf(s_v[ll + 60 + j][cc], s_ws[j][cc], accS);
    size_t o = ((size_t)(b * 2048 + l0 + ll)) * 1024 + c0 + cc;
    longp[o] = accL;
    shortp[o] = accS;
  }
}

// --------------------------------------------- K6: path stats + gate_in build
__global__ __launch_bounds__(256)
void k6_gatein(const float* __restrict__ hs, const float* __restrict__ shortp,
               const float* __restrict__ longp, const float* __restrict__ delta,
               const float* __restrict__ vpath, float* __restrict__ gate_in) {
  const size_t row = blockIdx.x;
  const int t = threadIdx.x, wv = t >> 6, lane = t & 63;
#pragma unroll
  for (int i = 0; i < 4; ++i) {
    int c = t + i * 256;
    gate_in[row * 1056 + c] = hs[row * 1024 + c];
  }
  const float* paths[4] = {shortp, longp, delta, vpath};
#pragma unroll
  for (int p = 0; p < 4; ++p) {
    float s = 0.f, sq = 0.f;
#pragma unroll
    for (int i = 0; i < 4; ++i) {
      int c = wv * 256 + lane + i * 64;
      float x = paths[p][row * 1024 + c];
      s += x; sq += x * x;
    }
#pragma unroll
    for (int off = 32; off; off >>= 1) {
      s += __shfl_xor(s, off);
      sq += __shfl_xor(sq, off);
    }
    if (lane == 0) {
      float mean = s * (1.f / 256.f);
      float var = sq * (1.f / 256.f) - mean * mean;
      gate_in[row * 1056 + 1024 + p * 8 + wv * 2 + 0] = mean;
      gate_in[row * 1056 + 1024 + p * 8 + wv * 2 + 1] = var;
    }
  }
}

// ------------------------------- K8: logits GEMV + softmax + floor + renorm
__global__ __launch_bounds__(256)
void k8_probs(const float* __restrict__ hmid, const float* __restrict__ w2,
              const float* __restrict__ bias, const float* __restrict__ log_temp,
              const float* __restrict__ floor_raw, float* __restrict__ probs) {
  const int t = threadIdx.x, wv = t >> 6, lane = t & 63;
  const size_t row = (size_t)blockIdx.x * 4 + wv;
  float acc[16];
#pragma unroll
  for (int o = 0; o < 16; ++o) acc[o] = 0.f;
  for (int it = 0; it < 32; ++it) {
    int c = lane + it * 64;
    float x = hmid[row * 2048 + c];
#pragma unroll
    for (int o = 0; o < 16; ++o)
      acc[o] = fmaf(x, w2[o * 2048 + c], acc[o]);
  }
#pragma unroll
  for (int off = 32; off; off >>= 1)
#pragma unroll
    for (int o = 0; o < 16; ++o) acc[o] += __shfl_xor(acc[o], off);

  if (lane == 0) {
    for (int h2 = 0; h2 < 4; ++h2) {
      float temp = log1pf(expf(log_temp[h2])) + 1e-4f;
      float li[4], m = -1e30f;
#pragma unroll
      for (int p = 0; p < 4; ++p) {
        li[p] = (acc[h2 * 4 + p] + bias[h2 * 4 + p]) / temp;
        m = fmaxf(m, li[p]);
      }
      float sum = 0.f;
#pragma unroll
      for (int p = 0; p < 4; ++p) { li[p] = expf(li[p] - m); sum += li[p]; }
      float pr[4], s2 = 0.f;
#pragma unroll
      for (int p = 0; p < 4; ++p) {
        float fv = 0.05f / (1.f + expf(-floor_raw[h2 * 4 + p]));
        pr[p] = fmaxf(li[p] / sum, fv);
        s2 += pr[p];
      }
#pragma unroll
      for (int p = 0; p < 4; ++p)
        probs[row * 16 + h2 * 4 + p] = pr[p] / s2;
    }
  }
}

// ------------------------------------------------ K9: mix paths + RMS-norm
__global__ __launch_bounds__(256)
void k9_mix(const float* __restrict__ shortp, const float* __restrict__ longp,
            const float* __restrict__ delta, const float* __restrict__ vpath,
            const float* __restrict__ probs, const float* __restrict__ onorm,
            float* __restrict__ mixed) {
  const size_t row = blockIdx.x;
  const int t = threadIdx.x, wv = t >> 6, lane = t & 63;
  float p0 = probs[row * 16 + wv * 4 + 0];
  float p1 = probs[row * 16 + wv * 4 + 1];
  float p2 = probs[row * 16 + wv * 4 + 2];
  float p3 = probs[row * 16 + wv * 4 + 3];
  float m[4];
  float sq = 0.f;
#pragma unroll
  for (int i = 0; i < 4; ++i) {
    int c = wv * 256 + lane + i * 64;
    size_t o = row * 1024 + c;
    float x = p0 * shortp[o] + p1 * longp[o] + p2 * delta[o] + p3 * vpath[o];
    m[i] = x;
    sq += x * x;
  }
#pragma unroll
  for (int off = 32; off; off >>= 1) sq += __shfl_xor(sq, off);
  float sc = rsqrtf(sq * (1.f / 256.f) + 1e-5f);
#pragma unroll
  for (int i = 0; i < 4; ++i) {
    int d = lane + i * 64;
    mixed[row * 1024 + wv * 256 + d] = m[i] * sc * onorm[d];
  }
}

// ---------------------------------------------------------------- launcher
extern "C" void kernel_launch(void* const* d_in, const int* in_sizes, int n_in,
                              void* d_out, int out_size, void* d_ws,
                              size_t ws_size, hipStream_t stream) {
  const float* hs   = (const float*)d_in[0];
  const float* Wq   = (const float*)d_in[1];
  const float* Wk   = (const float*)d_in[2];
  const float* Wv   = (const float*)d_in[3];
  const float* Wb   = (const float*)d_in[4];
  const float* qw   = (const float*)d_in[5];
  const float* kw   = (const float*)d_in[6];
  const float* vw   = (const float*)d_in[7];
  const float* fsw  = (const float*)d_in[8];
  const float* flw  = (const float*)d_in[9];
  const float* gw1  = (const float*)d_in[10];
  const float* gb1  = (const float*)d_in[11];
  const float* gw2  = (const float*)d_in[12];
  const float* ltmp = (const float*)d_in[13];
  const float* bbias= (const float*)d_in[14];
  const float* frw  = (const float*)d_in[15];
  const float* onw  = (const float*)d_in[16];
  const float* Wo   = (const float*)d_in[17];
  float* out = (float*)d_out;

  float* f = (float*)d_ws;
  const size_t BLD = 4194304;  // B*L*D
  float* qlin    = f + 0 * BLD;
  float* klin    = f + 1 * BLD;
  float* vlin    = f + 2 * BLD;
  float* qn      = f + 3 * BLD;
  float* kn      = f + 4 * BLD;
  float* vpath   = f + 5 * BLD;
  float* shortp  = f + 6 * BLD;
  float* longp   = f + 7 * BLD;
  float* gate_in = f + 8 * BLD;                 // 4,325,376 floats
  float* attnb   = gate_in + 4325376;           //   524,288
  float* probs   = attnb + 524288;              //    65,536
  float* beta    = probs + 65536;               //    16,384
  // reuses (lifetimes disjoint):
  float* u     = qlin;
  float* w_    = klin;
  float* delta = vlin;
  float* hmid  = qn;     // spans qn..kn (2*BLD floats), free after k4
  float* mixed = qlin;   // free after k4

  // 1) q/k/v linear projections
  gemm_nt<0><<<dim3(16, 32), 256, 0, stream>>>(hs, Wq, nullptr, qlin, 4096, 1024, 1024);
  gemm_nt<0><<<dim3(16, 32), 256, 0, stream>>>(hs, Wk, nullptr, klin, 4096, 1024, 1024);
  gemm_nt<0><<<dim3(16, 32), 256, 0, stream>>>(hs, Wv, nullptr, vlin, 4096, 1024, 1024);
  // 2) conv+silu+l2norm+beta
  k2_conv<<<4096, 256, 0, stream>>>(hs, qlin, klin, vlin, qw, kw, vw, Wb,
                                    qn, kn, vpath, beta);
  // 3) per-chunk transforms
  k3_chunk<<<512, 256, 0, stream>>>(qn, kn, vpath, beta, u, w_, attnb);
  // 4) serial scan
  k4_scan<<<128, 256, 0, stream>>>(qn, kn, u, w_, attnb, delta);
  // 5) FIR paths
  k5_fir<<<dim3(8, 32, 2), 256, 0, stream>>>(vpath, fsw, flw, shortp, longp);
  // 6) gate input
  k6_gatein<<<4096, 256, 0, stream>>>(hs, shortp, longp, delta, vpath, gate_in);
  // 7) gate MLP layer 1 (gelu)
  gemm_nt<1><<<dim3(32, 32), 256, 0, stream>>>(gate_in, gw1, gb1, hmid, 4096, 2048, 1056);
  // 8) logits -> probs
  k8_probs<<<1024, 256, 0, stream>>>(hmid, gw2, bbias, ltmp, frw, probs);
  // 9) mix + RMS norm
  k9_mix<<<4096, 256, 0, stream>>>(shortp, longp, delta, vpath, probs, onw, mixed);
  // 10) output projection
  gemm_nt<0><<<dim3(16, 32), 256, 0, stream>>>(mixed, Wo, nullptr, out, 4096, 1024, 1024);
}

// Round 2
// 1359.098 us; speedup vs baseline: 2.4391x; 2.4391x over previous
//
#include <hip/hip_runtime.h>
#include <cmath>

#define B_  2
#define L_  2048
#define D_  1024
#define H_  4
#define DK_ 256
#define NCH 64   // chunks of 32
#define CH_ 32

typedef __bf16 bf16;
typedef __bf16 bf16x8 __attribute__((ext_vector_type(8)));
typedef float  f32x4  __attribute__((ext_vector_type(4)));

#define MFMA16(a, b, c) __builtin_amdgcn_mfma_f32_16x16x32_bf16(a, b, c, 0, 0, 0)

static __device__ __forceinline__ unsigned pack2(float a, float b) {
  unsigned short ua = __builtin_bit_cast(unsigned short, (__bf16)a);
  unsigned short ub = __builtin_bit_cast(unsigned short, (__bf16)b);
  return (unsigned)ua | ((unsigned)ub << 16);
}

static __device__ __forceinline__ void lds_barrier() {
  asm volatile("s_waitcnt lgkmcnt(0)" ::: "memory");
  __builtin_amdgcn_sched_barrier(0);
  __builtin_amdgcn_s_barrier();
  __builtin_amdgcn_sched_barrier(0);
}

// ---------------------------------------------------------------- GEMM (f32)
// C[m][n] = sum_k A[m][k] * Bt[n][k]   (A: MxK row-major, Bt: NxK row-major)
// EPI: 0 = none, 1 = gelu(x + bias[n]) exact
#define GBM 128
#define GBN 64
#define GBK 16

template<int EPI>
__global__ __launch_bounds__(256)
void gemm_nt(const float* __restrict__ A, const float* __restrict__ Bt,
             const float* __restrict__ bias, float* __restrict__ C,
             int M, int N, int K) {
  __shared__ float As[GBK][GBM + 4];
  __shared__ float Bs[GBK][GBN + 4];
  const int t  = threadIdx.x;
  const int tx = t & 15;
  const int ty = t >> 4;
  const int m0 = blockIdx.y * GBM;
  const int n0 = blockIdx.x * GBN;
  const int lk = t & 15;
  const int lr = t >> 4;

  float acc[8][4];
#pragma unroll
  for (int i = 0; i < 8; ++i)
#pragma unroll
    for (int j = 0; j < 4; ++j) acc[i][j] = 0.f;

  for (int k0 = 0; k0 < K; k0 += GBK) {
    __syncthreads();
#pragma unroll
    for (int i = 0; i < 8; ++i) {
      int row = lr + 16 * i;
      As[lk][row] = A[(size_t)(m0 + row) * K + k0 + lk];
    }
#pragma unroll
    for (int i = 0; i < 4; ++i) {
      int row = lr + 16 * i;
      Bs[lk][row] = Bt[(size_t)(n0 + row) * K + k0 + lk];
    }
    __syncthreads();
#pragma unroll
    for (int k = 0; k < GBK; ++k) {
      const float4 a0 = *reinterpret_cast<const float4*>(&As[k][ty * 8]);
      const float4 a1 = *reinterpret_cast<const float4*>(&As[k][ty * 8 + 4]);
      const float4 b0 = *reinterpret_cast<const float4*>(&Bs[k][tx * 4]);
      const float av[8] = {a0.x, a0.y, a0.z, a0.w, a1.x, a1.y, a1.z, a1.w};
      const float bv[4] = {b0.x, b0.y, b0.z, b0.w};
#pragma unroll
      for (int i = 0; i < 8; ++i)
#pragma unroll
        for (int j = 0; j < 4; ++j)
          acc[i][j] = fmaf(av[i], bv[j], acc[i][j]);
    }
  }
#pragma unroll
  for (int i = 0; i < 8; ++i) {
    int m = m0 + ty * 8 + i;
#pragma unroll
    for (int j = 0; j < 4; ++j) {
      int nn = n0 + tx * 4 + j;
      float x = acc[i][j];
      if (EPI == 1) {
        x += bias[nn];
        x = 0.5f * x * (1.f + erff(x * 0.70710678118654752f));
      }
      C[(size_t)m * N + nn] = x;
    }
  }
}

// -------------------------------------------- K2: conv(K=4)+SiLU, l2norm, beta
__global__ __launch_bounds__(256)
void k2_conv(const float* __restrict__ hs,
             const float* __restrict__ qlin, const float* __restrict__ klin,
             const float* __restrict__ vlin,
             const float* __restrict__ qw, const float* __restrict__ kw,
             const float* __restrict__ vw, const float* __restrict__ Wb,
             float* __restrict__ qn, float* __restrict__ kn,
             float* __restrict__ vpath, float* __restrict__ beta) {
  const int bid  = blockIdx.x;
  const int b    = bid >> 11;
  const int l    = bid & 2047;
  const int t    = threadIdx.x;
  const int wv   = t >> 6;
  const int lane = t & 63;
  const size_t row = (size_t)bid;

  __shared__ float s_red[4][4];

  float pb[4] = {0.f, 0.f, 0.f, 0.f};
#pragma unroll
  for (int i = 0; i < 4; ++i) {
    int c = wv * 256 + lane + i * 64;
    float x = hs[row * 1024 + c];
    pb[0] += x * Wb[0 * 1024 + c];
    pb[1] += x * Wb[1 * 1024 + c];
    pb[2] += x * Wb[2 * 1024 + c];
    pb[3] += x * Wb[3 * 1024 + c];
  }
#pragma unroll
  for (int off = 32; off; off >>= 1) {
    pb[0] += __shfl_xor(pb[0], off);
    pb[1] += __shfl_xor(pb[1], off);
    pb[2] += __shfl_xor(pb[2], off);
    pb[3] += __shfl_xor(pb[3], off);
  }
  if (lane == 0) {
    s_red[0][wv] = pb[0]; s_red[1][wv] = pb[1];
    s_red[2][wv] = pb[2]; s_red[3][wv] = pb[3];
  }
  __syncthreads();

  float xq[4], xk[4], xv[4];
#pragma unroll
  for (int i = 0; i < 4; ++i) {
    int c = wv * 256 + lane + i * 64;
    float aq = 0.f, ak = 0.f, av = 0.f;
#pragma unroll
    for (int j = 0; j < 4; ++j) {
      int ls = l - 3 + j;
      if (ls >= 0) {
        size_t ro = (size_t)(b * 2048 + ls) * 1024 + c;
        aq = fmaf(qlin[ro], qw[c * 4 + j], aq);
        ak = fmaf(klin[ro], kw[c * 4 + j], ak);
        av = fmaf(vlin[ro], vw[c * 4 + j], av);
      }
    }
    xq[i] = aq / (1.f + expf(-aq));
    xk[i] = ak / (1.f + expf(-ak));
    xv[i] = av / (1.f + expf(-av));
  }

  float sq = 0.f, sk = 0.f;
#pragma unroll
  for (int i = 0; i < 4; ++i) { sq += xq[i] * xq[i]; sk += xk[i] * xk[i]; }
#pragma unroll
  for (int off = 32; off; off >>= 1) {
    sq += __shfl_xor(sq, off);
    sk += __shfl_xor(sk, off);
  }
  float rq = rsqrtf(sq + 1e-6f);
  float rk = rsqrtf(sk + 1e-6f);
  float bsum = s_red[wv][0] + s_red[wv][1] + s_red[wv][2] + s_red[wv][3];
  float betaw = 1.f / (1.f + expf(-bsum));
  if (lane == 0) beta[(size_t)bid * 4 + wv] = betaw;

  const int chk = l >> 5, pos = l & 31;
  size_t cbase = ((size_t)((b * 4 + wv) * 64 + chk) * 32 + pos) * 256;
#pragma unroll
  for (int i = 0; i < 4; ++i) {
    int d = lane + i * 64;
    qn[cbase + d] = xq[i] * rq;
    kn[cbase + d] = xk[i] * rk;
    vpath[row * 1024 + wv * 256 + d] = xv[i];
  }
}

// -------------------- K3: per-chunk A, (I+A)^-1 transform; exports bf16 frags
// outputs: u (f32 [chunk][32][256]); qb (bf16, q, row-major); wb (bf16, -w);
//          knTp (bf16, k TRANSPOSED [chunk][256][32]); attnb (bf16 [chunk][32][32])
__global__ __launch_bounds__(256)
void k3_chunk(const float* __restrict__ qn, const float* __restrict__ kn,
              const float* __restrict__ vpath, const float* __restrict__ beta,
              float* __restrict__ u, bf16* __restrict__ qb,
              bf16* __restrict__ wb, bf16* __restrict__ knTp,
              bf16* __restrict__ attnb) {
  __shared__ float s_kn[32][257];
  __shared__ float s_kb[32][257];
  __shared__ float s_x[32][257];
  __shared__ float s_A[32][33];
  __shared__ float s_beta[32];
  const int bid = blockIdx.x;
  const int bh = bid >> 6, chk = bid & 63;
  const int b = bh >> 2, h = bh & 3;
  const int t = threadIdx.x;
  const size_t base = (size_t)bid * 8192;

  if (t < 32)
    s_beta[t] = beta[((size_t)(b * 2048 + chk * 32 + t)) * 4 + h];
  for (int i = 0; i < 32; ++i) {
    int idx = t + i * 256;
    int r = idx >> 8, d = idx & 255;
    s_kn[r][d] = kn[base + idx];
    s_x[r][d]  = qn[base + idx];
  }
  __syncthreads();
  for (int i = 0; i < 32; ++i) {
    int idx = t + i * 256;
    int r = idx >> 8, d = idx & 255;
    s_kb[r][d] = s_kn[r][d] * s_beta[r];
  }
  __syncthreads();

  // A = -(kb @ kn^T) strictly-lower;  attn = tril(qn @ kn^T) -> bf16
  {
    const int r = t & 31, cg = t >> 5;
    float accA[4] = {0.f, 0.f, 0.f, 0.f};
    float accT[4] = {0.f, 0.f, 0.f, 0.f};
    for (int d = 0; d < 256; ++d) {
      float kbr = s_kb[r][d];
      float qr  = s_x[r][d];
#pragma unroll
      for (int q = 0; q < 4; ++q) {
        float knc = s_kn[cg * 4 + q][d];
        accA[q] = fmaf(kbr, knc, accA[q]);
        accT[q] = fmaf(qr,  knc, accT[q]);
      }
    }
    float at[4];
#pragma unroll
    for (int q = 0; q < 4; ++q) {
      int c = cg * 4 + q;
      s_A[r][c] = (r > c) ? -accA[q] : 0.f;
      at[q] = (r >= c) ? accT[q] : 0.f;
    }
    uint2 pk;
    pk.x = pack2(at[0], at[1]);
    pk.y = pack2(at[2], at[3]);
    *(uint2*)((char*)(attnb + (size_t)bid * 1024) + r * 64 + cg * 8) = pk;
  }

  // export qb (bf16) and knT (bf16, transposed) while s_x still holds q
  for (int i = 0; i < 32; ++i) {
    int idx = t + i * 256;
    int r = idx >> 8, d = idx & 255;
    qb[base + idx] = (bf16)s_x[r][d];
  }
  for (int i = 0; i < 32; ++i) {
    int d = (i << 3) + (t >> 5);
    int r = t & 31;
    knTp[base + d * 32 + r] = (bf16)s_kn[r][d];
  }
  __syncthreads();

  // iterative inversion
  for (int i = 1; i < 32; ++i) {
    float s = 0.f;
    if (t < i) {
      for (int j = 0; j < 32; ++j) s = fmaf(s_A[i][j], s_A[j][t], s);
    }
    __syncthreads();
    if (t < i) s_A[i][t] += s;
    __syncthreads();
  }

  // load vb = v * beta into s_x (qb export completed before inversion barriers)
  for (int i = 0; i < 32; ++i) {
    int idx = t + i * 256;
    int r = idx >> 8, d = idx & 255;
    s_x[r][d] = vpath[((size_t)(b * 2048 + chk * 32 + r)) * 1024 + h * 256 + d]
                * s_beta[r];
  }
  __syncthreads();

  // u = T @ vb (f32) ; wb = -(T @ kb) (bf16)
  {
    const int lane = t & 63, wvv = t >> 6;
    for (int rr = 0; rr < 8; ++rr) {
      int r = wvv * 8 + rr;
      float au[4] = {0.f, 0.f, 0.f, 0.f};
      float aw[4] = {0.f, 0.f, 0.f, 0.f};
      for (int j = 0; j <= r; ++j) {
        float tc = (j == r) ? 1.f : s_A[r][j];
#pragma unroll
        for (int dd = 0; dd < 4; ++dd) {
          au[dd] = fmaf(tc, s_x[j][lane + dd * 64], au[dd]);
          aw[dd] = fmaf(tc, s_kb[j][lane + dd * 64], aw[dd]);
        }
      }
#pragma unroll
      for (int dd = 0; dd < 4; ++dd) {
        int d = lane + dd * 64;
        u[base + r * 256 + d]  = au[dd];
        wb[base + r * 256 + d] = (bf16)(-aw[dd]);
      }
    }
  }
}

// ---------------- K4: MFMA chunk scan. 32 blocks = 8 bh x 4 col-blocks(64).
// Per wave: one 16-col N-slice (wave-private S cols/tmp/o => 1 barrier/chunk).
__global__ __launch_bounds__(256, 1)
void k4_scan_mfma(const bf16* __restrict__ qb, const bf16* __restrict__ wbp,
                  const bf16* __restrict__ knTp, const bf16* __restrict__ attnb,
                  const float* __restrict__ u, float* __restrict__ delta) {
  __shared__ __align__(16) bf16 s_w[2][32][272];   // [buf][row][k] (-w)
  __shared__ __align__(16) bf16 s_q[2][32][272];
  __shared__ __align__(16) bf16 s_kT[2][256][32];  // [buf][d][chunk-row]
  __shared__ __align__(16) bf16 s_S[64][264];      // [c_local][d] bf16 shadow of S
  __shared__ __align__(16) bf16 s_tT[64][32];      // tmp^T [c_local][row]
  __shared__ __align__(16) float s_o[32][68];      // Q@S partial
  const int tid = threadIdx.x;
  const int wv  = tid >> 6;          // N-slice 0..3
  const int l   = tid & 63;
  const int lr  = l & 15;
  const int lg  = l >> 4;
  const int cl  = wv * 16 + lr;      // block-local col
  const int bh  = blockIdx.x >> 2;
  const int c0  = (blockIdx.x & 3) * 64;
  const int b   = bh >> 2, h = bh & 3;
  const int chb = bh * 64;

  // zero S (regs + bf16 shadow)
  for (int i = tid; i < 64 * 264 / 2; i += 256) ((unsigned*)s_S)[i] = 0u;
  f32x4 S[16];
#pragma unroll
  for (int dt = 0; dt < 16; ++dt) S[dt] = (f32x4){0.f, 0.f, 0.f, 0.f};

  // prologue: stage chunk 0 into buf 0; prefetch chunk-0 reg frags
  {
    const uint4* gw = (const uint4*)(wbp  + (size_t)chb * 8192);
    const uint4* gq = (const uint4*)(qb   + (size_t)chb * 8192);
    const uint4* gk = (const uint4*)(knTp + (size_t)chb * 8192);
    uint4 st[12];
#pragma unroll
    for (int i = 0; i < 4; ++i) st[i]     = gw[tid + i * 256];
#pragma unroll
    for (int i = 0; i < 4; ++i) st[4 + i] = gq[tid + i * 256];
#pragma unroll
    for (int i = 0; i < 4; ++i) st[8 + i] = gk[tid + i * 256];
#pragma unroll
    for (int i = 0; i < 4; ++i) {
      int p = tid + i * 256;
      *(uint4*)((char*)s_w[0] + (p >> 5) * 544 + (p & 31) * 16) = st[i];
      *(uint4*)((char*)s_q[0] + (p >> 5) * 544 + (p & 31) * 16) = st[4 + i];
      *(uint4*)((char*)s_kT[0] + p * 16) = st[8 + i];
    }
  }
  bf16x8 atA0, atA1, atA0n, atA1n;
  float uc[8], un[8];
  {
    const char* cat = (const char*)(attnb + (size_t)chb * 1024);
    atA0 = *(const bf16x8*)(cat + lr * 64 + lg * 16);
    atA1 = *(const bf16x8*)(cat + (16 + lr) * 64 + lg * 16);
    const float* cu = u + (size_t)chb * 8192;
#pragma unroll
    for (int mt = 0; mt < 2; ++mt)
#pragma unroll
      for (int j = 0; j < 4; ++j)
        uc[mt * 4 + j] = cu[(mt * 16 + lg * 4 + j) * 256 + c0 + cl];
  }
  __syncthreads();

  for (int t = 0; t < 64; ++t) {
    const int bc = t & 1, nb = bc ^ 1;
    // ---- issue next-chunk staging loads (consumed at end of this chunk)
    uint4 st[12];
    if (t < 63) {
      const uint4* gw = (const uint4*)(wbp  + (size_t)(chb + t + 1) * 8192);
      const uint4* gq = (const uint4*)(qb   + (size_t)(chb + t + 1) * 8192);
      const uint4* gk = (const uint4*)(knTp + (size_t)(chb + t + 1) * 8192);
#pragma unroll
      for (int i = 0; i < 4; ++i) st[i]     = gw[tid + i * 256];
#pragma unroll
      for (int i = 0; i < 4; ++i) st[4 + i] = gq[tid + i * 256];
#pragma unroll
      for (int i = 0; i < 4; ++i) st[8 + i] = gk[tid + i * 256];
      const char* cat = (const char*)(attnb + (size_t)(chb + t + 1) * 1024);
      atA0n = *(const bf16x8*)(cat + lr * 64 + lg * 16);
      atA1n = *(const bf16x8*)(cat + (16 + lr) * 64 + lg * 16);
      const float* cu = u + (size_t)(chb + t + 1) * 8192;
#pragma unroll
      for (int mt = 0; mt < 2; ++mt)
#pragma unroll
        for (int j = 0; j < 4; ++j)
          un[mt * 4 + j] = cu[(mt * 16 + lg * 4 + j) * 256 + c0 + cl];
    }

    // ---- phase 1: tmp = u + (-W)@S ; O1 = Q@S   (K = 256, 8 MFMA steps)
    const char* pw = (const char*)s_w[bc];
    const char* pq = (const char*)s_q[bc];
    const bf16* srow = &s_S[cl][0];
    f32x4 t0 = (f32x4){uc[0], uc[1], uc[2], uc[3]};
    f32x4 t1 = (f32x4){uc[4], uc[5], uc[6], uc[7]};
    f32x4 o0 = (f32x4){0.f, 0.f, 0.f, 0.f};
    f32x4 o1 = (f32x4){0.f, 0.f, 0.f, 0.f};
#pragma unroll
    for (int kb = 0; kb < 8; ++kb) {
      bf16x8 sB  = *(const bf16x8*)(srow + kb * 32 + lg * 8);
      bf16x8 aw0 = *(const bf16x8*)(pw + lr * 544 + kb * 64 + lg * 16);
      bf16x8 aw1 = *(const bf16x8*)(pw + (16 + lr) * 544 + kb * 64 + lg * 16);
      bf16x8 aq0 = *(const bf16x8*)(pq + lr * 544 + kb * 64 + lg * 16);
      bf16x8 aq1 = *(const bf16x8*)(pq + (16 + lr) * 544 + kb * 64 + lg * 16);
      t0 = MFMA16(aw0, sB, t0);
      t1 = MFMA16(aw1, sB, t1);
      o0 = MFMA16(aq0, sB, o0);
      o1 = MFMA16(aq1, sB, o1);
    }
    // write tmp^T (bf16) and O1 (f32) — wave-private columns
    *(unsigned*)&s_tT[cl][lg * 4]      = pack2(t0[0], t0[1]);
    *(unsigned*)&s_tT[cl][lg * 4 + 2]  = pack2(t0[2], t0[3]);
    *(unsigned*)&s_tT[cl][16 + lg * 4]     = pack2(t1[0], t1[1]);
    *(unsigned*)&s_tT[cl][16 + lg * 4 + 2] = pack2(t1[2], t1[3]);
#pragma unroll
    for (int j = 0; j < 4; ++j) {
      s_o[lg * 4 + j][cl]      = o0[j];
      s_o[16 + lg * 4 + j][cl] = o1[j];
    }

    // ---- phase 2: O = O1 + attn @ tmp ; store delta
    bf16x8 tB = *(const bf16x8*)((const char*)&s_tT[cl][0] + lg * 16);
    f32x4 O0 = (f32x4){s_o[lg * 4 + 0][cl], s_o[lg * 4 + 1][cl],
                       s_o[lg * 4 + 2][cl], s_o[lg * 4 + 3][cl]};
    f32x4 O1 = (f32x4){s_o[16 + lg * 4 + 0][cl], s_o[16 + lg * 4 + 1][cl],
                       s_o[16 + lg * 4 + 2][cl], s_o[16 + lg * 4 + 3][cl]};
    O0 = MFMA16(atA0, tB, O0);
    O1 = MFMA16(atA1, tB, O1);
#pragma unroll
    for (int j = 0; j < 4; ++j) {
      int r0 = t * 32 + lg * 4 + j;
      delta[((size_t)(b * 2048 + r0)) * 1024 + h * 256 + c0 + cl] = O0[j];
      delta[((size_t)(b * 2048 + r0 + 16)) * 1024 + h * 256 + c0 + cl] = O1[j];
    }

    // ---- phase 3: S += K^T @ tmp  (16 d-tiles) + refresh bf16 shadow
    const char* pk = (const char*)s_kT[bc];
#pragma unroll
    for (int dt = 0; dt < 16; ++dt) {
      bf16x8 aK = *(const bf16x8*)(pk + (dt * 16 + lr) * 64 + lg * 16);
      S[dt] = MFMA16(aK, tB, S[dt]);
    }
#pragma unroll
    for (int dt = 0; dt < 16; ++dt) {
      *(unsigned*)&s_S[cl][dt * 16 + lg * 4]     = pack2(S[dt][0], S[dt][1]);
      *(unsigned*)&s_S[cl][dt * 16 + lg * 4 + 2] = pack2(S[dt][2], S[dt][3]);
    }

    // ---- write next-chunk staging into other buffer; swap reg prefetches
    if (t < 63) {
#pragma unroll
      for (int i = 0; i < 4; ++i) {
        int p = tid + i * 256;
        *(uint4*)((char*)s_w[nb] + (p >> 5) * 544 + (p & 31) * 16) = st[i];
        *(uint4*)((char*)s_q[nb] + (p >> 5) * 544 + (p & 31) * 16) = st[4 + i];
        *(uint4*)((char*)s_kT[nb] + p * 16) = st[8 + i];
      }
      atA0 = atA0n; atA1 = atA1n;
#pragma unroll
      for (int j = 0; j < 8; ++j) uc[j] = un[j];
    }
    lds_barrier();
  }
}

// ------------------------------------------------- K5: FIR short(3)/long(63)
__global__ __launch_bounds__(256)
void k5_fir(const float* __restrict__ vpath, const float* __restrict__ wsrt,
            const float* __restrict__ wlng, float* __restrict__ shortp,
            float* __restrict__ longp) {
  __shared__ float s_v[126][128];
  __shared__ float s_wl[63][128];
  __shared__ float s_ws[3][128];
  const int c0 = blockIdx.x * 128;
  const int l0 = blockIdx.y * 64;
  const int b  = blockIdx.z;
  const int t  = threadIdx.x;

  for (int i = 0; i < 63; ++i) {
    int idx = t + i * 256;
    int rr = idx >> 7, cc = idx & 127;
    int gl = l0 - 62 + rr;
    s_v[rr][cc] = (gl >= 0)
        ? vpath[((size_t)(b * 2048 + gl)) * 1024 + c0 + cc] : 0.f;
  }
  for (int i = t; i < 63 * 128; i += 256) {
    int cc = i / 63, j = i % 63;
    s_wl[j][cc] = wlng[(size_t)(c0 + cc) * 63 + j];
  }
  for (int i = t; i < 3 * 128; i += 256) {
    int cc = i / 3, j = i % 3;
    s_ws[j][cc] = wsrt[(size_t)(c0 + cc) * 3 + j];
  }
  __syncthreads();

  const int cc = t & 127, lh = t >> 7;
  for (int m = 0; m < 32; ++m) {
    int ll = lh * 32 + m;
    float accL = 0.f;
    for (int j = 0; j < 63; ++j)
      accL = fmaf(s_v[ll + j][cc], s_wl[j][cc], accL);
    float accS = 0.f;
#pragma unroll
    for (int j = 0; j < 3; ++j)
      accS = fmaf(s_v[ll + 60 + j][cc], s_ws[j][cc], accS);
    size_t o = ((size_t)(b * 2048 + l0 + ll)) * 1024 + c0 + cc;
    longp[o] = accL;
    shortp[o] = accS;
  }
}

// --------------------------------------------- K6: path stats + gate_in build
__global__ __launch_bounds__(256)
void k6_gatein(const float* __restrict__ hs, const float* __restrict__ shortp,
               const float* __restrict__ longp, const float* __restrict__ delta,
               const float* __restrict__ vpath, float* __restrict__ gate_in) {
  const size_t row = blockIdx.x;
  const int t = threadIdx.x, wv = t >> 6, lane = t & 63;
#pragma unroll
  for (int i = 0; i < 4; ++i) {
    int c = t + i * 256;
    gate_in[row * 1056 + c] = hs[row * 1024 + c];
  }
  const float* paths[4] = {shortp, longp, delta, vpath};
#pragma unroll
  for (int p = 0; p < 4; ++p) {
    float s = 0.f, sq = 0.f;
#pragma unroll
    for (int i = 0; i < 4; ++i) {
      int c = wv * 256 + lane + i * 64;
      float x = paths[p][row * 1024 + c];
      s += x; sq += x * x;
    }
#pragma unroll
    for (int off = 32; off; off >>= 1) {
      s += __shfl_xor(s, off);
      sq += __shfl_xor(sq, off);
    }
    if (lane == 0) {
      float mean = s * (1.f / 256.f);
      float var = sq * (1.f / 256.f) - mean * mean;
      gate_in[row * 1056 + 1024 + p * 8 + wv * 2 + 0] = mean;
      gate_in[row * 1056 + 1024 + p * 8 + wv * 2 + 1] = var;
    }
  }
}

// ------------------------------- K8: logits GEMV + softmax + floor + renorm
__global__ __launch_bounds__(256)
void k8_probs(const float* __restrict__ hmid, const float* __restrict__ w2,
              const float* __restrict__ bias, const float* __restrict__ log_temp,
              const float* __restrict__ floor_raw, float* __restrict__ probs) {
  const int t = threadIdx.x, wv = t >> 6, lane = t & 63;
  const size_t row = (size_t)blockIdx.x * 4 + wv;
  float acc[16];
#pragma unroll
  for (int o = 0; o < 16; ++o) acc[o] = 0.f;
  for (int it = 0; it < 32; ++it) {
    int c = lane + it * 64;
    float x = hmid[row * 2048 + c];
#pragma unroll
    for (int o = 0; o < 16; ++o)
      acc[o] = fmaf(x, w2[o * 2048 + c], acc[o]);
  }
#pragma unroll
  for (int off = 32; off; off >>= 1)
#pragma unroll
    for (int o = 0; o < 16; ++o) acc[o] += __shfl_xor(acc[o], off);

  if (lane == 0) {
    for (int h2 = 0; h2 < 4; ++h2) {
      float temp = log1pf(expf(log_temp[h2])) + 1e-4f;
      float li[4], m = -1e30f;
#pragma unroll
      for (int p = 0; p < 4; ++p) {
        li[p] = (acc[h2 * 4 + p] + bias[h2 * 4 + p]) / temp;
        m = fmaxf(m, li[p]);
      }
      float sum = 0.f;
#pragma unroll
      for (int p = 0; p < 4; ++p) { li[p] = expf(li[p] - m); sum += li[p]; }
      float pr[4], s2 = 0.f;
#pragma unroll
      for (int p = 0; p < 4; ++p) {
        float fv = 0.05f / (1.f + expf(-floor_raw[h2 * 4 + p]));
        pr[p] = fmaxf(li[p] / sum, fv);
        s2 += pr[p];
      }
#pragma unroll
      for (int p = 0; p < 4; ++p)
        probs[row * 16 + h2 * 4 + p] = pr[p] / s2;
    }
  }
}

// ------------------------------------------------ K9: mix paths + RMS-norm
__global__ __launch_bounds__(256)
void k9_mix(const float* __restrict__ shortp, const float* __restrict__ longp,
            const float* __restrict__ delta, const float* __restrict__ vpath,
            const float* __restrict__ probs, const float* __restrict__ onorm,
            float* __restrict__ mixed) {
  const size_t row = blockIdx.x;
  const int t = threadIdx.x, wv = t >> 6, lane = t & 63;
  float p0 = probs[row * 16 + wv * 4 + 0];
  float p1 = probs[row * 16 + wv * 4 + 1];
  float p2 = probs[row * 16 + wv * 4 + 2];
  float p3 = probs[row * 16 + wv * 4 + 3];
  float m[4];
  float sq = 0.f;
#pragma unroll
  for (int i = 0; i < 4; ++i) {
    int c = wv * 256 + lane + i * 64;
    size_t o = row * 1024 + c;
    float x = p0 * shortp[o] + p1 * longp[o] + p2 * delta[o] + p3 * vpath[o];
    m[i] = x;
    sq += x * x;
  }
#pragma unroll
  for (int off = 32; off; off >>= 1) sq += __shfl_xor(sq, off);
  float sc = rsqrtf(sq * (1.f / 256.f) + 1e-5f);
#pragma unroll
  for (int i = 0; i < 4; ++i) {
    int d = lane + i * 64;
    mixed[row * 1024 + wv * 256 + d] = m[i] * sc * onorm[d];
  }
}

// ---------------------------------------------------------------- launcher
extern "C" void kernel_launch(void* const* d_in, const int* in_sizes, int n_in,
                              void* d_out, int out_size, void* d_ws,
                              size_t ws_size, hipStream_t stream) {
  const float* hs   = (const float*)d_in[0];
  const float* Wq   = (const float*)d_in[1];
  const float* Wk   = (const float*)d_in[2];
  const float* Wv   = (const float*)d_in[3];
  const float* Wb   = (const float*)d_in[4];
  const float* qw   = (const float*)d_in[5];
  const float* kw   = (const float*)d_in[6];
  const float* vw   = (const float*)d_in[7];
  const float* fsw  = (const float*)d_in[8];
  const float* flw  = (const float*)d_in[9];
  const float* gw1  = (const float*)d_in[10];
  const float* gb1  = (const float*)d_in[11];
  const float* gw2  = (const float*)d_in[12];
  const float* ltmp = (const float*)d_in[13];
  const float* bbias= (const float*)d_in[14];
  const float* frw  = (const float*)d_in[15];
  const float* onw  = (const float*)d_in[16];
  const float* Wo   = (const float*)d_in[17];
  float* out = (float*)d_out;

  float* f = (float*)d_ws;
  const size_t BLD = 4194304;  // B*L*D
  float* qlin    = f + 0 * BLD;
  float* klin    = f + 1 * BLD;
  float* vlin    = f + 2 * BLD;
  float* qn      = f + 3 * BLD;
  float* kn      = f + 4 * BLD;
  float* vpath   = f + 5 * BLD;
  float* shortp  = f + 6 * BLD;
  float* longp   = f + 7 * BLD;
  float* gate_in = f + 8 * BLD;                 // 4,325,376 floats
  float* probs   = gate_in + 4325376;           //    65,536
  float* beta    = probs + 65536;               //    16,384
  // reuses (lifetimes disjoint):
  float* u_f32 = qlin;            // [8][64][32][256] f32 (k3 out, k4 in)
  bf16*  qbb   = (bf16*)shortp;   // 512*8192 bf16 — dead once k5 writes shortp
  bf16*  wbb   = qbb + 512 * 8192;
  bf16*  knTb  = wbb + 512 * 8192;
  bf16*  attnb = knTb + 512 * 8192;  // 512*1024 bf16
  float* delta = vlin;
  float* hmid  = qn;     // spans qn..kn (2*BLD floats), free after k4
  float* mixed = klin;   // free after k4 (wb f32 gone; klin dead after k2/k3)

  // 1) q/k/v linear projections
  gemm_nt<0><<<dim3(16, 32), 256, 0, stream>>>(hs, Wq, nullptr, qlin, 4096, 1024, 1024);
  gemm_nt<0><<<dim3(16, 32), 256, 0, stream>>>(hs, Wk, nullptr, klin, 4096, 1024, 1024);
  gemm_nt<0><<<dim3(16, 32), 256, 0, stream>>>(hs, Wv, nullptr, vlin, 4096, 1024, 1024);
  // 2) conv+silu+l2norm+beta
  k2_conv<<<4096, 256, 0, stream>>>(hs, qlin, klin, vlin, qw, kw, vw, Wb,
                                    qn, kn, vpath, beta);
  // 3) per-chunk transforms (also exports bf16 MFMA operands)
  k3_chunk<<<512, 256, 0, stream>>>(qn, kn, vpath, beta, u_f32, qbb, wbb,
                                    knTb, attnb);
  // 4) MFMA serial scan
  k4_scan_mfma<<<32, 256, 0, stream>>>(qbb, wbb, knTb, attnb, u_f32, delta);
  // 5) FIR paths (MUST stay after k4: overwrites qbb/wbb/knTb region)
  k5_fir<<<dim3(8, 32, 2), 256, 0, stream>>>(vpath, fsw, flw, shortp, longp);
  // 6) gate input
  k6_gatein<<<4096, 256, 0, stream>>>(hs, shortp, longp, delta, vpath, gate_in);
  // 7) gate MLP layer 1 (gelu)
  gemm_nt<1><<<dim3(32, 32), 256, 0, stream>>>(gate_in, gw1, gb1, hmid, 4096, 2048, 1056);
  // 8) logits -> probs
  k8_probs<<<1024, 256, 0, stream>>>(hmid, gw2, bbias, ltmp, frw, probs);
  // 9) mix + RMS norm
  k9_mix<<<4096, 256, 0, stream>>>(shortp, longp, delta, vpath, probs, onw, mixed);
  // 10) output projection
  gemm_nt<0><<<dim3(16, 32), 256, 0, stream>>>(mixed, Wo, nullptr, out, 4096, 1024, 1024);
}

// Round 3
// 900.044 us; speedup vs baseline: 3.6831x; 1.5100x over previous
//
#include <hip/hip_runtime.h>
#include <cmath>

#define B_  2
#define L_  2048
#define D_  1024
#define H_  4
#define DK_ 256
#define NCH 64   // chunks of 32
#define CH_ 32

typedef __bf16 bf16;
typedef __bf16 bf16x8 __attribute__((ext_vector_type(8)));
typedef float  f32x4  __attribute__((ext_vector_type(4)));

#define MFMA16(a, b, c) __builtin_amdgcn_mfma_f32_16x16x32_bf16(a, b, c, 0, 0, 0)

static __device__ __forceinline__ unsigned pack2(float a, float b) {
  unsigned short ua = __builtin_bit_cast(unsigned short, (__bf16)a);
  unsigned short ub = __builtin_bit_cast(unsigned short, (__bf16)b);
  return (unsigned)ua | ((unsigned)ub << 16);
}

static __device__ __forceinline__ void lds_barrier() {
  asm volatile("s_waitcnt lgkmcnt(0)" ::: "memory");
  __builtin_amdgcn_sched_barrier(0);
  __builtin_amdgcn_s_barrier();
  __builtin_amdgcn_sched_barrier(0);
}

// ------------------------------------------------------- f32 -> bf16 convert
__global__ __launch_bounds__(256)
void kcvt(const float* __restrict__ in, bf16* __restrict__ outp, int n) {
  int i = (blockIdx.x * 256 + threadIdx.x) * 8;
  if (i < n) {
    float4 a = *(const float4*)(in + i);
    float4 b = *(const float4*)(in + i + 4);
    uint4 v = make_uint4(pack2(a.x, a.y), pack2(a.z, a.w),
                         pack2(b.x, b.y), pack2(b.z, b.w));
    *(uint4*)(outp + i) = v;
  }
}

// convert with row padding (zero-fill cols [cin, cout))
__global__ __launch_bounds__(256)
void kcvt_pad(const float* __restrict__ in, bf16* __restrict__ outp,
              int cin, int cout) {
  int r = blockIdx.x, c = threadIdx.x * 8;
  if (c >= cout) return;
  uint4 v = make_uint4(0u, 0u, 0u, 0u);
  if (c < cin) {
    float4 a = *(const float4*)(in + (size_t)r * cin + c);
    float4 b = *(const float4*)(in + (size_t)r * cin + c + 4);
    v = make_uint4(pack2(a.x, a.y), pack2(a.z, a.w),
                   pack2(b.x, b.y), pack2(b.z, b.w));
  }
  *(uint4*)(outp + (size_t)r * cout + c) = v;
}

// ---------------------------------------------------------- GEMM (bf16 MFMA)
// C[m][n] = sum_k A[m][k]*Bt[n][k]; A:[M][K] bf16, Bt:[N][K] bf16, C f32.
// BM=128, BN=64, BK=64; 4 waves stacked on M (32 rows each).
// LDS rows are exactly 128B; XOR swizzle byte^=((row&7)<<4) both sides (T2).
template<int EPI>   // 0 = none, 1 = gelu(x + bias[n]) exact
__global__ __launch_bounds__(256)
void gemm_bf16(const bf16* __restrict__ A, const bf16* __restrict__ Bt,
               const float* __restrict__ bias, float* __restrict__ C,
               int M, int N, int K) {
  __shared__ __align__(16) bf16 sA[128 * 64];
  __shared__ __align__(16) bf16 sB[64 * 64];
  const int t = threadIdx.x;
  const int wid = t >> 6, l = t & 63, lr = l & 15, lg = l >> 4;
  const int m0 = blockIdx.y * 128, n0 = blockIdx.x * 64;
  const int nsteps = K >> 6;

  f32x4 acc[2][4];
#pragma unroll
  for (int mt = 0; mt < 2; ++mt)
#pragma unroll
    for (int nt = 0; nt < 4; ++nt) acc[mt][nt] = (f32x4){0.f, 0.f, 0.f, 0.f};

  uint4 ra[4], rb[2];
  auto gload = [&](int s) {
#pragma unroll
    for (int i = 0; i < 4; ++i) {
      int u = t + i * 256, row = u >> 3, sl = u & 7;
      ra[i] = *(const uint4*)(A + (size_t)(m0 + row) * K + s * 64 + sl * 8);
    }
#pragma unroll
    for (int i = 0; i < 2; ++i) {
      int u = t + i * 256, row = u >> 3, sl = u & 7;
      rb[i] = *(const uint4*)(Bt + (size_t)(n0 + row) * K + s * 64 + sl * 8);
    }
  };

  gload(0);
  for (int s = 0; s < nsteps; ++s) {
#pragma unroll
    for (int i = 0; i < 4; ++i) {
      int u = t + i * 256, row = u >> 3, sl = u & 7;
      *(uint4*)((char*)sA + row * 128 + ((sl ^ (row & 7)) << 4)) = ra[i];
    }
#pragma unroll
    for (int i = 0; i < 2; ++i) {
      int u = t + i * 256, row = u >> 3, sl = u & 7;
      *(uint4*)((char*)sB + row * 128 + ((sl ^ (row & 7)) << 4)) = rb[i];
    }
    __syncthreads();
    if (s + 1 < nsteps) gload(s + 1);
#pragma unroll
    for (int kb = 0; kb < 2; ++kb) {
      const int ks = kb * 4 + lg;
      const int sw = (ks ^ (lr & 7)) << 4;
      bf16x8 bfr[4], afr[2];
#pragma unroll
      for (int nt = 0; nt < 4; ++nt)
        bfr[nt] = *(const bf16x8*)((const char*)sB + (nt * 16 + lr) * 128 + sw);
#pragma unroll
      for (int mt = 0; mt < 2; ++mt)
        afr[mt] = *(const bf16x8*)((const char*)sA +
                                   (wid * 32 + mt * 16 + lr) * 128 + sw);
#pragma unroll
      for (int mt = 0; mt < 2; ++mt)
#pragma unroll
        for (int nt = 0; nt < 4; ++nt)
          acc[mt][nt] = MFMA16(afr[mt], bfr[nt], acc[mt][nt]);
    }
    __syncthreads();
  }

#pragma unroll
  for (int mt = 0; mt < 2; ++mt)
#pragma unroll
    for (int nt = 0; nt < 4; ++nt) {
      int nn = n0 + nt * 16 + lr;
#pragma unroll
      for (int j = 0; j < 4; ++j) {
        int m = m0 + wid * 32 + mt * 16 + lg * 4 + j;
        float x = acc[mt][nt][j];
        if (EPI == 1) {
          x += bias[nn];
          x = 0.5f * x * (1.f + erff(x * 0.70710678118654752f));
        }
        C[(size_t)m * N + nn] = x;
      }
    }
}

// -------------------------------------------- K2: conv(K=4)+SiLU, l2norm, beta
__global__ __launch_bounds__(256)
void k2_conv(const float* __restrict__ hs,
             const float* __restrict__ qlin, const float* __restrict__ klin,
             const float* __restrict__ vlin,
             const float* __restrict__ qw, const float* __restrict__ kw,
             const float* __restrict__ vw, const float* __restrict__ Wb,
             float* __restrict__ qn, float* __restrict__ kn,
             float* __restrict__ vpath, float* __restrict__ beta) {
  const int bid  = blockIdx.x;
  const int b    = bid >> 11;
  const int l    = bid & 2047;
  const int t    = threadIdx.x;
  const int wv   = t >> 6;
  const int lane = t & 63;
  const size_t row = (size_t)bid;

  __shared__ float s_red[4][4];

  float pb[4] = {0.f, 0.f, 0.f, 0.f};
#pragma unroll
  for (int i = 0; i < 4; ++i) {
    int c = wv * 256 + lane + i * 64;
    float x = hs[row * 1024 + c];
    pb[0] += x * Wb[0 * 1024 + c];
    pb[1] += x * Wb[1 * 1024 + c];
    pb[2] += x * Wb[2 * 1024 + c];
    pb[3] += x * Wb[3 * 1024 + c];
  }
#pragma unroll
  for (int off = 32; off; off >>= 1) {
    pb[0] += __shfl_xor(pb[0], off);
    pb[1] += __shfl_xor(pb[1], off);
    pb[2] += __shfl_xor(pb[2], off);
    pb[3] += __shfl_xor(pb[3], off);
  }
  if (lane == 0) {
    s_red[0][wv] = pb[0]; s_red[1][wv] = pb[1];
    s_red[2][wv] = pb[2]; s_red[3][wv] = pb[3];
  }
  __syncthreads();

  float xq[4], xk[4], xv[4];
#pragma unroll
  for (int i = 0; i < 4; ++i) {
    int c = wv * 256 + lane + i * 64;
    float aq = 0.f, ak = 0.f, av = 0.f;
#pragma unroll
    for (int j = 0; j < 4; ++j) {
      int ls = l - 3 + j;
      if (ls >= 0) {
        size_t ro = (size_t)(b * 2048 + ls) * 1024 + c;
        aq = fmaf(qlin[ro], qw[c * 4 + j], aq);
        ak = fmaf(klin[ro], kw[c * 4 + j], ak);
        av = fmaf(vlin[ro], vw[c * 4 + j], av);
      }
    }
    xq[i] = aq / (1.f + expf(-aq));
    xk[i] = ak / (1.f + expf(-ak));
    xv[i] = av / (1.f + expf(-av));
  }

  float sq = 0.f, sk = 0.f;
#pragma unroll
  for (int i = 0; i < 4; ++i) { sq += xq[i] * xq[i]; sk += xk[i] * xk[i]; }
#pragma unroll
  for (int off = 32; off; off >>= 1) {
    sq += __shfl_xor(sq, off);
    sk += __shfl_xor(sk, off);
  }
  float rq = rsqrtf(sq + 1e-6f);
  float rk = rsqrtf(sk + 1e-6f);
  float bsum = s_red[wv][0] + s_red[wv][1] + s_red[wv][2] + s_red[wv][3];
  float betaw = 1.f / (1.f + expf(-bsum));
  if (lane == 0) beta[(size_t)bid * 4 + wv] = betaw;

  const int chk = l >> 5, pos = l & 31;
  size_t cbase = ((size_t)((b * 4 + wv) * 64 + chk) * 32 + pos) * 256;
#pragma unroll
  for (int i = 0; i < 4; ++i) {
    int d = lane + i * 64;
    qn[cbase + d] = xq[i] * rq;
    kn[cbase + d] = xk[i] * rk;
    vpath[row * 1024 + wv * 256 + d] = xv[i];
  }
}

// -------------------- K3: per-chunk A, (I+A)^-1 transform; exports bf16 frags
__global__ __launch_bounds__(256)
void k3_chunk(const float* __restrict__ qn, const float* __restrict__ kn,
              const float* __restrict__ vpath, const float* __restrict__ beta,
              float* __restrict__ u, bf16* __restrict__ qb,
              bf16* __restrict__ wb, bf16* __restrict__ knTp,
              bf16* __restrict__ attnb) {
  __shared__ float s_kn[32][257];
  __shared__ float s_kb[32][257];
  __shared__ float s_x[32][257];
  __shared__ float s_A[32][33];
  __shared__ float s_beta[32];
  const int bid = blockIdx.x;
  const int bh = bid >> 6, chk = bid & 63;
  const int b = bh >> 2, h = bh & 3;
  const int t = threadIdx.x;
  const size_t base = (size_t)bid * 8192;

  if (t < 32)
    s_beta[t] = beta[((size_t)(b * 2048 + chk * 32 + t)) * 4 + h];
  for (int i = 0; i < 32; ++i) {
    int idx = t + i * 256;
    int r = idx >> 8, d = idx & 255;
    s_kn[r][d] = kn[base + idx];
    s_x[r][d]  = qn[base + idx];
  }
  __syncthreads();
  for (int i = 0; i < 32; ++i) {
    int idx = t + i * 256;
    int r = idx >> 8, d = idx & 255;
    s_kb[r][d] = s_kn[r][d] * s_beta[r];
  }
  __syncthreads();

  {
    const int r = t & 31, cg = t >> 5;
    float accA[4] = {0.f, 0.f, 0.f, 0.f};
    float accT[4] = {0.f, 0.f, 0.f, 0.f};
    for (int d = 0; d < 256; ++d) {
      float kbr = s_kb[r][d];
      float qr  = s_x[r][d];
#pragma unroll
      for (int q = 0; q < 4; ++q) {
        float knc = s_kn[cg * 4 + q][d];
        accA[q] = fmaf(kbr, knc, accA[q]);
        accT[q] = fmaf(qr,  knc, accT[q]);
      }
    }
    float at[4];
#pragma unroll
    for (int q = 0; q < 4; ++q) {
      int c = cg * 4 + q;
      s_A[r][c] = (r > c) ? -accA[q] : 0.f;
      at[q] = (r >= c) ? accT[q] : 0.f;
    }
    uint2 pk;
    pk.x = pack2(at[0], at[1]);
    pk.y = pack2(at[2], at[3]);
    *(uint2*)((char*)(attnb + (size_t)bid * 1024) + r * 64 + cg * 8) = pk;
  }

  for (int i = 0; i < 32; ++i) {
    int idx = t + i * 256;
    int r = idx >> 8, d = idx & 255;
    qb[base + idx] = (bf16)s_x[r][d];
  }
  for (int i = 0; i < 32; ++i) {
    int d = (i << 3) + (t >> 5);
    int r = t & 31;
    knTp[base + d * 32 + r] = (bf16)s_kn[r][d];
  }
  __syncthreads();

  for (int i = 1; i < 32; ++i) {
    float s = 0.f;
    if (t < i) {
      for (int j = 0; j < 32; ++j) s = fmaf(s_A[i][j], s_A[j][t], s);
    }
    __syncthreads();
    if (t < i) s_A[i][t] += s;
    __syncthreads();
  }

  for (int i = 0; i < 32; ++i) {
    int idx = t + i * 256;
    int r = idx >> 8, d = idx & 255;
    s_x[r][d] = vpath[((size_t)(b * 2048 + chk * 32 + r)) * 1024 + h * 256 + d]
                * s_beta[r];
  }
  __syncthreads();

  {
    const int lane = t & 63, wvv = t >> 6;
    for (int rr = 0; rr < 8; ++rr) {
      int r = wvv * 8 + rr;
      float au[4] = {0.f, 0.f, 0.f, 0.f};
      float aw[4] = {0.f, 0.f, 0.f, 0.f};
      for (int j = 0; j <= r; ++j) {
        float tc = (j == r) ? 1.f : s_A[r][j];
#pragma unroll
        for (int dd = 0; dd < 4; ++dd) {
          au[dd] = fmaf(tc, s_x[j][lane + dd * 64], au[dd]);
          aw[dd] = fmaf(tc, s_kb[j][lane + dd * 64], aw[dd]);
        }
      }
#pragma unroll
      for (int dd = 0; dd < 4; ++dd) {
        int d = lane + dd * 64;
        u[base + r * 256 + d]  = au[dd];
        wb[base + r * 256 + d] = (bf16)(-aw[dd]);
      }
    }
  }
}

// ---------------- K4: MFMA chunk scan. 32 blocks = 8 bh x 4 col-blocks(64).
__global__ __launch_bounds__(256, 1)
void k4_scan_mfma(const bf16* __restrict__ qb, const bf16* __restrict__ wbp,
                  const bf16* __restrict__ knTp, const bf16* __restrict__ attnb,
                  const float* __restrict__ u, float* __restrict__ delta) {
  __shared__ __align__(16) bf16 s_w[2][32][272];
  __shared__ __align__(16) bf16 s_q[2][32][272];
  __shared__ __align__(16) bf16 s_kT[2][256][32];
  __shared__ __align__(16) bf16 s_S[64][264];
  __shared__ __align__(16) bf16 s_tT[64][32];
  __shared__ __align__(16) float s_o[32][68];
  const int tid = threadIdx.x;
  const int wv  = tid >> 6;
  const int l   = tid & 63;
  const int lr  = l & 15;
  const int lg  = l >> 4;
  const int cl  = wv * 16 + lr;
  const int bh  = blockIdx.x >> 2;
  const int c0  = (blockIdx.x & 3) * 64;
  const int b   = bh >> 2, h = bh & 3;
  const int chb = bh * 64;

  for (int i = tid; i < 64 * 264 / 2; i += 256) ((unsigned*)s_S)[i] = 0u;
  f32x4 S[16];
#pragma unroll
  for (int dt = 0; dt < 16; ++dt) S[dt] = (f32x4){0.f, 0.f, 0.f, 0.f};

  {
    const uint4* gw = (const uint4*)(wbp  + (size_t)chb * 8192);
    const uint4* gq = (const uint4*)(qb   + (size_t)chb * 8192);
    const uint4* gk = (const uint4*)(knTp + (size_t)chb * 8192);
    uint4 st[12];
#pragma unroll
    for (int i = 0; i < 4; ++i) st[i]     = gw[tid + i * 256];
#pragma unroll
    for (int i = 0; i < 4; ++i) st[4 + i] = gq[tid + i * 256];
#pragma unroll
    for (int i = 0; i < 4; ++i) st[8 + i] = gk[tid + i * 256];
#pragma unroll
    for (int i = 0; i < 4; ++i) {
      int p = tid + i * 256;
      *(uint4*)((char*)s_w[0] + (p >> 5) * 544 + (p & 31) * 16) = st[i];
      *(uint4*)((char*)s_q[0] + (p >> 5) * 544 + (p & 31) * 16) = st[4 + i];
      *(uint4*)((char*)s_kT[0] + p * 16) = st[8 + i];
    }
  }
  bf16x8 atA0, atA1, atA0n, atA1n;
  float uc[8], un[8];
  {
    const char* cat = (const char*)(attnb + (size_t)chb * 1024);
    atA0 = *(const bf16x8*)(cat + lr * 64 + lg * 16);
    atA1 = *(const bf16x8*)(cat + (16 + lr) * 64 + lg * 16);
    const float* cu = u + (size_t)chb * 8192;
#pragma unroll
    for (int mt = 0; mt < 2; ++mt)
#pragma unroll
      for (int j = 0; j < 4; ++j)
        uc[mt * 4 + j] = cu[(mt * 16 + lg * 4 + j) * 256 + c0 + cl];
  }
  __syncthreads();

  for (int t = 0; t < 64; ++t) {
    const int bc = t & 1, nb = bc ^ 1;
    uint4 st[12];
    if (t < 63) {
      const uint4* gw = (const uint4*)(wbp  + (size_t)(chb + t + 1) * 8192);
      const uint4* gq = (const uint4*)(qb   + (size_t)(chb + t + 1) * 8192);
      const uint4* gk = (const uint4*)(knTp + (size_t)(chb + t + 1) * 8192);
#pragma unroll
      for (int i = 0; i < 4; ++i) st[i]     = gw[tid + i * 256];
#pragma unroll
      for (int i = 0; i < 4; ++i) st[4 + i] = gq[tid + i * 256];
#pragma unroll
      for (int i = 0; i < 4; ++i) st[8 + i] = gk[tid + i * 256];
      const char* cat = (const char*)(attnb + (size_t)(chb + t + 1) * 1024);
      atA0n = *(const bf16x8*)(cat + lr * 64 + lg * 16);
      atA1n = *(const bf16x8*)(cat + (16 + lr) * 64 + lg * 16);
      const float* cu = u + (size_t)(chb + t + 1) * 8192;
#pragma unroll
      for (int mt = 0; mt < 2; ++mt)
#pragma unroll
        for (int j = 0; j < 4; ++j)
          un[mt * 4 + j] = cu[(mt * 16 + lg * 4 + j) * 256 + c0 + cl];
    }

    const char* pw = (const char*)s_w[bc];
    const char* pq = (const char*)s_q[bc];
    const bf16* srow = &s_S[cl][0];
    f32x4 t0 = (f32x4){uc[0], uc[1], uc[2], uc[3]};
    f32x4 t1 = (f32x4){uc[4], uc[5], uc[6], uc[7]};
    f32x4 o0 = (f32x4){0.f, 0.f, 0.f, 0.f};
    f32x4 o1 = (f32x4){0.f, 0.f, 0.f, 0.f};
#pragma unroll
    for (int kb = 0; kb < 8; ++kb) {
      bf16x8 sB  = *(const bf16x8*)(srow + kb * 32 + lg * 8);
      bf16x8 aw0 = *(const bf16x8*)(pw + lr * 544 + kb * 64 + lg * 16);
      bf16x8 aw1 = *(const bf16x8*)(pw + (16 + lr) * 544 + kb * 64 + lg * 16);
      bf16x8 aq0 = *(const bf16x8*)(pq + lr * 544 + kb * 64 + lg * 16);
      bf16x8 aq1 = *(const bf16x8*)(pq + (16 + lr) * 544 + kb * 64 + lg * 16);
      t0 = MFMA16(aw0, sB, t0);
      t1 = MFMA16(aw1, sB, t1);
      o0 = MFMA16(aq0, sB, o0);
      o1 = MFMA16(aq1, sB, o1);
    }
    *(unsigned*)&s_tT[cl][lg * 4]      = pack2(t0[0], t0[1]);
    *(unsigned*)&s_tT[cl][lg * 4 + 2]  = pack2(t0[2], t0[3]);
    *(unsigned*)&s_tT[cl][16 + lg * 4]     = pack2(t1[0], t1[1]);
    *(unsigned*)&s_tT[cl][16 + lg * 4 + 2] = pack2(t1[2], t1[3]);
#pragma unroll
    for (int j = 0; j < 4; ++j) {
      s_o[lg * 4 + j][cl]      = o0[j];
      s_o[16 + lg * 4 + j][cl] = o1[j];
    }

    bf16x8 tB = *(const bf16x8*)((const char*)&s_tT[cl][0] + lg * 16);
    f32x4 O0 = (f32x4){s_o[lg * 4 + 0][cl], s_o[lg * 4 + 1][cl],
                       s_o[lg * 4 + 2][cl], s_o[lg * 4 + 3][cl]};
    f32x4 O1 = (f32x4){s_o[16 + lg * 4 + 0][cl], s_o[16 + lg * 4 + 1][cl],
                       s_o[16 + lg * 4 + 2][cl], s_o[16 + lg * 4 + 3][cl]};
    O0 = MFMA16(atA0, tB, O0);
    O1 = MFMA16(atA1, tB, O1);
#pragma unroll
    for (int j = 0; j < 4; ++j) {
      int r0 = t * 32 + lg * 4 + j;
      delta[((size_t)(b * 2048 + r0)) * 1024 + h * 256 + c0 + cl] = O0[j];
      delta[((size_t)(b * 2048 + r0 + 16)) * 1024 + h * 256 + c0 + cl] = O1[j];
    }

    const char* pk = (const char*)s_kT[bc];
#pragma unroll
    for (int dt = 0; dt < 16; ++dt) {
      bf16x8 aK = *(const bf16x8*)(pk + (dt * 16 + lr) * 64 + lg * 16);
      S[dt] = MFMA16(aK, tB, S[dt]);
    }
#pragma unroll
    for (int dt = 0; dt < 16; ++dt) {
      *(unsigned*)&s_S[cl][dt * 16 + lg * 4]     = pack2(S[dt][0], S[dt][1]);
      *(unsigned*)&s_S[cl][dt * 16 + lg * 4 + 2] = pack2(S[dt][2], S[dt][3]);
    }

    if (t < 63) {
#pragma unroll
      for (int i = 0; i < 4; ++i) {
        int p = tid + i * 256;
        *(uint4*)((char*)s_w[nb] + (p >> 5) * 544 + (p & 31) * 16) = st[i];
        *(uint4*)((char*)s_q[nb] + (p >> 5) * 544 + (p & 31) * 16) = st[4 + i];
        *(uint4*)((char*)s_kT[nb] + p * 16) = st[8 + i];
      }
      atA0 = atA0n; atA1 = atA1n;
#pragma unroll
      for (int j = 0; j < 8; ++j) uc[j] = un[j];
    }
    lds_barrier();
  }
}

// ------------------------------------------------- K5: FIR short(3)/long(63)
__global__ __launch_bounds__(256)
void k5_fir(const float* __restrict__ vpath, const float* __restrict__ wsrt,
            const float* __restrict__ wlng, float* __restrict__ shortp,
            float* __restrict__ longp) {
  __shared__ float s_v[126][128];
  __shared__ float s_wl[63][128];
  __shared__ float s_ws[3][128];
  const int c0 = blockIdx.x * 128;
  const int l0 = blockIdx.y * 64;
  const int b  = blockIdx.z;
  const int t  = threadIdx.x;

  for (int i = 0; i < 63; ++i) {
    int idx = t + i * 256;
    int rr = idx >> 7, cc = idx & 127;
    int gl = l0 - 62 + rr;
    s_v[rr][cc] = (gl >= 0)
        ? vpath[((size_t)(b * 2048 + gl)) * 1024 + c0 + cc] : 0.f;
  }
  for (int i = t; i < 63 * 128; i += 256) {
    int cc = i / 63, j = i % 63;
    s_wl[j][cc] = wlng[(size_t)(c0 + cc) * 63 + j];
  }
  for (int i = t; i < 3 * 128; i += 256) {
    int cc = i / 3, j = i % 3;
    s_ws[j][cc] = wsrt[(size_t)(c0 + cc) * 3 + j];
  }
  __syncthreads();

  const int cc = t & 127, lh = t >> 7;
  for (int m = 0; m < 32; ++m) {
    int ll = lh * 32 + m;
    float accL = 0.f;
    for (int j = 0; j < 63; ++j)
      accL = fmaf(s_v[ll + j][cc], s_wl[j][cc], accL);
    float accS = 0.f;
#pragma unroll
    for (int j = 0; j < 3; ++j)
      accS = fmaf(s_v[ll + 60 + j][cc], s_ws[j][cc], accS);
    size_t o = ((size_t)(b * 2048 + l0 + ll)) * 1024 + c0 + cc;
    longp[o] = accL;
    shortp[o] = accS;
  }
}

// --------------------- K6: path stats + gate_in build (bf16, padded to 1088)
__global__ __launch_bounds__(256)
void k6_gatein(const float* __restrict__ hs, const float* __restrict__ shortp,
               const float* __restrict__ longp, const float* __restrict__ delta,
               const float* __restrict__ vpath, bf16* __restrict__ gate_in) {
  const size_t row = blockIdx.x;
  const int t = threadIdx.x, wv = t >> 6, lane = t & 63;
  bf16* gr = gate_in + row * 1088;
#pragma unroll
  for (int i = 0; i < 2; ++i) {
    int c2 = (t + i * 256) * 2;
    float a = hs[row * 1024 + c2];
    float b = hs[row * 1024 + c2 + 1];
    *(unsigned*)(gr + c2) = pack2(a, b);
  }
  if (t < 16) *(unsigned*)(gr + 1056 + t * 2) = 0u;   // zero pad [1056,1088)
  const float* paths[4] = {shortp, longp, delta, vpath};
#pragma unroll
  for (int p = 0; p < 4; ++p) {
    float s = 0.f, sq = 0.f;
#pragma unroll
    for (int i = 0; i < 4; ++i) {
      int c = wv * 256 + lane + i * 64;
      float x = paths[p][row * 1024 + c];
      s += x; sq += x * x;
    }
#pragma unroll
    for (int off = 32; off; off >>= 1) {
      s += __shfl_xor(s, off);
      sq += __shfl_xor(sq, off);
    }
    if (lane == 0) {
      float mean = s * (1.f / 256.f);
      float var = sq * (1.f / 256.f) - mean * mean;
      *(unsigned*)(gr + 1024 + p * 8 + wv * 2) = pack2(mean, var);
    }
  }
}

// ------------------------------- K8: logits GEMV + softmax + floor + renorm
__global__ __launch_bounds__(256)
void k8_probs(const float* __restrict__ hmid, const float* __restrict__ w2,
              const float* __restrict__ bias, const float* __restrict__ log_temp,
              const float* __restrict__ floor_raw, float* __restrict__ probs) {
  const int t = threadIdx.x, wv = t >> 6, lane = t & 63;
  const size_t row = (size_t)blockIdx.x * 4 + wv;
  float acc[16];
#pragma unroll
  for (int o = 0; o < 16; ++o) acc[o] = 0.f;
  for (int it = 0; it < 32; ++it) {
    int c = lane + it * 64;
    float x = hmid[row * 2048 + c];
#pragma unroll
    for (int o = 0; o < 16; ++o)
      acc[o] = fmaf(x, w2[o * 2048 + c], acc[o]);
  }
#pragma unroll
  for (int off = 32; off; off >>= 1)
#pragma unroll
    for (int o = 0; o < 16; ++o) acc[o] += __shfl_xor(acc[o], off);

  if (lane == 0) {
    for (int h2 = 0; h2 < 4; ++h2) {
      float temp = log1pf(expf(log_temp[h2])) + 1e-4f;
      float li[4], m = -1e30f;
#pragma unroll
      for (int p = 0; p < 4; ++p) {
        li[p] = (acc[h2 * 4 + p] + bias[h2 * 4 + p]) / temp;
        m = fmaxf(m, li[p]);
      }
      float sum = 0.f;
#pragma unroll
      for (int p = 0; p < 4; ++p) { li[p] = expf(li[p] - m); sum += li[p]; }
      float pr[4], s2 = 0.f;
#pragma unroll
      for (int p = 0; p < 4; ++p) {
        float fv = 0.05f / (1.f + expf(-floor_raw[h2 * 4 + p]));
        pr[p] = fmaxf(li[p] / sum, fv);
        s2 += pr[p];
      }
#pragma unroll
      for (int p = 0; p < 4; ++p)
        probs[row * 16 + h2 * 4 + p] = pr[p] / s2;
    }
  }
}

// ------------------------------- K9: mix paths + RMS-norm (bf16 out for GEMM)
__global__ __launch_bounds__(256)
void k9_mix(const float* __restrict__ shortp, const float* __restrict__ longp,
            const float* __restrict__ delta, const float* __restrict__ vpath,
            const float* __restrict__ probs, const float* __restrict__ onorm,
            bf16* __restrict__ mixed) {
  const size_t row = blockIdx.x;
  const int t = threadIdx.x, wv = t >> 6, lane = t & 63;
  float p0 = probs[row * 16 + wv * 4 + 0];
  float p1 = probs[row * 16 + wv * 4 + 1];
  float p2 = probs[row * 16 + wv * 4 + 2];
  float p3 = probs[row * 16 + wv * 4 + 3];
  float m[4];
  float sq = 0.f;
#pragma unroll
  for (int i = 0; i < 4; ++i) {
    int c = wv * 256 + lane + i * 64;
    size_t o = row * 1024 + c;
    float x = p0 * shortp[o] + p1 * longp[o] + p2 * delta[o] + p3 * vpath[o];
    m[i] = x;
    sq += x * x;
  }
#pragma unroll
  for (int off = 32; off; off >>= 1) sq += __shfl_xor(sq, off);
  float sc = rsqrtf(sq * (1.f / 256.f) + 1e-5f);
#pragma unroll
  for (int i = 0; i < 4; ++i) {
    int d = lane + i * 64;
    mixed[row * 1024 + wv * 256 + d] = (bf16)(m[i] * sc * onorm[d]);
  }
}

// ---------------------------------------------------------------- launcher
extern "C" void kernel_launch(void* const* d_in, const int* in_sizes, int n_in,
                              void* d_out, int out_size, void* d_ws,
                              size_t ws_size, hipStream_t stream) {
  const float* hs   = (const float*)d_in[0];
  const float* Wq   = (const float*)d_in[1];
  const float* Wk   = (const float*)d_in[2];
  const float* Wv   = (const float*)d_in[3];
  const float* Wb   = (const float*)d_in[4];
  const float* qw   = (const float*)d_in[5];
  const float* kw   = (const float*)d_in[6];
  const float* vw   = (const float*)d_in[7];
  const float* fsw  = (const float*)d_in[8];
  const float* flw  = (const float*)d_in[9];
  const float* gw1  = (const float*)d_in[10];
  const float* gb1  = (const float*)d_in[11];
  const float* gw2  = (const float*)d_in[12];
  const float* ltmp = (const float*)d_in[13];
  const float* bbias= (const float*)d_in[14];
  const float* frw  = (const float*)d_in[15];
  const float* onw  = (const float*)d_in[16];
  const float* Wo   = (const float*)d_in[17];
  float* out = (float*)d_out;

  float* f = (float*)d_ws;
  const size_t BLD = 4194304;  // B*L*D
  float* qlin    = f + 0 * BLD;
  float* klin    = f + 1 * BLD;
  float* vlin    = f + 2 * BLD;
  float* qn      = f + 3 * BLD;
  float* kn      = f + 4 * BLD;
  float* vpath   = f + 5 * BLD;
  float* shortp  = f + 6 * BLD;
  float* longp   = f + 7 * BLD;
  float* gate_f  = f + 8 * BLD;                 // 4,325,376 f32 region
  float* probs   = gate_f + 4325376;            //    65,536
  float* beta    = probs + 65536;               //    16,384

  // bf16 overlays (lifetimes disjoint):
  bf16* hsb  = (bf16*)gate_f;                   // [0, 4194304) — dead after QKV
  bf16* ginb = (bf16*)gate_f;                   // [0, 4456448) — written at k6
  bf16* gw1b = (bf16*)gate_f + 4456448;         // 2,228,224 (2048 x 1088 padded)
  bf16* wob  = (bf16*)gate_f + 4456448 + 2228224;  // 1,048,576
  bf16* wqb  = (bf16*)kn;                       // dead before k2 writes kn
  bf16* wkb  = wqb + 1048576;
  bf16* wvb  = wkb + 1048576;

  float* u_f32 = qlin;
  bf16*  qbb   = (bf16*)shortp;
  bf16*  wbb   = qbb + 512 * 8192;
  bf16*  knTb  = (bf16*)longp;
  bf16*  attnb = knTb + 512 * 8192;
  float* delta = vlin;
  float* hmid  = qn;                            // spans qn..kn (2 BLD)
  bf16*  mixb  = (bf16*)klin;

  // 0) f32 -> bf16 conversions
  kcvt<<<2048, 256, 0, stream>>>(hs, hsb, 4194304);
  kcvt<<<512, 256, 0, stream>>>(Wq, wqb, 1048576);
  kcvt<<<512, 256, 0, stream>>>(Wk, wkb, 1048576);
  kcvt<<<512, 256, 0, stream>>>(Wv, wvb, 1048576);
  kcvt<<<512, 256, 0, stream>>>(Wo, wob, 1048576);
  kcvt_pad<<<2048, 256, 0, stream>>>(gw1, gw1b, 1056, 1088);
  // 1) q/k/v linear projections (bf16 MFMA)
  gemm_bf16<0><<<dim3(16, 32), 256, 0, stream>>>(hsb, wqb, nullptr, qlin, 4096, 1024, 1024);
  gemm_bf16<0><<<dim3(16, 32), 256, 0, stream>>>(hsb, wkb, nullptr, klin, 4096, 1024, 1024);
  gemm_bf16<0><<<dim3(16, 32), 256, 0, stream>>>(hsb, wvb, nullptr, vlin, 4096, 1024, 1024);
  // 2) conv+silu+l2norm+beta
  k2_conv<<<4096, 256, 0, stream>>>(hs, qlin, klin, vlin, qw, kw, vw, Wb,
                                    qn, kn, vpath, beta);
  // 3) per-chunk transforms (exports bf16 MFMA operands)
  k3_chunk<<<512, 256, 0, stream>>>(qn, kn, vpath, beta, u_f32, qbb, wbb,
                                    knTb, attnb);
  // 4) MFMA serial scan
  k4_scan_mfma<<<32, 256, 0, stream>>>(qbb, wbb, knTb, attnb, u_f32, delta);
  // 5) FIR paths (after k4: overwrites qbb/wbb/knTb region)
  k5_fir<<<dim3(8, 32, 2), 256, 0, stream>>>(vpath, fsw, flw, shortp, longp);
  // 6) gate input (bf16, K padded to 1088)
  k6_gatein<<<4096, 256, 0, stream>>>(hs, shortp, longp, delta, vpath, ginb);
  // 7) gate MLP layer 1 (gelu, bf16 MFMA)
  gemm_bf16<1><<<dim3(32, 32), 256, 0, stream>>>(ginb, gw1b, gb1, hmid, 4096, 2048, 1088);
  // 8) logits -> probs
  k8_probs<<<1024, 256, 0, stream>>>(hmid, gw2, bbias, ltmp, frw, probs);
  // 9) mix + RMS norm (bf16 out)
  k9_mix<<<4096, 256, 0, stream>>>(shortp, longp, delta, vpath, probs, onw, mixb);
  // 10) output projection (bf16 MFMA)
  gemm_bf16<0><<<dim3(16, 32), 256, 0, stream>>>(mixb, wob, nullptr, out, 4096, 1024, 1024);
}

// Round 4
// 702.227 us; speedup vs baseline: 4.7206x; 1.2817x over previous
//
#include <hip/hip_runtime.h>
#include <cmath>

typedef __bf16 bf16;
typedef __bf16 bf16x8 __attribute__((ext_vector_type(8)));
typedef float  f32x4  __attribute__((ext_vector_type(4)));

#define MFMA16(a, b, c) __builtin_amdgcn_mfma_f32_16x16x32_bf16(a, b, c, 0, 0, 0)

#define GLD16(gsrc, ldst)                                                     \
  __builtin_amdgcn_global_load_lds(                                           \
      (const __attribute__((address_space(1))) unsigned*)(gsrc),              \
      (__attribute__((address_space(3))) unsigned*)(ldst), 16, 0, 0)

static __device__ __forceinline__ unsigned pack2(float a, float b) {
  unsigned short ua = __builtin_bit_cast(unsigned short, (__bf16)a);
  unsigned short ub = __builtin_bit_cast(unsigned short, (__bf16)b);
  return (unsigned)ua | ((unsigned)ub << 16);
}

// ------------------------------------------------------- f32 -> bf16 convert
__global__ __launch_bounds__(256)
void kcvt(const float* __restrict__ in, bf16* __restrict__ outp, int n) {
  int i = (blockIdx.x * 256 + threadIdx.x) * 8;
  if (i < n) {
    float4 a = *(const float4*)(in + i);
    float4 b = *(const float4*)(in + i + 4);
    uint4 v = make_uint4(pack2(a.x, a.y), pack2(a.z, a.w),
                         pack2(b.x, b.y), pack2(b.z, b.w));
    *(uint4*)(outp + i) = v;
  }
}

__global__ __launch_bounds__(256)
void kcvt_pad(const float* __restrict__ in, bf16* __restrict__ outp,
              int cin, int cout) {
  int r = blockIdx.x, c = threadIdx.x * 8;
  if (c >= cout) return;
  uint4 v = make_uint4(0u, 0u, 0u, 0u);
  if (c < cin) {
    float4 a = *(const float4*)(in + (size_t)r * cin + c);
    float4 b = *(const float4*)(in + (size_t)r * cin + c + 4);
    v = make_uint4(pack2(a.x, a.y), pack2(a.z, a.w),
                   pack2(b.x, b.y), pack2(b.z, b.w));
  }
  *(uint4*)(outp + (size_t)r * cout + c) = v;
}

// ---------------------------------------------------------- GEMM (bf16 MFMA)
// C = A @ Bt^T. A:[M][K] bf16, Bt:[N][K] bf16, C f32. 128x128 tile, BK=64,
// double-buffered LDS via global_load_lds (m97 structure). 4 waves, 64x64 each.
template<int EPI>   // 0 = none, 1 = gelu(x + bias[n]) exact
__global__ __launch_bounds__(256)
void gemm_bf16(const bf16* __restrict__ A, const bf16* __restrict__ Bt,
               const float* __restrict__ bias, float* __restrict__ C,
               int M, int N, int K) {
  __shared__ __align__(16) bf16 sA[2][128 * 64];
  __shared__ __align__(16) bf16 sB[2][128 * 64];
  const int t = threadIdx.x;
  const int w = t >> 6, l = t & 63, lr = l & 15, lg = l >> 4;
  const int m0 = blockIdx.y * 128, n0 = blockIdx.x * 128;
  const int wm = (w & 1) * 64, wn = (w >> 1) * 64;
  const int w32 = w * 32;
  const int nst = K >> 6;

  f32x4 acc[4][4];
#pragma unroll
  for (int mt = 0; mt < 4; ++mt)
#pragma unroll
    for (int nt = 0; nt < 4; ++nt) acc[mt][nt] = (f32x4){0.f, 0.f, 0.f, 0.f};

  auto stage = [&](int s, int bf) {
    const char* ga = (const char*)A + ((size_t)(m0 + w32) * K + (size_t)s * 64) * 2;
    const char* gb = (const char*)Bt + ((size_t)(n0 + w32) * K + (size_t)s * 64) * 2;
    char* da = (char*)&sA[bf][0] + w32 * 128;
    char* db = (char*)&sB[bf][0] + w32 * 128;
    const size_t rs = (size_t)K * 2;
#pragma unroll
    for (int i = 0; i < 4; ++i) {
      GLD16(ga + (i * 8 + (l >> 3)) * rs + (l & 7) * 16, da + i * 1024);
      GLD16(gb + (i * 8 + (l >> 3)) * rs + (l & 7) * 16, db + i * 1024);
    }
  };

  stage(0, 0);
  __syncthreads();
  for (int s = 0; s < nst; ++s) {
    const int bf = s & 1;
    if (s + 1 < nst) stage(s + 1, bf ^ 1);
    const char* pa = (const char*)&sA[bf][0];
    const char* pb = (const char*)&sB[bf][0];
#pragma unroll
    for (int kb = 0; kb < 2; ++kb) {
      bf16x8 af[4], bfg[4];
#pragma unroll
      for (int mt = 0; mt < 4; ++mt)
        af[mt] = *(const bf16x8*)(pa + (wm + mt * 16 + lr) * 128 + kb * 64 + lg * 16);
#pragma unroll
      for (int nt = 0; nt < 4; ++nt)
        bfg[nt] = *(const bf16x8*)(pb + (wn + nt * 16 + lr) * 128 + kb * 64 + lg * 16);
#pragma unroll
      for (int mt = 0; mt < 4; ++mt)
#pragma unroll
        for (int nt = 0; nt < 4; ++nt)
          acc[mt][nt] = MFMA16(af[mt], bfg[nt], acc[mt][nt]);
    }
    __syncthreads();
  }

#pragma unroll
  for (int mt = 0; mt < 4; ++mt)
#pragma unroll
    for (int nt = 0; nt < 4; ++nt) {
      int nn = n0 + wn + nt * 16 + lr;
#pragma unroll
      for (int j = 0; j < 4; ++j) {
        int m = m0 + wm + mt * 16 + lg * 4 + j;
        float x = acc[mt][nt][j];
        if (EPI == 1) {
          x += bias[nn];
          x = 0.5f * x * (1.f + erff(x * 0.70710678118654752f));
        }
        C[(size_t)m * N + nn] = x;
      }
    }
}

// -------------------------------------------- K2: conv(K=4)+SiLU, l2norm, beta
__global__ __launch_bounds__(256)
void k2_conv(const float* __restrict__ hs,
             const float* __restrict__ qlin, const float* __restrict__ klin,
             const float* __restrict__ vlin,
             const float* __restrict__ qw, const float* __restrict__ kw,
             const float* __restrict__ vw, const float* __restrict__ Wb,
             float* __restrict__ qn, float* __restrict__ kn,
             float* __restrict__ vpath, float* __restrict__ beta) {
  const int bid  = blockIdx.x;
  const int b    = bid >> 11;
  const int l    = bid & 2047;
  const int t    = threadIdx.x;
  const int wv   = t >> 6;
  const int lane = t & 63;
  const size_t row = (size_t)bid;

  __shared__ float s_red[4][4];

  float pb[4] = {0.f, 0.f, 0.f, 0.f};
#pragma unroll
  for (int i = 0; i < 4; ++i) {
    int c = wv * 256 + lane + i * 64;
    float x = hs[row * 1024 + c];
    pb[0] += x * Wb[0 * 1024 + c];
    pb[1] += x * Wb[1 * 1024 + c];
    pb[2] += x * Wb[2 * 1024 + c];
    pb[3] += x * Wb[3 * 1024 + c];
  }
#pragma unroll
  for (int off = 32; off; off >>= 1) {
    pb[0] += __shfl_xor(pb[0], off);
    pb[1] += __shfl_xor(pb[1], off);
    pb[2] += __shfl_xor(pb[2], off);
    pb[3] += __shfl_xor(pb[3], off);
  }
  if (lane == 0) {
    s_red[0][wv] = pb[0]; s_red[1][wv] = pb[1];
    s_red[2][wv] = pb[2]; s_red[3][wv] = pb[3];
  }
  __syncthreads();

  float xq[4], xk[4], xv[4];
#pragma unroll
  for (int i = 0; i < 4; ++i) {
    int c = wv * 256 + lane + i * 64;
    float aq = 0.f, ak = 0.f, av = 0.f;
#pragma unroll
    for (int j = 0; j < 4; ++j) {
      int ls = l - 3 + j;
      if (ls >= 0) {
        size_t ro = (size_t)(b * 2048 + ls) * 1024 + c;
        aq = fmaf(qlin[ro], qw[c * 4 + j], aq);
        ak = fmaf(klin[ro], kw[c * 4 + j], ak);
        av = fmaf(vlin[ro], vw[c * 4 + j], av);
      }
    }
    xq[i] = aq / (1.f + expf(-aq));
    xk[i] = ak / (1.f + expf(-ak));
    xv[i] = av / (1.f + expf(-av));
  }

  float sq = 0.f, sk = 0.f;
#pragma unroll
  for (int i = 0; i < 4; ++i) { sq += xq[i] * xq[i]; sk += xk[i] * xk[i]; }
#pragma unroll
  for (int off = 32; off; off >>= 1) {
    sq += __shfl_xor(sq, off);
    sk += __shfl_xor(sk, off);
  }
  float rq = rsqrtf(sq + 1e-6f);
  float rk = rsqrtf(sk + 1e-6f);
  float bsum = s_red[wv][0] + s_red[wv][1] + s_red[wv][2] + s_red[wv][3];
  float betaw = 1.f / (1.f + expf(-bsum));
  if (lane == 0) beta[(size_t)bid * 4 + wv] = betaw;

  const int chk = l >> 5, pos = l & 31;
  size_t cbase = ((size_t)((b * 4 + wv) * 64 + chk) * 32 + pos) * 256;
#pragma unroll
  for (int i = 0; i < 4; ++i) {
    int d = lane + i * 64;
    qn[cbase + d] = xq[i] * rq;
    kn[cbase + d] = xk[i] * rk;
    vpath[row * 1024 + wv * 256 + d] = xv[i];
  }
}

// -------------------- K3: per-chunk A, (I+A)^-1 transform; exports MFMA frags
// Exports (all per global chunk bid = bh*64+chk):
//  qb/wb: [chunk] 32x256 bf16, LDS-linear with byte^=((row&15)<<4) col swizzle
//  knTp:  [chunk][256][32] bf16 (transposed, linear)
//  attnb: [chunk][mt 2][lane 64][8] bf16 A-fragment order
//  u:     [chunk][slice 8][lg 4][cl 32][8] f32
__global__ __launch_bounds__(256)
void k3_chunk(const float* __restrict__ qn, const float* __restrict__ kn,
              const float* __restrict__ vpath, const float* __restrict__ beta,
              float* __restrict__ u, bf16* __restrict__ qb,
              bf16* __restrict__ wb, bf16* __restrict__ knTp,
              bf16* __restrict__ attnb) {
  __shared__ float s_kn[32][257];
  __shared__ float s_kb[32][257];
  __shared__ float s_x[32][257];
  __shared__ float s_A[32][33];
  __shared__ float s_beta[32];
  const int bid = blockIdx.x;
  const int bh = bid >> 6, chk = bid & 63;
  const int b = bh >> 2, h = bh & 3;
  const int t = threadIdx.x;
  const size_t base = (size_t)bid * 8192;

  if (t < 32)
    s_beta[t] = beta[((size_t)(b * 2048 + chk * 32 + t)) * 4 + h];
  for (int i = 0; i < 32; ++i) {
    int idx = t + i * 256;
    int r = idx >> 8, d = idx & 255;
    s_kn[r][d] = kn[base + idx];
    s_x[r][d]  = qn[base + idx];
  }
  __syncthreads();
  for (int i = 0; i < 32; ++i) {
    int idx = t + i * 256;
    int r = idx >> 8, d = idx & 255;
    s_kb[r][d] = s_kn[r][d] * s_beta[r];
  }
  __syncthreads();

  {
    const int r = t & 31, cg = t >> 5;
    float accA[4] = {0.f, 0.f, 0.f, 0.f};
    float accT[4] = {0.f, 0.f, 0.f, 0.f};
    for (int d = 0; d < 256; ++d) {
      float kbr = s_kb[r][d];
      float qr  = s_x[r][d];
#pragma unroll
      for (int q = 0; q < 4; ++q) {
        float knc = s_kn[cg * 4 + q][d];
        accA[q] = fmaf(kbr, knc, accA[q]);
        accT[q] = fmaf(qr,  knc, accT[q]);
      }
    }
    float at[4];
#pragma unroll
    for (int q = 0; q < 4; ++q) {
      int c = cg * 4 + q;
      s_A[r][c] = (r > c) ? -accA[q] : 0.f;
      at[q] = (r >= c) ? accT[q] : 0.f;
    }
    // attn A-fragment export: lane=(cg>>1)*16+(r&15), elems (cg&1)*4..+3
    uint2 pk2;
    pk2.x = pack2(at[0], at[1]);
    pk2.y = pack2(at[2], at[3]);
    *(uint2*)((char*)attnb + (size_t)bid * 2048 +
              ((r >> 4) * 64 + (cg >> 1) * 16 + (r & 15)) * 16 + (cg & 1) * 8) = pk2;
  }

  // q export (swizzled) while s_x still holds q; kT export (linear)
  for (int i = 0; i < 32; ++i) {
    int idx = t + i * 256;
    int r = idx >> 8, d = idx & 255;
    *(bf16*)((char*)qb + (size_t)bid * 16384 + r * 512 +
             ((2 * d) ^ ((r & 15) << 4))) = (bf16)s_x[r][d];
  }
  for (int i = 0; i < 32; ++i) {
    int d = (i << 3) + (t >> 5);
    int r = t & 31;
    knTp[(size_t)bid * 8192 + d * 32 + r] = (bf16)s_kn[r][d];
  }
  __syncthreads();

  for (int i = 1; i < 32; ++i) {
    float s = 0.f;
    if (t < i) {
      for (int j = 0; j < 32; ++j) s = fmaf(s_A[i][j], s_A[j][t], s);
    }
    __syncthreads();
    if (t < i) s_A[i][t] += s;
    __syncthreads();
  }

  for (int i = 0; i < 32; ++i) {
    int idx = t + i * 256;
    int r = idx >> 8, d = idx & 255;
    s_x[r][d] = vpath[((size_t)(b * 2048 + chk * 32 + r)) * 1024 + h * 256 + d]
                * s_beta[r];
  }
  __syncthreads();

  {
    const int lane = t & 63, wvv = t >> 6;
    for (int rr = 0; rr < 8; ++rr) {
      int r = wvv * 8 + rr;
      float au[4] = {0.f, 0.f, 0.f, 0.f};
      float aw[4] = {0.f, 0.f, 0.f, 0.f};
      for (int j = 0; j <= r; ++j) {
        float tc = (j == r) ? 1.f : s_A[r][j];
#pragma unroll
        for (int dd = 0; dd < 4; ++dd) {
          au[dd] = fmaf(tc, s_x[j][lane + dd * 64], au[dd]);
          aw[dd] = fmaf(tc, s_kb[j][lane + dd * 64], aw[dd]);
        }
      }
#pragma unroll
      for (int dd = 0; dd < 4; ++dd) {
        int d = lane + dd * 64;
        // u: [slice][lg][cl][idx]
        u[(size_t)bid * 8192 +
          ((((d >> 5) << 2) + ((r >> 2) & 3)) * 32 + (d & 31)) * 8 +
          ((r >> 4) << 2) + (r & 3)] = au[dd];
        *(bf16*)((char*)wb + (size_t)bid * 16384 + r * 512 +
                 ((2 * d) ^ ((r & 15) << 4))) = (bf16)(-aw[dd]);
      }
    }
  }
}

// ---------------- K4: MFMA chunk scan. 64 blocks = 8 bh x 8 col-slices(32).
// bh = blk&7 (XCD-grouped so same-bh blocks share an XCD L2 for w/q/kT).
// 2 waves/block, 16 cols each; S cols wave-private -> 1 barrier per chunk.
// Staging via global_load_lds into double-buffered linear LDS.
__global__ __launch_bounds__(128, 1)
void k4_scan_mfma(const bf16* __restrict__ qb, const bf16* __restrict__ wbp,
                  const bf16* __restrict__ knTp, const bf16* __restrict__ attnb,
                  const float* __restrict__ u, float* __restrict__ delta) {
  __shared__ __align__(16) bf16 s_w[2][32 * 256];   // [buf] rows 512B, swizzled
  __shared__ __align__(16) bf16 s_q[2][32 * 256];
  __shared__ __align__(16) bf16 s_kT[2][256 * 32];  // [buf][d][chunk-row]
  __shared__ __align__(16) bf16 s_S[32 * 264];      // [col][264] (528B stride)
  __shared__ __align__(16) bf16 s_tT[32 * 32];      // [col][row]
  const int tid = threadIdx.x;
  const int wv = tid >> 6, l = tid & 63, lr = l & 15, lg = l >> 4;
  const int cl = wv * 16 + lr;
  const int bh = blockIdx.x & 7;
  const int slice = blockIdx.x >> 3;
  const int b = bh >> 2, h = bh & 3;
  const int chb = bh * 64;

  for (int i = tid; i < 32 * 264 / 2; i += 128) ((unsigned*)s_S)[i] = 0u;
  f32x4 S[16];
#pragma unroll
  for (int dt = 0; dt < 16; ++dt) S[dt] = (f32x4){0.f, 0.f, 0.f, 0.f};

  auto stage_chunk = [&](int ck, int bf) {
    const char* gw = (const char*)wbp  + (size_t)ck * 16384 + wv * 8192;
    const char* gq = (const char*)qb   + (size_t)ck * 16384 + wv * 8192;
    const char* gk = (const char*)knTp + (size_t)ck * 16384 + wv * 8192;
    char* dw = (char*)&s_w[bf][0]  + wv * 8192;
    char* dq = (char*)&s_q[bf][0]  + wv * 8192;
    char* dk = (char*)&s_kT[bf][0] + wv * 8192;
#pragma unroll
    for (int i = 0; i < 8; ++i) {
      GLD16(gw + i * 1024 + l * 16, dw + i * 1024);
      GLD16(gq + i * 1024 + l * 16, dq + i * 1024);
      GLD16(gk + i * 1024 + l * 16, dk + i * 1024);
    }
  };
  auto pre_ua = [&](int ck, float* uu, bf16x8& a0, bf16x8& a1) {
    const float* cu = u + (size_t)ck * 8192 + (((slice << 2) + lg) * 32 + cl) * 8;
    float4 x = *(const float4*)cu;
    float4 y = *(const float4*)(cu + 4);
    uu[0] = x.x; uu[1] = x.y; uu[2] = x.z; uu[3] = x.w;
    uu[4] = y.x; uu[5] = y.y; uu[6] = y.z; uu[7] = y.w;
    const char* cat = (const char*)attnb + (size_t)ck * 2048;
    a0 = *(const bf16x8*)(cat + l * 16);
    a1 = *(const bf16x8*)(cat + 1024 + l * 16);
  };

  float uc[8], un[8];
  bf16x8 atA0, atA1, atA0n, atA1n;
  stage_chunk(chb, 0);
  pre_ua(chb, uc, atA0, atA1);
  __syncthreads();

  for (int t = 0; t < 64; ++t) {
    const int bc = t & 1, nb = bc ^ 1;
    if (t < 63) {
      stage_chunk(chb + t + 1, nb);
      pre_ua(chb + t + 1, un, atA0n, atA1n);
    }

    // ---- phase 1: tmp = u + (-W)@S ; O1 = Q@S  (K=256, swizzled A reads)
    const char* pw = (const char*)&s_w[bc][0];
    const char* pq = (const char*)&s_q[bc][0];
    f32x4 t0 = (f32x4){uc[0], uc[1], uc[2], uc[3]};
    f32x4 t1 = (f32x4){uc[4], uc[5], uc[6], uc[7]};
    f32x4 o0 = (f32x4){0.f, 0.f, 0.f, 0.f};
    f32x4 o1 = (f32x4){0.f, 0.f, 0.f, 0.f};
#pragma unroll
    for (int kb = 0; kb < 8; ++kb) {
      const int sw = (kb * 64 + lg * 16) ^ (lr << 4);
      bf16x8 sB  = *(const bf16x8*)((const char*)s_S + cl * 528 + kb * 64 + lg * 16);
      bf16x8 aw0 = *(const bf16x8*)(pw + lr * 512 + sw);
      bf16x8 aw1 = *(const bf16x8*)(pw + (16 + lr) * 512 + sw);
      bf16x8 aq0 = *(const bf16x8*)(pq + lr * 512 + sw);
      bf16x8 aq1 = *(const bf16x8*)(pq + (16 + lr) * 512 + sw);
      t0 = MFMA16(aw0, sB, t0);
      t1 = MFMA16(aw1, sB, t1);
      o0 = MFMA16(aq0, sB, o0);
      o1 = MFMA16(aq1, sB, o1);
    }
    // tmp^T to LDS (wave-private cols)
    *(unsigned*)((char*)s_tT + cl * 64 + lg * 8)          = pack2(t0[0], t0[1]);
    *(unsigned*)((char*)s_tT + cl * 64 + lg * 8 + 4)      = pack2(t0[2], t0[3]);
    *(unsigned*)((char*)s_tT + cl * 64 + 32 + lg * 8)     = pack2(t1[0], t1[1]);
    *(unsigned*)((char*)s_tT + cl * 64 + 32 + lg * 8 + 4) = pack2(t1[2], t1[3]);

    // ---- phase 2: O = O1 + attn @ tmp (C-init straight from o-regs)
    bf16x8 tB = *(const bf16x8*)((const char*)s_tT + cl * 64 + lg * 16);
    o0 = MFMA16(atA0, tB, o0);
    o1 = MFMA16(atA1, tB, o1);
#pragma unroll
    for (int j = 0; j < 4; ++j) {
      int r0 = t * 32 + lg * 4 + j;
      size_t col = h * 256 + slice * 32 + cl;
      delta[((size_t)(b * 2048 + r0)) * 1024 + col] = o0[j];
      delta[((size_t)(b * 2048 + r0 + 16)) * 1024 + col] = o1[j];
    }

    // ---- phase 3: S += K^T @ tmp ; refresh bf16 shadow (wave-private cols)
    const char* pk = (const char*)&s_kT[bc][0];
#pragma unroll
    for (int dt = 0; dt < 16; ++dt) {
      bf16x8 aK = *(const bf16x8*)(pk + (dt * 16 + lr) * 64 + lg * 16);
      S[dt] = MFMA16(aK, tB, S[dt]);
    }
#pragma unroll
    for (int dt = 0; dt < 16; ++dt) {
      *(unsigned*)((char*)s_S + cl * 528 + dt * 32 + lg * 8)     = pack2(S[dt][0], S[dt][1]);
      *(unsigned*)((char*)s_S + cl * 528 + dt * 32 + lg * 8 + 4) = pack2(S[dt][2], S[dt][3]);
    }

    __syncthreads();   // drains staging vmcnt + publishes both waves' halves
    if (t < 63) {
#pragma unroll
      for (int j = 0; j < 8; ++j) uc[j] = un[j];
      atA0 = atA0n; atA1 = atA1n;
    }
  }
}

// ------------------------------------------------- K5: FIR short(3)/long(63)
__global__ __launch_bounds__(256)
void k5_fir(const float* __restrict__ vpath, const float* __restrict__ wsrt,
            const float* __restrict__ wlng, float* __restrict__ shortp,
            float* __restrict__ longp) {
  __shared__ float s_v[126][128];
  __shared__ float s_wl[63][128];
  __shared__ float s_ws[3][128];
  const int c0 = blockIdx.x * 128;
  const int l0 = blockIdx.y * 64;
  const int b  = blockIdx.z;
  const int t  = threadIdx.x;

  for (int i = 0; i < 63; ++i) {
    int idx = t + i * 256;
    int rr = idx >> 7, cc = idx & 127;
    int gl = l0 - 62 + rr;
    s_v[rr][cc] = (gl >= 0)
        ? vpath[((size_t)(b * 2048 + gl)) * 1024 + c0 + cc] : 0.f;
  }
  for (int i = t; i < 63 * 128; i += 256) {
    int cc = i / 63, j = i % 63;
    s_wl[j][cc] = wlng[(size_t)(c0 + cc) * 63 + j];
  }
  for (int i = t; i < 3 * 128; i += 256) {
    int cc = i / 3, j = i % 3;
    s_ws[j][cc] = wsrt[(size_t)(c0 + cc) * 3 + j];
  }
  __syncthreads();

  const int cc = t & 127, lh = t >> 7;
  for (int m = 0; m < 32; ++m) {
    int ll = lh * 32 + m;
    float accL = 0.f;
    for (int j = 0; j < 63; ++j)
      accL = fmaf(s_v[ll + j][cc], s_wl[j][cc], accL);
    float accS = 0.f;
#pragma unroll
    for (int j = 0; j < 3; ++j)
      accS = fmaf(s_v[ll + 60 + j][cc], s_ws[j][cc], accS);
    size_t o = ((size_t)(b * 2048 + l0 + ll)) * 1024 + c0 + cc;
    longp[o] = accL;
    shortp[o] = accS;
  }
}

// --------------------- K6: path stats + gate_in build (bf16, padded to 1088)
__global__ __launch_bounds__(256)
void k6_gatein(const float* __restrict__ hs, const float* __restrict__ shortp,
               const float* __restrict__ longp, const float* __restrict__ delta,
               const float* __restrict__ vpath, bf16* __restrict__ gate_in) {
  const size_t row = blockIdx.x;
  const int t = threadIdx.x, wv = t >> 6, lane = t & 63;
  bf16* gr = gate_in + row * 1088;
#pragma unroll
  for (int i = 0; i < 2; ++i) {
    int c2 = (t + i * 256) * 2;
    float a = hs[row * 1024 + c2];
    float b = hs[row * 1024 + c2 + 1];
    *(unsigned*)(gr + c2) = pack2(a, b);
  }
  if (t < 16) *(unsigned*)(gr + 1056 + t * 2) = 0u;
  const float* paths[4] = {shortp, longp, delta, vpath};
#pragma unroll
  for (int p = 0; p < 4; ++p) {
    float s = 0.f, sq = 0.f;
#pragma unroll
    for (int i = 0; i < 4; ++i) {
      int c = wv * 256 + lane + i * 64;
      float x = paths[p][row * 1024 + c];
      s += x; sq += x * x;
    }
#pragma unroll
    for (int off = 32; off; off >>= 1) {
      s += __shfl_xor(s, off);
      sq += __shfl_xor(sq, off);
    }
    if (lane == 0) {
      float mean = s * (1.f / 256.f);
      float var = sq * (1.f / 256.f) - mean * mean;
      *(unsigned*)(gr + 1024 + p * 8 + wv * 2) = pack2(mean, var);
    }
  }
}

// ------------------------------- K8: logits GEMV + softmax + floor + renorm
__global__ __launch_bounds__(256)
void k8_probs(const float* __restrict__ hmid, const float* __restrict__ w2,
              const float* __restrict__ bias, const float* __restrict__ log_temp,
              const float* __restrict__ floor_raw, float* __restrict__ probs) {
  const int t = threadIdx.x, wv = t >> 6, lane = t & 63;
  const size_t row = (size_t)blockIdx.x * 4 + wv;
  float acc[16];
#pragma unroll
  for (int o = 0; o < 16; ++o) acc[o] = 0.f;
  for (int it = 0; it < 32; ++it) {
    int c = lane + it * 64;
    float x = hmid[row * 2048 + c];
#pragma unroll
    for (int o = 0; o < 16; ++o)
      acc[o] = fmaf(x, w2[o * 2048 + c], acc[o]);
  }
#pragma unroll
  for (int off = 32; off; off >>= 1)
#pragma unroll
    for (int o = 0; o < 16; ++o) acc[o] += __shfl_xor(acc[o], off);

  if (lane == 0) {
    for (int h2 = 0; h2 < 4; ++h2) {
      float temp = log1pf(expf(log_temp[h2])) + 1e-4f;
      float li[4], m = -1e30f;
#pragma unroll
      for (int p = 0; p < 4; ++p) {
        li[p] = (acc[h2 * 4 + p] + bias[h2 * 4 + p]) / temp;
        m = fmaxf(m, li[p]);
      }
      float sum = 0.f;
#pragma unroll
      for (int p = 0; p < 4; ++p) { li[p] = expf(li[p] - m); sum += li[p]; }
      float pr[4], s2 = 0.f;
#pragma unroll
      for (int p = 0; p < 4; ++p) {
        float fv = 0.05f / (1.f + expf(-floor_raw[h2 * 4 + p]));
        pr[p] = fmaxf(li[p] / sum, fv);
        s2 += pr[p];
      }
#pragma unroll
      for (int p = 0; p < 4; ++p)
        probs[row * 16 + h2 * 4 + p] = pr[p] / s2;
    }
  }
}

// ------------------------------- K9: mix paths + RMS-norm (bf16 out for GEMM)
__global__ __launch_bounds__(256)
void k9_mix(const float* __restrict__ shortp, const float* __restrict__ longp,
            const float* __restrict__ delta, const float* __restrict__ vpath,
            const float* __restrict__ probs, const float* __restrict__ onorm,
            bf16* __restrict__ mixed) {
  const size_t row = blockIdx.x;
  const int t = threadIdx.x, wv = t >> 6, lane = t & 63;
  float p0 = probs[row * 16 + wv * 4 + 0];
  float p1 = probs[row * 16 + wv * 4 + 1];
  float p2 = probs[row * 16 + wv * 4 + 2];
  float p3 = probs[row * 16 + wv * 4 + 3];
  float m[4];
  float sq = 0.f;
#pragma unroll
  for (int i = 0; i < 4; ++i) {
    int c = wv * 256 + lane + i * 64;
    size_t o = row * 1024 + c;
    float x = p0 * shortp[o] + p1 * longp[o] + p2 * delta[o] + p3 * vpath[o];
    m[i] = x;
    sq += x * x;
  }
#pragma unroll
  for (int off = 32; off; off >>= 1) sq += __shfl_xor(sq, off);
  float sc = rsqrtf(sq * (1.f / 256.f) + 1e-5f);
#pragma unroll
  for (int i = 0; i < 4; ++i) {
    int d = lane + i * 64;
    mixed[row * 1024 + wv * 256 + d] = (bf16)(m[i] * sc * onorm[d]);
  }
}

// ---------------------------------------------------------------- launcher
extern "C" void kernel_launch(void* const* d_in, const int* in_sizes, int n_in,
                              void* d_out, int out_size, void* d_ws,
                              size_t ws_size, hipStream_t stream) {
  const float* hs   = (const float*)d_in[0];
  const float* Wq   = (const float*)d_in[1];
  const float* Wk   = (const float*)d_in[2];
  const float* Wv   = (const float*)d_in[3];
  const float* Wb   = (const float*)d_in[4];
  const float* qw   = (const float*)d_in[5];
  const float* kw   = (const float*)d_in[6];
  const float* vw   = (const float*)d_in[7];
  const float* fsw  = (const float*)d_in[8];
  const float* flw  = (const float*)d_in[9];
  const float* gw1  = (const float*)d_in[10];
  const float* gb1  = (const float*)d_in[11];
  const float* gw2  = (const float*)d_in[12];
  const float* ltmp = (const float*)d_in[13];
  const float* bbias= (const float*)d_in[14];
  const float* frw  = (const float*)d_in[15];
  const float* onw  = (const float*)d_in[16];
  const float* Wo   = (const float*)d_in[17];
  float* out = (float*)d_out;

  float* f = (float*)d_ws;
  const size_t BLD = 4194304;  // B*L*D
  float* qlin    = f + 0 * BLD;
  float* klin    = f + 1 * BLD;
  float* vlin    = f + 2 * BLD;
  float* qn      = f + 3 * BLD;
  float* kn      = f + 4 * BLD;
  float* vpath   = f + 5 * BLD;
  float* shortp  = f + 6 * BLD;
  float* longp   = f + 7 * BLD;
  float* gate_f  = f + 8 * BLD;
  float* probs   = gate_f + 4325376;
  float* beta    = probs + 65536;

  bf16* hsb  = (bf16*)gate_f;
  bf16* ginb = (bf16*)gate_f;
  bf16* gw1b = (bf16*)gate_f + 4456448;
  bf16* wob  = (bf16*)gate_f + 4456448 + 2228224;
  bf16* wqb  = (bf16*)kn;
  bf16* wkb  = wqb + 1048576;
  bf16* wvb  = wkb + 1048576;

  float* u_f32 = qlin;
  bf16*  qbb   = (bf16*)shortp;
  bf16*  wbb   = qbb + 512 * 8192;
  bf16*  knTb  = (bf16*)longp;
  bf16*  attnb = knTb + 512 * 8192;
  float* delta = vlin;
  float* hmid  = qn;
  bf16*  mixb  = (bf16*)klin;

  kcvt<<<2048, 256, 0, stream>>>(hs, hsb, 4194304);
  kcvt<<<512, 256, 0, stream>>>(Wq, wqb, 1048576);
  kcvt<<<512, 256, 0, stream>>>(Wk, wkb, 1048576);
  kcvt<<<512, 256, 0, stream>>>(Wv, wvb, 1048576);
  kcvt<<<512, 256, 0, stream>>>(Wo, wob, 1048576);
  kcvt_pad<<<2048, 256, 0, stream>>>(gw1, gw1b, 1056, 1088);

  gemm_bf16<0><<<dim3(8, 32), 256, 0, stream>>>(hsb, wqb, nullptr, qlin, 4096, 1024, 1024);
  gemm_bf16<0><<<dim3(8, 32), 256, 0, stream>>>(hsb, wkb, nullptr, klin, 4096, 1024, 1024);
  gemm_bf16<0><<<dim3(8, 32), 256, 0, stream>>>(hsb, wvb, nullptr, vlin, 4096, 1024, 1024);

  k2_conv<<<4096, 256, 0, stream>>>(hs, qlin, klin, vlin, qw, kw, vw, Wb,
                                    qn, kn, vpath, beta);
  k3_chunk<<<512, 256, 0, stream>>>(qn, kn, vpath, beta, u_f32, qbb, wbb,
                                    knTb, attnb);
  k4_scan_mfma<<<64, 128, 0, stream>>>(qbb, wbb, knTb, attnb, u_f32, delta);
  k5_fir<<<dim3(8, 32, 2), 256, 0, stream>>>(vpath, fsw, flw, shortp, longp);
  k6_gatein<<<4096, 256, 0, stream>>>(hs, shortp, longp, delta, vpath, ginb);
  gemm_bf16<1><<<dim3(16, 32), 256, 0, stream>>>(ginb, gw1b, gb1, hmid, 4096, 2048, 1088);
  k8_probs<<<1024, 256, 0, stream>>>(hmid, gw2, bbias, ltmp, frw, probs);
  k9_mix<<<4096, 256, 0, stream>>>(shortp, longp, delta, vpath, probs, onw, mixb);
  gemm_bf16<0><<<dim3(8, 32), 256, 0, stream>>>(mixb, wob, nullptr, out, 4096, 1024, 1024);
}

// Round 5
// 638.165 us; speedup vs baseline: 5.1945x; 1.1004x over previous
//
#include <hip/hip_runtime.h>
#include <cmath>

typedef __bf16 bf16;
typedef __bf16 bf16x8 __attribute__((ext_vector_type(8)));
typedef float  f32x4  __attribute__((ext_vector_type(4)));

#define MFMA16(a, b, c) __builtin_amdgcn_mfma_f32_16x16x32_bf16(a, b, c, 0, 0, 0)

#define GLD16(gsrc, ldst)                                                     \
  __builtin_amdgcn_global_load_lds(                                           \
      (const __attribute__((address_space(1))) unsigned*)(gsrc),              \
      (__attribute__((address_space(3))) unsigned*)(ldst), 16, 0, 0)

static __device__ __forceinline__ unsigned pack2(float a, float b) {
  unsigned short ua = __builtin_bit_cast(unsigned short, (__bf16)a);
  unsigned short ub = __builtin_bit_cast(unsigned short, (__bf16)b);
  return (unsigned)ua | ((unsigned)ub << 16);
}

// ------------------------------------------------------- f32 -> bf16 convert
__global__ __launch_bounds__(256)
void kcvt(const float* __restrict__ in, bf16* __restrict__ outp, int n) {
  int i = (blockIdx.x * 256 + threadIdx.x) * 8;
  if (i < n) {
    float4 a = *(const float4*)(in + i);
    float4 b = *(const float4*)(in + i + 4);
    uint4 v = make_uint4(pack2(a.x, a.y), pack2(a.z, a.w),
                         pack2(b.x, b.y), pack2(b.z, b.w));
    *(uint4*)(outp + i) = v;
  }
}

__global__ __launch_bounds__(256)
void kcvt_pad(const float* __restrict__ in, bf16* __restrict__ outp,
              int cin, int cout) {
  int r = blockIdx.x, c = threadIdx.x * 8;
  if (c >= cout) return;
  uint4 v = make_uint4(0u, 0u, 0u, 0u);
  if (c < cin) {
    float4 a = *(const float4*)(in + (size_t)r * cin + c);
    float4 b = *(const float4*)(in + (size_t)r * cin + c + 4);
    v = make_uint4(pack2(a.x, a.y), pack2(a.z, a.w),
                   pack2(b.x, b.y), pack2(b.z, b.w));
  }
  *(uint4*)(outp + (size_t)r * cout + c) = v;
}

// ---------------------------------------------------------- GEMM (bf16 MFMA)
template<int EPI>   // 0 = none, 1 = gelu(x + bias[n]) exact
__global__ __launch_bounds__(256)
void gemm_bf16(const bf16* __restrict__ A, const bf16* __restrict__ Bt,
               const float* __restrict__ bias, float* __restrict__ C,
               int M, int N, int K) {
  __shared__ __align__(16) bf16 sA[2][128 * 64];
  __shared__ __align__(16) bf16 sB[2][128 * 64];
  const int t = threadIdx.x;
  const int w = t >> 6, l = t & 63, lr = l & 15, lg = l >> 4;
  const int m0 = blockIdx.y * 128, n0 = blockIdx.x * 128;
  const int wm = (w & 1) * 64, wn = (w >> 1) * 64;
  const int w32 = w * 32;
  const int nst = K >> 6;

  f32x4 acc[4][4];
#pragma unroll
  for (int mt = 0; mt < 4; ++mt)
#pragma unroll
    for (int nt = 0; nt < 4; ++nt) acc[mt][nt] = (f32x4){0.f, 0.f, 0.f, 0.f};

  auto stage = [&](int s, int bf) {
    const char* ga = (const char*)A + ((size_t)(m0 + w32) * K + (size_t)s * 64) * 2;
    const char* gb = (const char*)Bt + ((size_t)(n0 + w32) * K + (size_t)s * 64) * 2;
    char* da = (char*)&sA[bf][0] + w32 * 128;
    char* db = (char*)&sB[bf][0] + w32 * 128;
    const size_t rs = (size_t)K * 2;
#pragma unroll
    for (int i = 0; i < 4; ++i) {
      GLD16(ga + (i * 8 + (l >> 3)) * rs + (l & 7) * 16, da + i * 1024);
      GLD16(gb + (i * 8 + (l >> 3)) * rs + (l & 7) * 16, db + i * 1024);
    }
  };

  stage(0, 0);
  __syncthreads();
  for (int s = 0; s < nst; ++s) {
    const int bf = s & 1;
    if (s + 1 < nst) stage(s + 1, bf ^ 1);
    const char* pa = (const char*)&sA[bf][0];
    const char* pb = (const char*)&sB[bf][0];
#pragma unroll
    for (int kb = 0; kb < 2; ++kb) {
      bf16x8 af[4], bfg[4];
#pragma unroll
      for (int mt = 0; mt < 4; ++mt)
        af[mt] = *(const bf16x8*)(pa + (wm + mt * 16 + lr) * 128 + kb * 64 + lg * 16);
#pragma unroll
      for (int nt = 0; nt < 4; ++nt)
        bfg[nt] = *(const bf16x8*)(pb + (wn + nt * 16 + lr) * 128 + kb * 64 + lg * 16);
#pragma unroll
      for (int mt = 0; mt < 4; ++mt)
#pragma unroll
        for (int nt = 0; nt < 4; ++nt)
          acc[mt][nt] = MFMA16(af[mt], bfg[nt], acc[mt][nt]);
    }
    __syncthreads();
  }

#pragma unroll
  for (int mt = 0; mt < 4; ++mt)
#pragma unroll
    for (int nt = 0; nt < 4; ++nt) {
      int nn = n0 + wn + nt * 16 + lr;
#pragma unroll
      for (int j = 0; j < 4; ++j) {
        int m = m0 + wm + mt * 16 + lg * 4 + j;
        float x = acc[mt][nt][j];
        if (EPI == 1) {
          x += bias[nn];
          x = 0.5f * x * (1.f + erff(x * 0.70710678118654752f));
        }
        C[(size_t)m * N + nn] = x;
      }
    }
}

// -------------------------------------------- K2: conv(K=4)+SiLU, l2norm, beta
__global__ __launch_bounds__(256)
void k2_conv(const float* __restrict__ hs,
             const float* __restrict__ qlin, const float* __restrict__ klin,
             const float* __restrict__ vlin,
             const float* __restrict__ qw, const float* __restrict__ kw,
             const float* __restrict__ vw, const float* __restrict__ Wb,
             float* __restrict__ qn, float* __restrict__ kn,
             float* __restrict__ vpath, float* __restrict__ beta) {
  const int bid  = blockIdx.x;
  const int b    = bid >> 11;
  const int l    = bid & 2047;
  const int t    = threadIdx.x;
  const int wv   = t >> 6;
  const int lane = t & 63;
  const size_t row = (size_t)bid;

  __shared__ float s_red[4][4];

  float pb[4] = {0.f, 0.f, 0.f, 0.f};
#pragma unroll
  for (int i = 0; i < 4; ++i) {
    int c = wv * 256 + lane + i * 64;
    float x = hs[row * 1024 + c];
    pb[0] += x * Wb[0 * 1024 + c];
    pb[1] += x * Wb[1 * 1024 + c];
    pb[2] += x * Wb[2 * 1024 + c];
    pb[3] += x * Wb[3 * 1024 + c];
  }
#pragma unroll
  for (int off = 32; off; off >>= 1) {
    pb[0] += __shfl_xor(pb[0], off);
    pb[1] += __shfl_xor(pb[1], off);
    pb[2] += __shfl_xor(pb[2], off);
    pb[3] += __shfl_xor(pb[3], off);
  }
  if (lane == 0) {
    s_red[0][wv] = pb[0]; s_red[1][wv] = pb[1];
    s_red[2][wv] = pb[2]; s_red[3][wv] = pb[3];
  }
  __syncthreads();

  float xq[4], xk[4], xv[4];
#pragma unroll
  for (int i = 0; i < 4; ++i) {
    int c = wv * 256 + lane + i * 64;
    float aq = 0.f, ak = 0.f, av = 0.f;
#pragma unroll
    for (int j = 0; j < 4; ++j) {
      int ls = l - 3 + j;
      if (ls >= 0) {
        size_t ro = (size_t)(b * 2048 + ls) * 1024 + c;
        aq = fmaf(qlin[ro], qw[c * 4 + j], aq);
        ak = fmaf(klin[ro], kw[c * 4 + j], ak);
        av = fmaf(vlin[ro], vw[c * 4 + j], av);
      }
    }
    xq[i] = aq / (1.f + expf(-aq));
    xk[i] = ak / (1.f + expf(-ak));
    xv[i] = av / (1.f + expf(-av));
  }

  float sq = 0.f, sk = 0.f;
#pragma unroll
  for (int i = 0; i < 4; ++i) { sq += xq[i] * xq[i]; sk += xk[i] * xk[i]; }
#pragma unroll
  for (int off = 32; off; off >>= 1) {
    sq += __shfl_xor(sq, off);
    sk += __shfl_xor(sk, off);
  }
  float rq = rsqrtf(sq + 1e-6f);
  float rk = rsqrtf(sk + 1e-6f);
  float bsum = s_red[wv][0] + s_red[wv][1] + s_red[wv][2] + s_red[wv][3];
  float betaw = 1.f / (1.f + expf(-bsum));
  if (lane == 0) beta[(size_t)bid * 4 + wv] = betaw;

  const int chk = l >> 5, pos = l & 31;
  size_t cbase = ((size_t)((b * 4 + wv) * 64 + chk) * 32 + pos) * 256;
#pragma unroll
  for (int i = 0; i < 4; ++i) {
    int d = lane + i * 64;
    qn[cbase + d] = xq[i] * rq;
    kn[cbase + d] = xk[i] * rk;
    vpath[row * 1024 + wv * 256 + d] = xv[i];
  }
}

// -------------------- K3: per-chunk A, (I+A)^-1 transform; exports MFMA frags
// qb/wb: 32x256 bf16, LDS-linear w/ byte^=((row&15)<<4) swizzle (512B rows)
// knTp:  [chunk][256][40] bf16 (transposed, PADDED 80B rows, pad uninit)
// attnb: [chunk][2][64][8] bf16 A-fragment order
// u:     [chunk][slice8][lg4][cl32][8] f32
__global__ __launch_bounds__(256)
void k3_chunk(const float* __restrict__ qn, const float* __restrict__ kn,
              const float* __restrict__ vpath, const float* __restrict__ beta,
              float* __restrict__ u, bf16* __restrict__ qb,
              bf16* __restrict__ wb, bf16* __restrict__ knTp,
              bf16* __restrict__ attnb) {
  __shared__ float s_kn[32][257];
  __shared__ float s_kb[32][257];
  __shared__ float s_x[32][257];
  __shared__ float s_A[32][33];
  __shared__ float s_beta[32];
  const int bid = blockIdx.x;
  const int bh = bid >> 6, chk = bid & 63;
  const int b = bh >> 2, h = bh & 3;
  const int t = threadIdx.x;
  const size_t base = (size_t)bid * 8192;

  if (t < 32)
    s_beta[t] = beta[((size_t)(b * 2048 + chk * 32 + t)) * 4 + h];
  for (int i = 0; i < 32; ++i) {
    int idx = t + i * 256;
    int r = idx >> 8, d = idx & 255;
    s_kn[r][d] = kn[base + idx];
    s_x[r][d]  = qn[base + idx];
  }
  __syncthreads();
  for (int i = 0; i < 32; ++i) {
    int idx = t + i * 256;
    int r = idx >> 8, d = idx & 255;
    s_kb[r][d] = s_kn[r][d] * s_beta[r];
  }
  __syncthreads();

  {
    const int r = t & 31, cg = t >> 5;
    float accA[4] = {0.f, 0.f, 0.f, 0.f};
    float accT[4] = {0.f, 0.f, 0.f, 0.f};
    for (int d = 0; d < 256; ++d) {
      float kbr = s_kb[r][d];
      float qr  = s_x[r][d];
#pragma unroll
      for (int q = 0; q < 4; ++q) {
        float knc = s_kn[cg * 4 + q][d];
        accA[q] = fmaf(kbr, knc, accA[q]);
        accT[q] = fmaf(qr,  knc, accT[q]);
      }
    }
    float at[4];
#pragma unroll
    for (int q = 0; q < 4; ++q) {
      int c = cg * 4 + q;
      s_A[r][c] = (r > c) ? -accA[q] : 0.f;
      at[q] = (r >= c) ? accT[q] : 0.f;
    }
    uint2 pk2;
    pk2.x = pack2(at[0], at[1]);
    pk2.y = pack2(at[2], at[3]);
    *(uint2*)((char*)attnb + (size_t)bid * 2048 +
              ((r >> 4) * 64 + (cg >> 1) * 16 + (r & 15)) * 16 + (cg & 1) * 8) = pk2;
  }

  for (int i = 0; i < 32; ++i) {
    int idx = t + i * 256;
    int r = idx >> 8, d = idx & 255;
    *(bf16*)((char*)qb + (size_t)bid * 16384 + r * 512 +
             ((2 * d) ^ ((r & 15) << 4))) = (bf16)s_x[r][d];
  }
  for (int i = 0; i < 32; ++i) {
    int d = (i << 3) + (t >> 5);
    int r = t & 31;
    knTp[(size_t)bid * 10240 + d * 40 + r] = (bf16)s_kn[r][d];
  }
  __syncthreads();

  for (int i = 1; i < 32; ++i) {
    float s = 0.f;
    if (t < i) {
      for (int j = 0; j < 32; ++j) s = fmaf(s_A[i][j], s_A[j][t], s);
    }
    __syncthreads();
    if (t < i) s_A[i][t] += s;
    __syncthreads();
  }

  for (int i = 0; i < 32; ++i) {
    int idx = t + i * 256;
    int r = idx >> 8, d = idx & 255;
    s_x[r][d] = vpath[((size_t)(b * 2048 + chk * 32 + r)) * 1024 + h * 256 + d]
                * s_beta[r];
  }
  __syncthreads();

  {
    const int lane = t & 63, wvv = t >> 6;
    for (int rr = 0; rr < 8; ++rr) {
      int r = wvv * 8 + rr;
      float au[4] = {0.f, 0.f, 0.f, 0.f};
      float aw[4] = {0.f, 0.f, 0.f, 0.f};
      for (int j = 0; j <= r; ++j) {
        float tc = (j == r) ? 1.f : s_A[r][j];
#pragma unroll
        for (int dd = 0; dd < 4; ++dd) {
          au[dd] = fmaf(tc, s_x[j][lane + dd * 64], au[dd]);
          aw[dd] = fmaf(tc, s_kb[j][lane + dd * 64], aw[dd]);
        }
      }
#pragma unroll
      for (int dd = 0; dd < 4; ++dd) {
        int d = lane + dd * 64;
        u[(size_t)bid * 8192 +
          ((((d >> 5) << 2) + ((r >> 2) & 3)) * 32 + (d & 31)) * 8 +
          ((r >> 4) << 2) + (r & 3)] = au[dd];
        *(bf16*)((char*)wb + (size_t)bid * 16384 + r * 512 +
                 ((2 * d) ^ ((r & 15) << 4))) = (bf16)(-aw[dd]);
      }
    }
  }
}

// ---------------- K4: MFMA chunk scan. 64 blocks = 8 bh x 8 col-slices(32).
// 2 waves/block, 16 cols each; kT/tT rows padded to 80B (2-way banks);
// manual 2-deep ds_read pipelining in phase1/phase3.
__global__ __launch_bounds__(128, 1)
void k4_scan_mfma(const bf16* __restrict__ qb, const bf16* __restrict__ wbp,
                  const bf16* __restrict__ knTp, const bf16* __restrict__ attnb,
                  const float* __restrict__ u, float* __restrict__ delta) {
  __shared__ __align__(16) bf16 s_w[2][32 * 256];   // 512B rows, swizzled
  __shared__ __align__(16) bf16 s_q[2][32 * 256];
  __shared__ __align__(16) bf16 s_kT[2][256 * 40];  // [buf][d][40] 80B rows
  __shared__ __align__(16) bf16 s_S[32 * 264];      // [col][264] 528B stride
  __shared__ __align__(16) bf16 s_tT[32 * 40];      // [col][40] 80B stride
  const int tid = threadIdx.x;
  const int wv = tid >> 6, l = tid & 63, lr = l & 15, lg = l >> 4;
  const int cl = wv * 16 + lr;
  const int bh = blockIdx.x & 7;
  const int slice = blockIdx.x >> 3;
  const int b = bh >> 2, h = bh & 3;
  const int chb = bh * 64;

  for (int i = tid; i < 32 * 264 / 2; i += 128) ((unsigned*)s_S)[i] = 0u;
  f32x4 S[16];
#pragma unroll
  for (int dt = 0; dt < 16; ++dt) S[dt] = (f32x4){0.f, 0.f, 0.f, 0.f};

  auto stage_chunk = [&](int ck, int bf) {
    const char* gw = (const char*)wbp  + (size_t)ck * 16384 + wv * 8192;
    const char* gq = (const char*)qb   + (size_t)ck * 16384 + wv * 8192;
    const char* gk = (const char*)knTp + (size_t)ck * 20480 + wv * 10240;
    char* dw = (char*)&s_w[bf][0]  + wv * 8192;
    char* dq = (char*)&s_q[bf][0]  + wv * 8192;
    char* dk = (char*)&s_kT[bf][0] + wv * 10240;
#pragma unroll
    for (int i = 0; i < 8; ++i) {
      GLD16(gw + i * 1024 + l * 16, dw + i * 1024);
      GLD16(gq + i * 1024 + l * 16, dq + i * 1024);
    }
#pragma unroll
    for (int i = 0; i < 10; ++i)
      GLD16(gk + i * 1024 + l * 16, dk + i * 1024);
  };
  auto pre_ua = [&](int ck, float* uu, bf16x8& a0, bf16x8& a1) {
    const float* cu = u + (size_t)ck * 8192 + (((slice << 2) + lg) * 32 + cl) * 8;
    float4 x = *(const float4*)cu;
    float4 y = *(const float4*)(cu + 4);
    uu[0] = x.x; uu[1] = x.y; uu[2] = x.z; uu[3] = x.w;
    uu[4] = y.x; uu[5] = y.y; uu[6] = y.z; uu[7] = y.w;
    const char* cat = (const char*)attnb + (size_t)ck * 2048;
    a0 = *(const bf16x8*)(cat + l * 16);
    a1 = *(const bf16x8*)(cat + 1024 + l * 16);
  };

  float uc[8], un[8];
  bf16x8 atA0, atA1, atA0n, atA1n;
  stage_chunk(chb, 0);
  pre_ua(chb, uc, atA0, atA1);
  __syncthreads();

  for (int t = 0; t < 64; ++t) {
    const int bc = t & 1, nb = bc ^ 1;
    if (t < 63) {
      stage_chunk(chb + t + 1, nb);
      pre_ua(chb + t + 1, un, atA0n, atA1n);
    }

    // ---- phase 1: tmp = u + (-W)@S ; O1 = Q@S  (2-deep pipelined reads)
    const char* pw = (const char*)&s_w[bc][0];
    const char* pq = (const char*)&s_q[bc][0];
    f32x4 t0 = (f32x4){uc[0], uc[1], uc[2], uc[3]};
    f32x4 t1 = (f32x4){uc[4], uc[5], uc[6], uc[7]};
    f32x4 o0 = (f32x4){0.f, 0.f, 0.f, 0.f};
    f32x4 o1 = (f32x4){0.f, 0.f, 0.f, 0.f};
    bf16x8 sBr[2], awA[2], awB[2], aqA[2], aqB[2];
#define LOADG(kb, bi)                                                          \
    {                                                                          \
      const int sw_ = ((kb) * 64 + lg * 16) ^ (lr << 4);                       \
      sBr[bi] = *(const bf16x8*)((const char*)s_S + cl * 528 + (kb) * 64 + lg * 16); \
      awA[bi] = *(const bf16x8*)(pw + lr * 512 + sw_);                         \
      awB[bi] = *(const bf16x8*)(pw + (16 + lr) * 512 + sw_);                  \
      aqA[bi] = *(const bf16x8*)(pq + lr * 512 + sw_);                         \
      aqB[bi] = *(const bf16x8*)(pq + (16 + lr) * 512 + sw_);                  \
    }
    LOADG(0, 0)
#pragma unroll
    for (int kb = 0; kb < 8; ++kb) {
      const int cur = kb & 1;
      if (kb < 7) LOADG(kb + 1, cur ^ 1)
      t0 = MFMA16(awA[cur], sBr[cur], t0);
      t1 = MFMA16(awB[cur], sBr[cur], t1);
      o0 = MFMA16(aqA[cur], sBr[cur], o0);
      o1 = MFMA16(aqB[cur], sBr[cur], o1);
    }
#undef LOADG
    // tmp^T to LDS (80B rows; wave-private cols)
    *(unsigned*)((char*)s_tT + cl * 80 + lg * 8)          = pack2(t0[0], t0[1]);
    *(unsigned*)((char*)s_tT + cl * 80 + lg * 8 + 4)      = pack2(t0[2], t0[3]);
    *(unsigned*)((char*)s_tT + cl * 80 + 32 + lg * 8)     = pack2(t1[0], t1[1]);
    *(unsigned*)((char*)s_tT + cl * 80 + 32 + lg * 8 + 4) = pack2(t1[2], t1[3]);

    // ---- phase 2: O = O1 + attn @ tmp
    bf16x8 tB = *(const bf16x8*)((const char*)s_tT + cl * 80 + lg * 16);
    o0 = MFMA16(atA0, tB, o0);
    o1 = MFMA16(atA1, tB, o1);
#pragma unroll
    for (int j = 0; j < 4; ++j) {
      int r0 = t * 32 + lg * 4 + j;
      size_t col = h * 256 + slice * 32 + cl;
      delta[((size_t)(b * 2048 + r0)) * 1024 + col] = o0[j];
      delta[((size_t)(b * 2048 + r0 + 16)) * 1024 + col] = o1[j];
    }

    // ---- phase 3: S += K^T @ tmp (2-deep kT prefetch, 80B rows)
    const char* pk = (const char*)&s_kT[bc][0];
    bf16x8 kf[2];
    kf[0] = *(const bf16x8*)(pk + lr * 80 + lg * 16);
#pragma unroll
    for (int dt = 0; dt < 16; ++dt) {
      const int cur = dt & 1;
      if (dt < 15)
        kf[cur ^ 1] = *(const bf16x8*)(pk + ((dt + 1) * 16 + lr) * 80 + lg * 16);
      S[dt] = MFMA16(kf[cur], tB, S[dt]);
    }
#pragma unroll
    for (int dt = 0; dt < 16; ++dt) {
      *(unsigned*)((char*)s_S + cl * 528 + dt * 32 + lg * 8)     = pack2(S[dt][0], S[dt][1]);
      *(unsigned*)((char*)s_S + cl * 528 + dt * 32 + lg * 8 + 4) = pack2(S[dt][2], S[dt][3]);
    }

    __syncthreads();
    if (t < 63) {
#pragma unroll
      for (int j = 0; j < 8; ++j) uc[j] = un[j];
      atA0 = atA0n; atA1 = atA1n;
    }
  }
}

// ------------------- K5: FIR short(3)/long(63), taps in registers, v in LDS
__global__ __launch_bounds__(256)
void k5_fir(const float* __restrict__ vpath, const float* __restrict__ wsrt,
            const float* __restrict__ wlng, float* __restrict__ shortp,
            float* __restrict__ longp) {
  __shared__ float s_v[126][128];
  const int c0 = blockIdx.x * 128;
  const int l0 = blockIdx.y * 64;
  const int b  = blockIdx.z;
  const int t  = threadIdx.x;

  for (int i = 0; i < 63; ++i) {
    int idx = t + i * 256;
    int rr = idx >> 7, cc2 = idx & 127;
    int gl = l0 - 62 + rr;
    s_v[rr][cc2] = (gl >= 0)
        ? vpath[((size_t)(b * 2048 + gl)) * 1024 + c0 + cc2] : 0.f;
  }

  const int cc = t & 127, lh = t >> 7;
  float wl[63];
#pragma unroll
  for (int j = 0; j < 63; ++j)
    wl[j] = wlng[(size_t)(c0 + cc) * 63 + j];
  float ws0 = wsrt[(size_t)(c0 + cc) * 3 + 0];
  float ws1 = wsrt[(size_t)(c0 + cc) * 3 + 1];
  float ws2 = wsrt[(size_t)(c0 + cc) * 3 + 2];
  __syncthreads();

  for (int m = 0; m < 32; ++m) {
    int ll = lh * 32 + m;
    float accL = 0.f;
#pragma unroll
    for (int j = 0; j < 63; ++j)
      accL = fmaf(s_v[ll + j][cc], wl[j], accL);
    float accS = s_v[ll + 60][cc] * ws0;
    accS = fmaf(s_v[ll + 61][cc], ws1, accS);
    accS = fmaf(s_v[ll + 62][cc], ws2, accS);
    size_t o = ((size_t)(b * 2048 + l0 + ll)) * 1024 + c0 + cc;
    longp[o] = accL;
    shortp[o] = accS;
  }
}

// --------------------- K6: path stats + gate_in build (bf16, padded to 1088)
__global__ __launch_bounds__(256)
void k6_gatein(const float* __restrict__ hs, const float* __restrict__ shortp,
               const float* __restrict__ longp, const float* __restrict__ delta,
               const float* __restrict__ vpath, bf16* __restrict__ gate_in) {
  const size_t row = blockIdx.x;
  const int t = threadIdx.x, wv = t >> 6, lane = t & 63;
  bf16* gr = gate_in + row * 1088;
#pragma unroll
  for (int i = 0; i < 2; ++i) {
    int c2 = (t + i * 256) * 2;
    float a = hs[row * 1024 + c2];
    float b = hs[row * 1024 + c2 + 1];
    *(unsigned*)(gr + c2) = pack2(a, b);
  }
  if (t < 16) *(unsigned*)(gr + 1056 + t * 2) = 0u;
  const float* paths[4] = {shortp, longp, delta, vpath};
#pragma unroll
  for (int p = 0; p < 4; ++p) {
    float s = 0.f, sq = 0.f;
#pragma unroll
    for (int i = 0; i < 4; ++i) {
      int c = wv * 256 + lane + i * 64;
      float x = paths[p][row * 1024 + c];
      s += x; sq += x * x;
    }
#pragma unroll
    for (int off = 32; off; off >>= 1) {
      s += __shfl_xor(s, off);
      sq += __shfl_xor(sq, off);
    }
    if (lane == 0) {
      float mean = s * (1.f / 256.f);
      float var = sq * (1.f / 256.f) - mean * mean;
      *(unsigned*)(gr + 1024 + p * 8 + wv * 2) = pack2(mean, var);
    }
  }
}

// ------------------------------- K8: logits GEMV + softmax + floor + renorm
__global__ __launch_bounds__(256)
void k8_probs(const float* __restrict__ hmid, const float* __restrict__ w2,
              const float* __restrict__ bias, const float* __restrict__ log_temp,
              const float* __restrict__ floor_raw, float* __restrict__ probs) {
  const int t = threadIdx.x, wv = t >> 6, lane = t & 63;
  const size_t row = (size_t)blockIdx.x * 4 + wv;
  float acc[16];
#pragma unroll
  for (int o = 0; o < 16; ++o) acc[o] = 0.f;
  for (int it = 0; it < 32; ++it) {
    int c = lane + it * 64;
    float x = hmid[row * 2048 + c];
#pragma unroll
    for (int o = 0; o < 16; ++o)
      acc[o] = fmaf(x, w2[o * 2048 + c], acc[o]);
  }
#pragma unroll
  for (int off = 32; off; off >>= 1)
#pragma unroll
    for (int o = 0; o < 16; ++o) acc[o] += __shfl_xor(acc[o], off);

  if (lane == 0) {
    for (int h2 = 0; h2 < 4; ++h2) {
      float temp = log1pf(expf(log_temp[h2])) + 1e-4f;
      float li[4], m = -1e30f;
#pragma unroll
      for (int p = 0; p < 4; ++p) {
        li[p] = (acc[h2 * 4 + p] + bias[h2 * 4 + p]) / temp;
        m = fmaxf(m, li[p]);
      }
      float sum = 0.f;
#pragma unroll
      for (int p = 0; p < 4; ++p) { li[p] = expf(li[p] - m); sum += li[p]; }
      float pr[4], s2 = 0.f;
#pragma unroll
      for (int p = 0; p < 4; ++p) {
        float fv = 0.05f / (1.f + expf(-floor_raw[h2 * 4 + p]));
        pr[p] = fmaxf(li[p] / sum, fv);
        s2 += pr[p];
      }
#pragma unroll
      for (int p = 0; p < 4; ++p)
        probs[row * 16 + h2 * 4 + p] = pr[p] / s2;
    }
  }
}

// ------------------------------- K9: mix paths + RMS-norm (bf16 out for GEMM)
__global__ __launch_bounds__(256)
void k9_mix(const float* __restrict__ shortp, const float* __restrict__ longp,
            const float* __restrict__ delta, const float* __restrict__ vpath,
            const float* __restrict__ probs, const float* __restrict__ onorm,
            bf16* __restrict__ mixed) {
  const size_t row = blockIdx.x;
  const int t = threadIdx.x, wv = t >> 6, lane = t & 63;
  float p0 = probs[row * 16 + wv * 4 + 0];
  float p1 = probs[row * 16 + wv * 4 + 1];
  float p2 = probs[row * 16 + wv * 4 + 2];
  float p3 = probs[row * 16 + wv * 4 + 3];
  float m[4];
  float sq = 0.f;
#pragma unroll
  for (int i = 0; i < 4; ++i) {
    int c = wv * 256 + lane + i * 64;
    size_t o = row * 1024 + c;
    float x = p0 * shortp[o] + p1 * longp[o] + p2 * delta[o] + p3 * vpath[o];
    m[i] = x;
    sq += x * x;
  }
#pragma unroll
  for (int off = 32; off; off >>= 1) sq += __shfl_xor(sq, off);
  float sc = rsqrtf(sq * (1.f / 256.f) + 1e-5f);
#pragma unroll
  for (int i = 0; i < 4; ++i) {
    int d = lane + i * 64;
    mixed[row * 1024 + wv * 256 + d] = (bf16)(m[i] * sc * onorm[d]);
  }
}

// ---------------------------------------------------------------- launcher
extern "C" void kernel_launch(void* const* d_in, const int* in_sizes, int n_in,
                              void* d_out, int out_size, void* d_ws,
                              size_t ws_size, hipStream_t stream) {
  const float* hs   = (const float*)d_in[0];
  const float* Wq   = (const float*)d_in[1];
  const float* Wk   = (const float*)d_in[2];
  const float* Wv   = (const float*)d_in[3];
  const float* Wb   = (const float*)d_in[4];
  const float* qw   = (const float*)d_in[5];
  const float* kw   = (const float*)d_in[6];
  const float* vw   = (const float*)d_in[7];
  const float* fsw  = (const float*)d_in[8];
  const float* flw  = (const float*)d_in[9];
  const float* gw1  = (const float*)d_in[10];
  const float* gb1  = (const float*)d_in[11];
  const float* gw2  = (const float*)d_in[12];
  const float* ltmp = (const float*)d_in[13];
  const float* bbias= (const float*)d_in[14];
  const float* frw  = (const float*)d_in[15];
  const float* onw  = (const float*)d_in[16];
  const float* Wo   = (const float*)d_in[17];
  float* out = (float*)d_out;

  float* f = (float*)d_ws;
  const size_t BLD = 4194304;  // B*L*D
  float* qlin    = f + 0 * BLD;
  float* klin    = f + 1 * BLD;
  float* vlin    = f + 2 * BLD;
  float* qn      = f + 3 * BLD;
  float* kn      = f + 4 * BLD;
  float* vpath   = f + 5 * BLD;
  float* shortp  = f + 6 * BLD;
  float* longp   = f + 7 * BLD;
  float* gate_f  = f + 8 * BLD;
  float* probs   = gate_f + 4325376;
  float* beta    = probs + 65536;

  bf16* hsb  = (bf16*)gate_f;
  bf16* ginb = (bf16*)gate_f;
  bf16* gw1b = (bf16*)gate_f + 4456448;
  bf16* wob  = (bf16*)gate_f + 4456448 + 2228224;
  bf16* wqb  = (bf16*)kn;
  bf16* wkb  = wqb + 1048576;
  bf16* wvb  = wkb + 1048576;

  float* u_f32 = qlin;
  bf16*  qbb   = (bf16*)shortp;
  bf16*  wbb   = qbb + 512 * 8192;
  bf16*  knTb  = (bf16*)longp;                    // 512 * 10240 bf16 (padded)
  bf16*  attnb = knTb + 512 * 10240;
  float* delta = vlin;
  float* hmid  = qn;
  bf16*  mixb  = (bf16*)klin;

  kcvt<<<2048, 256, 0, stream>>>(hs, hsb, 4194304);
  kcvt<<<512, 256, 0, stream>>>(Wq, wqb, 1048576);
  kcvt<<<512, 256, 0, stream>>>(Wk, wkb, 1048576);
  kcvt<<<512, 256, 0, stream>>>(Wv, wvb, 1048576);
  kcvt<<<512, 256, 0, stream>>>(Wo, wob, 1048576);
  kcvt_pad<<<2048, 256, 0, stream>>>(gw1, gw1b, 1056, 1088);

  gemm_bf16<0><<<dim3(8, 32), 256, 0, stream>>>(hsb, wqb, nullptr, qlin, 4096, 1024, 1024);
  gemm_bf16<0><<<dim3(8, 32), 256, 0, stream>>>(hsb, wkb, nullptr, klin, 4096, 1024, 1024);
  gemm_bf16<0><<<dim3(8, 32), 256, 0, stream>>>(hsb, wvb, nullptr, vlin, 4096, 1024, 1024);

  k2_conv<<<4096, 256, 0, stream>>>(hs, qlin, klin, vlin, qw, kw, vw, Wb,
                                    qn, kn, vpath, beta);
  k3_chunk<<<512, 256, 0, stream>>>(qn, kn, vpath, beta, u_f32, qbb, wbb,
                                    knTb, attnb);
  k4_scan_mfma<<<64, 128, 0, stream>>>(qbb, wbb, knTb, attnb, u_f32, delta);
  k5_fir<<<dim3(8, 32, 2), 256, 0, stream>>>(vpath, fsw, flw, shortp, longp);
  k6_gatein<<<4096, 256, 0, stream>>>(hs, shortp, longp, delta, vpath, ginb);
  gemm_bf16<1><<<dim3(16, 32), 256, 0, stream>>>(ginb, gw1b, gb1, hmid, 4096, 2048, 1088);
  k8_probs<<<1024, 256, 0, stream>>>(hmid, gw2, bbias, ltmp, frw, probs);
  k9_mix<<<4096, 256, 0, stream>>>(shortp, longp, delta, vpath, probs, onw, mixb);
  gemm_bf16<0><<<dim3(8, 32), 256, 0, stream>>>(mixb, wob, nullptr, out, 4096, 1024, 1024);
}

// Round 6
// 607.792 us; speedup vs baseline: 5.4541x; 1.0500x over previous
//
#include <hip/hip_runtime.h>
#include <cmath>

typedef __bf16 bf16;
typedef __bf16 bf16x8 __attribute__((ext_vector_type(8)));
typedef float  f32x4  __attribute__((ext_vector_type(4)));

#define MFMA16(a, b, c) __builtin_amdgcn_mfma_f32_16x16x32_bf16(a, b, c, 0, 0, 0)

#define GLD16(gsrc, ldst)                                                     \
  __builtin_amdgcn_global_load_lds(                                           \
      (const __attribute__((address_space(1))) unsigned*)(gsrc),              \
      (__attribute__((address_space(3))) unsigned*)(ldst), 16, 0, 0)

static __device__ __forceinline__ unsigned pack2(float a, float b) {
  unsigned short ua = __builtin_bit_cast(unsigned short, (__bf16)a);
  unsigned short ub = __builtin_bit_cast(unsigned short, (__bf16)b);
  return (unsigned)ua | ((unsigned)ub << 16);
}

// ------------------------------------------------------- f32 -> bf16 convert
__global__ __launch_bounds__(256)
void kcvt(const float* __restrict__ in, bf16* __restrict__ outp, int n) {
  int i = (blockIdx.x * 256 + threadIdx.x) * 8;
  if (i < n) {
    float4 a = *(const float4*)(in + i);
    float4 b = *(const float4*)(in + i + 4);
    uint4 v = make_uint4(pack2(a.x, a.y), pack2(a.z, a.w),
                         pack2(b.x, b.y), pack2(b.z, b.w));
    *(uint4*)(outp + i) = v;
  }
}

__global__ __launch_bounds__(256)
void kcvt_pad(const float* __restrict__ in, bf16* __restrict__ outp,
              int cin, int cout) {
  int r = blockIdx.x, c = threadIdx.x * 8;
  if (c >= cout) return;
  uint4 v = make_uint4(0u, 0u, 0u, 0u);
  if (c < cin) {
    float4 a = *(const float4*)(in + (size_t)r * cin + c);
    float4 b = *(const float4*)(in + (size_t)r * cin + c + 4);
    v = make_uint4(pack2(a.x, a.y), pack2(a.z, a.w),
                   pack2(b.x, b.y), pack2(b.z, b.w));
  }
  *(uint4*)(outp + (size_t)r * cout + c) = v;
}

// ---------------------------------------------------------- GEMM (bf16 MFMA)
template<int EPI>   // 0 = none, 1 = gelu(x + bias[n]) exact
__global__ __launch_bounds__(256)
void gemm_bf16(const bf16* __restrict__ A, const bf16* __restrict__ Bt,
               const float* __restrict__ bias, float* __restrict__ C,
               int M, int N, int K) {
  __shared__ __align__(16) bf16 sA[2][128 * 64];
  __shared__ __align__(16) bf16 sB[2][128 * 64];
  const int t = threadIdx.x;
  const int w = t >> 6, l = t & 63, lr = l & 15, lg = l >> 4;
  const int m0 = blockIdx.y * 128, n0 = blockIdx.x * 128;
  const int wm = (w & 1) * 64, wn = (w >> 1) * 64;
  const int w32 = w * 32;
  const int nst = K >> 6;

  f32x4 acc[4][4];
#pragma unroll
  for (int mt = 0; mt < 4; ++mt)
#pragma unroll
    for (int nt = 0; nt < 4; ++nt) acc[mt][nt] = (f32x4){0.f, 0.f, 0.f, 0.f};

  auto stage = [&](int s, int bf) {
    const char* ga = (const char*)A + ((size_t)(m0 + w32) * K + (size_t)s * 64) * 2;
    const char* gb = (const char*)Bt + ((size_t)(n0 + w32) * K + (size_t)s * 64) * 2;
    char* da = (char*)&sA[bf][0] + w32 * 128;
    char* db = (char*)&sB[bf][0] + w32 * 128;
    const size_t rs = (size_t)K * 2;
#pragma unroll
    for (int i = 0; i < 4; ++i) {
      GLD16(ga + (i * 8 + (l >> 3)) * rs + (l & 7) * 16, da + i * 1024);
      GLD16(gb + (i * 8 + (l >> 3)) * rs + (l & 7) * 16, db + i * 1024);
    }
  };

  stage(0, 0);
  __syncthreads();
  for (int s = 0; s < nst; ++s) {
    const int bf = s & 1;
    if (s + 1 < nst) stage(s + 1, bf ^ 1);
    const char* pa = (const char*)&sA[bf][0];
    const char* pb = (const char*)&sB[bf][0];
#pragma unroll
    for (int kb = 0; kb < 2; ++kb) {
      bf16x8 af[4], bfg[4];
#pragma unroll
      for (int mt = 0; mt < 4; ++mt)
        af[mt] = *(const bf16x8*)(pa + (wm + mt * 16 + lr) * 128 + kb * 64 + lg * 16);
#pragma unroll
      for (int nt = 0; nt < 4; ++nt)
        bfg[nt] = *(const bf16x8*)(pb + (wn + nt * 16 + lr) * 128 + kb * 64 + lg * 16);
#pragma unroll
      for (int mt = 0; mt < 4; ++mt)
#pragma unroll
        for (int nt = 0; nt < 4; ++nt)
          acc[mt][nt] = MFMA16(af[mt], bfg[nt], acc[mt][nt]);
    }
    __syncthreads();
  }

#pragma unroll
  for (int mt = 0; mt < 4; ++mt)
#pragma unroll
    for (int nt = 0; nt < 4; ++nt) {
      int nn = n0 + wn + nt * 16 + lr;
#pragma unroll
      for (int j = 0; j < 4; ++j) {
        int m = m0 + wm + mt * 16 + lg * 4 + j;
        float x = acc[mt][nt][j];
        if (EPI == 1) {
          x += bias[nn];
          x = 0.5f * x * (1.f + erff(x * 0.70710678118654752f));
        }
        C[(size_t)m * N + nn] = x;
      }
    }
}

// ------------------- K2: conv(K=4)+SiLU, l2norm, beta (reads fused qkv 3072)
__global__ __launch_bounds__(256)
void k2_conv(const float* __restrict__ hs, const float* __restrict__ qkv,
             const float* __restrict__ qw, const float* __restrict__ kw,
             const float* __restrict__ vw, const float* __restrict__ Wb,
             float* __restrict__ qn, float* __restrict__ kn,
             float* __restrict__ vpath, float* __restrict__ beta) {
  const int bid  = blockIdx.x;
  const int b    = bid >> 11;
  const int l    = bid & 2047;
  const int t    = threadIdx.x;
  const int wv   = t >> 6;
  const int lane = t & 63;
  const size_t row = (size_t)bid;

  __shared__ float s_red[4][4];

  float pb[4] = {0.f, 0.f, 0.f, 0.f};
#pragma unroll
  for (int i = 0; i < 4; ++i) {
    int c = wv * 256 + lane + i * 64;
    float x = hs[row * 1024 + c];
    pb[0] += x * Wb[0 * 1024 + c];
    pb[1] += x * Wb[1 * 1024 + c];
    pb[2] += x * Wb[2 * 1024 + c];
    pb[3] += x * Wb[3 * 1024 + c];
  }
#pragma unroll
  for (int off = 32; off; off >>= 1) {
    pb[0] += __shfl_xor(pb[0], off);
    pb[1] += __shfl_xor(pb[1], off);
    pb[2] += __shfl_xor(pb[2], off);
    pb[3] += __shfl_xor(pb[3], off);
  }
  if (lane == 0) {
    s_red[0][wv] = pb[0]; s_red[1][wv] = pb[1];
    s_red[2][wv] = pb[2]; s_red[3][wv] = pb[3];
  }
  __syncthreads();

  float xq[4], xk[4], xv[4];
#pragma unroll
  for (int i = 0; i < 4; ++i) {
    int c = wv * 256 + lane + i * 64;
    float aq = 0.f, ak = 0.f, av = 0.f;
#pragma unroll
    for (int j = 0; j < 4; ++j) {
      int ls = l - 3 + j;
      if (ls >= 0) {
        size_t ro = (size_t)(b * 2048 + ls) * 3072 + c;
        aq = fmaf(qkv[ro], qw[c * 4 + j], aq);
        ak = fmaf(qkv[ro + 1024], kw[c * 4 + j], ak);
        av = fmaf(qkv[ro + 2048], vw[c * 4 + j], av);
      }
    }
    xq[i] = aq / (1.f + expf(-aq));
    xk[i] = ak / (1.f + expf(-ak));
    xv[i] = av / (1.f + expf(-av));
  }

  float sq = 0.f, sk = 0.f;
#pragma unroll
  for (int i = 0; i < 4; ++i) { sq += xq[i] * xq[i]; sk += xk[i] * xk[i]; }
#pragma unroll
  for (int off = 32; off; off >>= 1) {
    sq += __shfl_xor(sq, off);
    sk += __shfl_xor(sk, off);
  }
  float rq = rsqrtf(sq + 1e-6f);
  float rk = rsqrtf(sk + 1e-6f);
  float bsum = s_red[wv][0] + s_red[wv][1] + s_red[wv][2] + s_red[wv][3];
  float betaw = 1.f / (1.f + expf(-bsum));
  if (lane == 0) beta[(size_t)bid * 4 + wv] = betaw;

  const int chk = l >> 5, pos = l & 31;
  size_t cbase = ((size_t)((b * 4 + wv) * 64 + chk) * 32 + pos) * 256;
#pragma unroll
  for (int i = 0; i < 4; ++i) {
    int d = lane + i * 64;
    qn[cbase + d] = xq[i] * rq;
    kn[cbase + d] = xk[i] * rk;
    vpath[row * 1024 + wv * 256 + d] = xv[i];
  }
}

// -------------------- K3: per-chunk A, (I+A)^-1 transform; exports MFMA frags
// qb/wb: 32x256 bf16, rows 512B, byte^=((row&15)<<4) swizzle
// knTp:  [chunk][256][32] bf16 (transposed, linear)
// attnb: [chunk][mt2][lane64][8] bf16 A-fragment order
// u:     [chunk][slice16][mt2][lane64][4] f32
__global__ __launch_bounds__(256)
void k3_chunk(const float* __restrict__ qn, const float* __restrict__ kn,
              const float* __restrict__ vpath, const float* __restrict__ beta,
              float* __restrict__ u, bf16* __restrict__ qb,
              bf16* __restrict__ wb, bf16* __restrict__ knTp,
              bf16* __restrict__ attnb) {
  __shared__ float s_kn[32][257];
  __shared__ float s_kb[32][257];
  __shared__ float s_x[32][257];
  __shared__ float s_A[32][33];
  __shared__ float s_beta[32];
  const int bid = blockIdx.x;
  const int bh = bid >> 6, chk = bid & 63;
  const int b = bh >> 2, h = bh & 3;
  const int t = threadIdx.x;
  const size_t base = (size_t)bid * 8192;

  if (t < 32)
    s_beta[t] = beta[((size_t)(b * 2048 + chk * 32 + t)) * 4 + h];
  for (int i = 0; i < 32; ++i) {
    int idx = t + i * 256;
    int r = idx >> 8, d = idx & 255;
    s_kn[r][d] = kn[base + idx];
    s_x[r][d]  = qn[base + idx];
  }
  __syncthreads();
  for (int i = 0; i < 32; ++i) {
    int idx = t + i * 256;
    int r = idx >> 8, d = idx & 255;
    s_kb[r][d] = s_kn[r][d] * s_beta[r];
  }
  __syncthreads();

  {
    const int r = t & 31, cg = t >> 5;
    float accA[4] = {0.f, 0.f, 0.f, 0.f};
    float accT[4] = {0.f, 0.f, 0.f, 0.f};
    for (int d = 0; d < 256; ++d) {
      float kbr = s_kb[r][d];
      float qr  = s_x[r][d];
#pragma unroll
      for (int q = 0; q < 4; ++q) {
        float knc = s_kn[cg * 4 + q][d];
        accA[q] = fmaf(kbr, knc, accA[q]);
        accT[q] = fmaf(qr,  knc, accT[q]);
      }
    }
    float at[4];
#pragma unroll
    for (int q = 0; q < 4; ++q) {
      int c = cg * 4 + q;
      s_A[r][c] = (r > c) ? -accA[q] : 0.f;
      at[q] = (r >= c) ? accT[q] : 0.f;
    }
    uint2 pk2;
    pk2.x = pack2(at[0], at[1]);
    pk2.y = pack2(at[2], at[3]);
    *(uint2*)((char*)attnb + (size_t)bid * 2048 +
              ((r >> 4) * 64 + (cg >> 1) * 16 + (r & 15)) * 16 + (cg & 1) * 8) = pk2;
  }

  for (int i = 0; i < 32; ++i) {
    int idx = t + i * 256;
    int r = idx >> 8, d = idx & 255;
    *(bf16*)((char*)qb + (size_t)bid * 16384 + r * 512 +
             ((2 * d) ^ ((r & 15) << 4))) = (bf16)s_x[r][d];
  }
  for (int i = 0; i < 32; ++i) {
    int d = (i << 3) + (t >> 5);
    int r = t & 31;
    knTp[(size_t)bid * 8192 + d * 32 + r] = (bf16)s_kn[r][d];
  }
  __syncthreads();

  for (int i = 1; i < 32; ++i) {
    float s = 0.f;
    if (t < i) {
      for (int j = 0; j < 32; ++j) s = fmaf(s_A[i][j], s_A[j][t], s);
    }
    __syncthreads();
    if (t < i) s_A[i][t] += s;
    __syncthreads();
  }

  for (int i = 0; i < 32; ++i) {
    int idx = t + i * 256;
    int r = idx >> 8, d = idx & 255;
    s_x[r][d] = vpath[((size_t)(b * 2048 + chk * 32 + r)) * 1024 + h * 256 + d]
                * s_beta[r];
  }
  __syncthreads();

  {
    const int lane = t & 63, wvv = t >> 6;
    for (int rr = 0; rr < 8; ++rr) {
      int r = wvv * 8 + rr;
      float au[4] = {0.f, 0.f, 0.f, 0.f};
      float aw[4] = {0.f, 0.f, 0.f, 0.f};
      for (int j = 0; j <= r; ++j) {
        float tc = (j == r) ? 1.f : s_A[r][j];
#pragma unroll
        for (int dd = 0; dd < 4; ++dd) {
          au[dd] = fmaf(tc, s_x[j][lane + dd * 64], au[dd]);
          aw[dd] = fmaf(tc, s_kb[j][lane + dd * 64], aw[dd]);
        }
      }
#pragma unroll
      for (int dd = 0; dd < 4; ++dd) {
        int d = lane + dd * 64;
        // u: [slice d>>4][mt r>>4][lane ((r>>2)&3)*16 + (d&15)][j r&3]
        u[(size_t)bid * 8192 + (d >> 4) * 512 + (r >> 4) * 256 +
          ((((r >> 2) & 3) << 4) + (d & 15)) * 4 + (r & 3)] = au[dd];
        *(bf16*)((char*)wb + (size_t)bid * 16384 + r * 512 +
                 ((2 * d) ^ ((r & 15) << 4))) = (bf16)(-aw[dd]);
      }
    }
  }
}

// ---------------- K4: MFMA chunk scan. 128 blocks = 8 bh x 16 col-slices(16).
// ONE wave per block: S/tmp/O wave-private => NO barriers. All operands stream
// via global_load_lds into a double buffer; one vmcnt(0) drain per chunk
// (prefetch issued a full iteration earlier, so the drain is cheap).
__global__ __launch_bounds__(64, 1)
void k4_scan_mfma(const bf16* __restrict__ qb, const bf16* __restrict__ wbp,
                  const bf16* __restrict__ knTp, const bf16* __restrict__ attnb,
                  const float* __restrict__ u, float* __restrict__ delta) {
  __shared__ __align__(16) bf16 s_w[2][32 * 256];   // 512B rows, swizzled
  __shared__ __align__(16) bf16 s_q[2][32 * 256];
  __shared__ __align__(16) bf16 s_kT[2][256 * 32];  // [buf][d][32] 64B rows
  __shared__ __align__(16) float s_u[2][512];       // [buf][mt][lane][4]
  __shared__ __align__(16) bf16 s_at[2][1024];      // [buf][mt][lane][8]
  __shared__ __align__(16) bf16 s_S[16 * 264];      // [col][264] 528B stride
  __shared__ __align__(16) bf16 s_tT[16 * 40];      // [col][40] 80B stride
  const int l = threadIdx.x;
  const int lr = l & 15, lg = l >> 4;
  const int bh = blockIdx.x & 7;        // same-bh blocks share an XCD L2
  const int slice = blockIdx.x >> 3;    // 0..15
  const int b = bh >> 2, h = bh & 3;
  const int chb = bh * 64;

  for (int i = l; i < 16 * 264 / 2; i += 64) ((unsigned*)s_S)[i] = 0u;
  f32x4 S[16];
#pragma unroll
  for (int dt = 0; dt < 16; ++dt) S[dt] = (f32x4){0.f, 0.f, 0.f, 0.f};

  auto stage = [&](int ck, int bf) {
    const char* gw = (const char*)wbp  + (size_t)ck * 16384;
    const char* gq = (const char*)qb   + (size_t)ck * 16384;
    const char* gk = (const char*)knTp + (size_t)ck * 16384;
    const char* gu = (const char*)u + (size_t)ck * 32768 + slice * 2048;
    const char* ga = (const char*)attnb + (size_t)ck * 2048;
    char* dw = (char*)&s_w[bf][0];
    char* dq = (char*)&s_q[bf][0];
    char* dk = (char*)&s_kT[bf][0];
    char* du = (char*)&s_u[bf][0];
    char* da = (char*)&s_at[bf][0];
#pragma unroll
    for (int i = 0; i < 16; ++i) GLD16(gw + i * 1024 + l * 16, dw + i * 1024);
#pragma unroll
    for (int i = 0; i < 16; ++i) GLD16(gq + i * 1024 + l * 16, dq + i * 1024);
#pragma unroll
    for (int i = 0; i < 16; ++i) GLD16(gk + i * 1024 + l * 16, dk + i * 1024);
#pragma unroll
    for (int i = 0; i < 2; ++i)  GLD16(gu + i * 1024 + l * 16, du + i * 1024);
#pragma unroll
    for (int i = 0; i < 2; ++i)  GLD16(ga + i * 1024 + l * 16, da + i * 1024);
  };

  stage(chb, 0);
  asm volatile("s_waitcnt vmcnt(0)" ::: "memory");
  __builtin_amdgcn_sched_barrier(0);

#pragma clang loop unroll(disable)
  for (int t = 0; t < 64; ++t) {
    const int bc = t & 1;
    // drain prev prefetch (issued one full iter ago); no cross-wave barrier
    asm volatile("s_waitcnt vmcnt(0)" ::: "memory");
    __builtin_amdgcn_sched_barrier(0);
    if (t < 63) stage(chb + t + 1, bc ^ 1);

    // ---- phase 1: tmp = u + (-W)@S ; O1 = Q@S  (K = 256)
    const char* pw = (const char*)&s_w[bc][0];
    const char* pq = (const char*)&s_q[bc][0];
    f32x4 t0 = *(const f32x4*)(&s_u[bc][0] + l * 4);
    f32x4 t1 = *(const f32x4*)(&s_u[bc][0] + 256 + l * 4);
    bf16x8 atA0 = *(const bf16x8*)((const char*)&s_at[bc][0] + l * 16);
    bf16x8 atA1 = *(const bf16x8*)((const char*)&s_at[bc][0] + 1024 + l * 16);
    f32x4 o0 = (f32x4){0.f, 0.f, 0.f, 0.f};
    f32x4 o1 = (f32x4){0.f, 0.f, 0.f, 0.f};
#pragma unroll
    for (int kb = 0; kb < 8; ++kb) {
      const int sw = (kb * 64 + lg * 16) ^ (lr << 4);
      bf16x8 sB  = *(const bf16x8*)((const char*)s_S + lr * 528 + kb * 64 + lg * 16);
      bf16x8 aw0 = *(const bf16x8*)(pw + lr * 512 + sw);
      bf16x8 aw1 = *(const bf16x8*)(pw + (16 + lr) * 512 + sw);
      bf16x8 aq0 = *(const bf16x8*)(pq + lr * 512 + sw);
      bf16x8 aq1 = *(const bf16x8*)(pq + (16 + lr) * 512 + sw);
      t0 = MFMA16(aw0, sB, t0);
      t1 = MFMA16(aw1, sB, t1);
      o0 = MFMA16(aq0, sB, o0);
      o1 = MFMA16(aq1, sB, o1);
    }
    // tmp^T to LDS (80B rows; wave-private)
    *(unsigned*)((char*)s_tT + lr * 80 + lg * 8)          = pack2(t0[0], t0[1]);
    *(unsigned*)((char*)s_tT + lr * 80 + lg * 8 + 4)      = pack2(t0[2], t0[3]);
    *(unsigned*)((char*)s_tT + lr * 80 + 32 + lg * 8)     = pack2(t1[0], t1[1]);
    *(unsigned*)((char*)s_tT + lr * 80 + 32 + lg * 8 + 4) = pack2(t1[2], t1[3]);

    // ---- phase 2: O = O1 + attn @ tmp ; store delta
    bf16x8 tB = *(const bf16x8*)((const char*)s_tT + lr * 80 + lg * 16);
    o0 = MFMA16(atA0, tB, o0);
    o1 = MFMA16(atA1, tB, o1);
    {
      size_t col = h * 256 + slice * 16 + lr;
#pragma unroll
      for (int j = 0; j < 4; ++j) {
        int r0 = t * 32 + lg * 4 + j;
        delta[((size_t)(b * 2048 + r0)) * 1024 + col] = o0[j];
        delta[((size_t)(b * 2048 + r0 + 16)) * 1024 + col] = o1[j];
      }
    }

    // ---- phase 3: S += K^T @ tmp ; refresh bf16 shadow
    const char* pk = (const char*)&s_kT[bc][0];
#pragma unroll
    for (int dt = 0; dt < 16; ++dt) {
      bf16x8 aK = *(const bf16x8*)(pk + (dt * 16 + lr) * 64 + lg * 16);
      S[dt] = MFMA16(aK, tB, S[dt]);
    }
#pragma unroll
    for (int dt = 0; dt < 16; ++dt) {
      *(unsigned*)((char*)s_S + lr * 528 + dt * 32 + lg * 8)     = pack2(S[dt][0], S[dt][1]);
      *(unsigned*)((char*)s_S + lr * 528 + dt * 32 + lg * 8 + 4) = pack2(S[dt][2], S[dt][3]);
    }
  }
}

// ------------------- K5: FIR short(3)/long(63), taps in registers, v in LDS
__global__ __launch_bounds__(256)
void k5_fir(const float* __restrict__ vpath, const float* __restrict__ wsrt,
            const float* __restrict__ wlng, float* __restrict__ shortp,
            float* __restrict__ longp) {
  __shared__ float s_v[126][128];
  const int c0 = blockIdx.x * 128;
  const int l0 = blockIdx.y * 64;
  const int b  = blockIdx.z;
  const int t  = threadIdx.x;

  for (int i = 0; i < 63; ++i) {
    int idx = t + i * 256;
    int rr = idx >> 7, cc2 = idx & 127;
    int gl = l0 - 62 + rr;
    s_v[rr][cc2] = (gl >= 0)
        ? vpath[((size_t)(b * 2048 + gl)) * 1024 + c0 + cc2] : 0.f;
  }

  const int cc = t & 127, lh = t >> 7;
  float wl[63];
#pragma unroll
  for (int j = 0; j < 63; ++j)
    wl[j] = wlng[(size_t)(c0 + cc) * 63 + j];
  float ws0 = wsrt[(size_t)(c0 + cc) * 3 + 0];
  float ws1 = wsrt[(size_t)(c0 + cc) * 3 + 1];
  float ws2 = wsrt[(size_t)(c0 + cc) * 3 + 2];
  __syncthreads();

  for (int m = 0; m < 32; ++m) {
    int ll = lh * 32 + m;
    float accL = 0.f;
#pragma unroll
    for (int j = 0; j < 63; ++j)
      accL = fmaf(s_v[ll + j][cc], wl[j], accL);
    float accS = s_v[ll + 60][cc] * ws0;
    accS = fmaf(s_v[ll + 61][cc], ws1, accS);
    accS = fmaf(s_v[ll + 62][cc], ws2, accS);
    size_t o = ((size_t)(b * 2048 + l0 + ll)) * 1024 + c0 + cc;
    longp[o] = accL;
    shortp[o] = accS;
  }
}

// --------------------- K6: path stats + gate_in build (bf16, padded to 1088)
__global__ __launch_bounds__(256)
void k6_gatein(const float* __restrict__ hs, const float* __restrict__ shortp,
               const float* __restrict__ longp, const float* __restrict__ delta,
               const float* __restrict__ vpath, bf16* __restrict__ gate_in) {
  const size_t row = blockIdx.x;
  const int t = threadIdx.x, wv = t >> 6, lane = t & 63;
  bf16* gr = gate_in + row * 1088;
#pragma unroll
  for (int i = 0; i < 2; ++i) {
    int c2 = (t + i * 256) * 2;
    float a = hs[row * 1024 + c2];
    float b = hs[row * 1024 + c2 + 1];
    *(unsigned*)(gr + c2) = pack2(a, b);
  }
  if (t < 16) *(unsigned*)(gr + 1056 + t * 2) = 0u;
  const float* paths[4] = {shortp, longp, delta, vpath};
#pragma unroll
  for (int p = 0; p < 4; ++p) {
    float s = 0.f, sq = 0.f;
#pragma unroll
    for (int i = 0; i < 4; ++i) {
      int c = wv * 256 + lane + i * 64;
      float x = paths[p][row * 1024 + c];
      s += x; sq += x * x;
    }
#pragma unroll
    for (int off = 32; off; off >>= 1) {
      s += __shfl_xor(s, off);
      sq += __shfl_xor(sq, off);
    }
    if (lane == 0) {
      float mean = s * (1.f / 256.f);
      float var = sq * (1.f / 256.f) - mean * mean;
      *(unsigned*)(gr + 1024 + p * 8 + wv * 2) = pack2(mean, var);
    }
  }
}

// ------------------------------- K8: logits GEMV + softmax + floor + renorm
__global__ __launch_bounds__(256)
void k8_probs(const float* __restrict__ hmid, const float* __restrict__ w2,
              const float* __restrict__ bias, const float* __restrict__ log_temp,
              const float* __restrict__ floor_raw, float* __restrict__ probs) {
  const int t = threadIdx.x, wv = t >> 6, lane = t & 63;
  const size_t row = (size_t)blockIdx.x * 4 + wv;
  float acc[16];
#pragma unroll
  for (int o = 0; o < 16; ++o) acc[o] = 0.f;
  for (int it = 0; it < 32; ++it) {
    int c = lane + it * 64;
    float x = hmid[row * 2048 + c];
#pragma unroll
    for (int o = 0; o < 16; ++o)
      acc[o] = fmaf(x, w2[o * 2048 + c], acc[o]);
  }
#pragma unroll
  for (int off = 32; off; off >>= 1)
#pragma unroll
    for (int o = 0; o < 16; ++o) acc[o] += __shfl_xor(acc[o], off);

  if (lane == 0) {
    for (int h2 = 0; h2 < 4; ++h2) {
      float temp = log1pf(expf(log_temp[h2])) + 1e-4f;
      float li[4], m = -1e30f;
#pragma unroll
      for (int p = 0; p < 4; ++p) {
        li[p] = (acc[h2 * 4 + p] + bias[h2 * 4 + p]) / temp;
        m = fmaxf(m, li[p]);
      }
      float sum = 0.f;
#pragma unroll
      for (int p = 0; p < 4; ++p) { li[p] = expf(li[p] - m); sum += li[p]; }
      float pr[4], s2 = 0.f;
#pragma unroll
      for (int p = 0; p < 4; ++p) {
        float fv = 0.05f / (1.f + expf(-floor_raw[h2 * 4 + p]));
        pr[p] = fmaxf(li[p] / sum, fv);
        s2 += pr[p];
      }
#pragma unroll
      for (int p = 0; p < 4; ++p)
        probs[row * 16 + h2 * 4 + p] = pr[p] / s2;
    }
  }
}

// ------------------------------- K9: mix paths + RMS-norm (bf16 out for GEMM)
__global__ __launch_bounds__(256)
void k9_mix(const float* __restrict__ shortp, const float* __restrict__ longp,
            const float* __restrict__ delta, const float* __restrict__ vpath,
            const float* __restrict__ probs, const float* __restrict__ onorm,
            bf16* __restrict__ mixed) {
  const size_t row = blockIdx.x;
  const int t = threadIdx.x, wv = t >> 6, lane = t & 63;
  float p0 = probs[row * 16 + wv * 4 + 0];
  float p1 = probs[row * 16 + wv * 4 + 1];
  float p2 = probs[row * 16 + wv * 4 + 2];
  float p3 = probs[row * 16 + wv * 4 + 3];
  float m[4];
  float sq = 0.f;
#pragma unroll
  for (int i = 0; i < 4; ++i) {
    int c = wv * 256 + lane + i * 64;
    size_t o = row * 1024 + c;
    float x = p0 * shortp[o] + p1 * longp[o] + p2 * delta[o] + p3 * vpath[o];
    m[i] = x;
    sq += x * x;
  }
#pragma unroll
  for (int off = 32; off; off >>= 1) sq += __shfl_xor(sq, off);
  float sc = rsqrtf(sq * (1.f / 256.f) + 1e-5f);
#pragma unroll
  for (int i = 0; i < 4; ++i) {
    int d = lane + i * 64;
    mixed[row * 1024 + wv * 256 + d] = (bf16)(m[i] * sc * onorm[d]);
  }
}

// ---------------------------------------------------------------- launcher
extern "C" void kernel_launch(void* const* d_in, const int* in_sizes, int n_in,
                              void* d_out, int out_size, void* d_ws,
                              size_t ws_size, hipStream_t stream) {
  const float* hs   = (const float*)d_in[0];
  const float* Wq   = (const float*)d_in[1];
  const float* Wk   = (const float*)d_in[2];
  const float* Wv   = (const float*)d_in[3];
  const float* Wb   = (const float*)d_in[4];
  const float* qw   = (const float*)d_in[5];
  const float* kw   = (const float*)d_in[6];
  const float* vw   = (const float*)d_in[7];
  const float* fsw  = (const float*)d_in[8];
  const float* flw  = (const float*)d_in[9];
  const float* gw1  = (const float*)d_in[10];
  const float* gb1  = (const float*)d_in[11];
  const float* gw2  = (const float*)d_in[12];
  const float* ltmp = (const float*)d_in[13];
  const float* bbias= (const float*)d_in[14];
  const float* frw  = (const float*)d_in[15];
  const float* onw  = (const float*)d_in[16];
  const float* Wo   = (const float*)d_in[17];
  float* out = (float*)d_out;

  float* f = (float*)d_ws;
  const size_t BLD = 4194304;  // B*L*D
  float* qkv     = f + 0 * BLD;                 // [4096][3072] fused
  float* qn      = f + 3 * BLD;
  float* kn      = f + 4 * BLD;
  float* vpath   = f + 5 * BLD;
  float* shortp  = f + 6 * BLD;
  float* longp   = f + 7 * BLD;
  float* gate_f  = f + 8 * BLD;
  float* probs   = gate_f + 4325376;
  float* beta    = probs + 65536;

  bf16* hsb  = (bf16*)gate_f;
  bf16* ginb = (bf16*)gate_f;
  bf16* gw1b = (bf16*)gate_f + 4456448;
  bf16* wob  = (bf16*)gate_f + 4456448 + 2228224;
  bf16* wqb  = (bf16*)kn;                       // wq/wk/wv contiguous here
  bf16* wkb  = wqb + 1048576;
  bf16* wvb  = wkb + 1048576;

  float* u_f32 = f + 0 * BLD;                   // over dead qkv (q third)
  bf16*  qbb   = (bf16*)shortp;
  bf16*  wbb   = qbb + 512 * 8192;
  bf16*  knTb  = (bf16*)longp;                  // 512*8192 bf16
  bf16*  attnb = knTb + 512 * 8192;
  float* delta = f + 2 * BLD;                   // over dead qkv (v third)
  float* hmid  = qn;
  bf16*  mixb  = (bf16*)(f + 1 * BLD);          // over dead qkv (k third)

  kcvt<<<2048, 256, 0, stream>>>(hs, hsb, 4194304);
  kcvt<<<512, 256, 0, stream>>>(Wq, wqb, 1048576);
  kcvt<<<512, 256, 0, stream>>>(Wk, wkb, 1048576);
  kcvt<<<512, 256, 0, stream>>>(Wv, wvb, 1048576);
  kcvt<<<512, 256, 0, stream>>>(Wo, wob, 1048576);
  kcvt_pad<<<2048, 256, 0, stream>>>(gw1, gw1b, 1056, 1088);

  // fused QKV projection: C[4096][3072]
  gemm_bf16<0><<<dim3(24, 32), 256, 0, stream>>>(hsb, wqb, nullptr, qkv, 4096, 3072, 1024);

  k2_conv<<<4096, 256, 0, stream>>>(hs, qkv, qw, kw, vw, Wb,
                                    qn, kn, vpath, beta);
  k3_chunk<<<512, 256, 0, stream>>>(qn, kn, vpath, beta, u_f32, qbb, wbb,
                                    knTb, attnb);
  k4_scan_mfma<<<128, 64, 0, stream>>>(qbb, wbb, knTb, attnb, u_f32, delta);
  k5_fir<<<dim3(8, 32, 2), 256, 0, stream>>>(vpath, fsw, flw, shortp, longp);
  k6_gatein<<<4096, 256, 0, stream>>>(hs, shortp, longp, delta, vpath, ginb);
  gemm_bf16<1><<<dim3(16, 32), 256, 0, stream>>>(ginb, gw1b, gb1, hmid, 4096, 2048, 1088);
  k8_probs<<<1024, 256, 0, stream>>>(hmid, gw2, bbias, ltmp, frw, probs);
  k9_mix<<<4096, 256, 0, stream>>>(shortp, longp, delta, vpath, probs, onw, mixb);
  gemm_bf16<0><<<dim3(8, 32), 256, 0, stream>>>(mixb, wob, nullptr, out, 4096, 1024, 1024);
}

// Round 7
// 552.800 us; speedup vs baseline: 5.9967x; 1.0995x over previous
//
#include <hip/hip_runtime.h>
#include <cmath>

typedef __bf16 bf16;
typedef __bf16 bf16x8 __attribute__((ext_vector_type(8)));
typedef float  f32x4  __attribute__((ext_vector_type(4)));

#define MFMA16(a, b, c) __builtin_amdgcn_mfma_f32_16x16x32_bf16(a, b, c, 0, 0, 0)

#define GLD16(gsrc, ldst)                                                     \
  __builtin_amdgcn_global_load_lds(                                           \
      (const __attribute__((address_space(1))) unsigned*)(gsrc),              \
      (__attribute__((address_space(3))) unsigned*)(ldst), 16, 0, 0)

static __device__ __forceinline__ unsigned pack2(float a, float b) {
  unsigned short ua = __builtin_bit_cast(unsigned short, (__bf16)a);
  unsigned short ub = __builtin_bit_cast(unsigned short, (__bf16)b);
  return (unsigned)ua | ((unsigned)ub << 16);
}

// ------------------------------------------------------- f32 -> bf16 convert
__global__ __launch_bounds__(256)
void kcvt(const float* __restrict__ in, bf16* __restrict__ outp, int n) {
  int i = (blockIdx.x * 256 + threadIdx.x) * 8;
  if (i < n) {
    float4 a = *(const float4*)(in + i);
    float4 b = *(const float4*)(in + i + 4);
    uint4 v = make_uint4(pack2(a.x, a.y), pack2(a.z, a.w),
                         pack2(b.x, b.y), pack2(b.z, b.w));
    *(uint4*)(outp + i) = v;
  }
}

// 4 weight matrices (1048576 elems each) in one launch
__global__ __launch_bounds__(256)
void kcvt4(const float* __restrict__ i0, const float* __restrict__ i1,
           const float* __restrict__ i2, const float* __restrict__ i3,
           bf16* __restrict__ o0, bf16* __restrict__ o1,
           bf16* __restrict__ o2, bf16* __restrict__ o3) {
  int seg = blockIdx.x >> 9;
  int i = (((blockIdx.x & 511) * 256) + threadIdx.x) * 8;
  const float* in = (seg == 0) ? i0 : (seg == 1) ? i1 : (seg == 2) ? i2 : i3;
  bf16* outp = (seg == 0) ? o0 : (seg == 1) ? o1 : (seg == 2) ? o2 : o3;
  float4 a = *(const float4*)(in + i);
  float4 b = *(const float4*)(in + i + 4);
  uint4 v = make_uint4(pack2(a.x, a.y), pack2(a.z, a.w),
                       pack2(b.x, b.y), pack2(b.z, b.w));
  *(uint4*)(outp + i) = v;
}

__global__ __launch_bounds__(256)
void kcvt_pad(const float* __restrict__ in, bf16* __restrict__ outp,
              int cin, int cout) {
  int r = blockIdx.x, c = threadIdx.x * 8;
  if (c >= cout) return;
  uint4 v = make_uint4(0u, 0u, 0u, 0u);
  if (c < cin) {
    float4 a = *(const float4*)(in + (size_t)r * cin + c);
    float4 b = *(const float4*)(in + (size_t)r * cin + c + 4);
    v = make_uint4(pack2(a.x, a.y), pack2(a.z, a.w),
                   pack2(b.x, b.y), pack2(b.z, b.w));
  }
  *(uint4*)(outp + (size_t)r * cout + c) = v;
}

// ---------------------------------------------------------- GEMM (bf16 MFMA)
template<int EPI>   // 0 = none, 1 = gelu(x + bias[n]) exact
__global__ __launch_bounds__(256)
void gemm_bf16(const bf16* __restrict__ A, const bf16* __restrict__ Bt,
               const float* __restrict__ bias, float* __restrict__ C,
               int M, int N, int K) {
  __shared__ __align__(16) bf16 sA[2][128 * 64];
  __shared__ __align__(16) bf16 sB[2][128 * 64];
  const int t = threadIdx.x;
  const int w = t >> 6, l = t & 63, lr = l & 15, lg = l >> 4;
  const int m0 = blockIdx.y * 128, n0 = blockIdx.x * 128;
  const int wm = (w & 1) * 64, wn = (w >> 1) * 64;
  const int w32 = w * 32;
  const int nst = K >> 6;

  f32x4 acc[4][4];
#pragma unroll
  for (int mt = 0; mt < 4; ++mt)
#pragma unroll
    for (int nt = 0; nt < 4; ++nt) acc[mt][nt] = (f32x4){0.f, 0.f, 0.f, 0.f};

  auto stage = [&](int s, int bf) {
    const char* ga = (const char*)A + ((size_t)(m0 + w32) * K + (size_t)s * 64) * 2;
    const char* gb = (const char*)Bt + ((size_t)(n0 + w32) * K + (size_t)s * 64) * 2;
    char* da = (char*)&sA[bf][0] + w32 * 128;
    char* db = (char*)&sB[bf][0] + w32 * 128;
    const size_t rs = (size_t)K * 2;
#pragma unroll
    for (int i = 0; i < 4; ++i) {
      GLD16(ga + (i * 8 + (l >> 3)) * rs + (l & 7) * 16, da + i * 1024);
      GLD16(gb + (i * 8 + (l >> 3)) * rs + (l & 7) * 16, db + i * 1024);
    }
  };

  stage(0, 0);
  __syncthreads();
  for (int s = 0; s < nst; ++s) {
    const int bf = s & 1;
    if (s + 1 < nst) stage(s + 1, bf ^ 1);
    const char* pa = (const char*)&sA[bf][0];
    const char* pb = (const char*)&sB[bf][0];
#pragma unroll
    for (int kb = 0; kb < 2; ++kb) {
      bf16x8 af[4], bfg[4];
#pragma unroll
      for (int mt = 0; mt < 4; ++mt)
        af[mt] = *(const bf16x8*)(pa + (wm + mt * 16 + lr) * 128 + kb * 64 + lg * 16);
#pragma unroll
      for (int nt = 0; nt < 4; ++nt)
        bfg[nt] = *(const bf16x8*)(pb + (wn + nt * 16 + lr) * 128 + kb * 64 + lg * 16);
#pragma unroll
      for (int mt = 0; mt < 4; ++mt)
#pragma unroll
        for (int nt = 0; nt < 4; ++nt)
          acc[mt][nt] = MFMA16(af[mt], bfg[nt], acc[mt][nt]);
    }
    __syncthreads();
  }

#pragma unroll
  for (int mt = 0; mt < 4; ++mt)
#pragma unroll
    for (int nt = 0; nt < 4; ++nt) {
      int nn = n0 + wn + nt * 16 + lr;
#pragma unroll
      for (int j = 0; j < 4; ++j) {
        int m = m0 + wm + mt * 16 + lg * 4 + j;
        float x = acc[mt][nt][j];
        if (EPI == 1) {
          x += bias[nn];
          x = 0.5f * x * (1.f + erff(x * 0.70710678118654752f));
        }
        C[(size_t)m * N + nn] = x;
      }
    }
}

// ------------------- K2: conv(K=4)+SiLU, l2norm, beta (reads fused qkv 3072)
__global__ __launch_bounds__(256)
void k2_conv(const float* __restrict__ hs, const float* __restrict__ qkv,
             const float* __restrict__ qw, const float* __restrict__ kw,
             const float* __restrict__ vw, const float* __restrict__ Wb,
             float* __restrict__ qn, float* __restrict__ kn,
             float* __restrict__ vpath, float* __restrict__ beta) {
  const int bid  = blockIdx.x;
  const int b    = bid >> 11;
  const int l    = bid & 2047;
  const int t    = threadIdx.x;
  const int wv   = t >> 6;
  const int lane = t & 63;
  const size_t row = (size_t)bid;

  __shared__ float s_red[4][4];

  float pb[4] = {0.f, 0.f, 0.f, 0.f};
#pragma unroll
  for (int i = 0; i < 4; ++i) {
    int c = wv * 256 + lane + i * 64;
    float x = hs[row * 1024 + c];
    pb[0] += x * Wb[0 * 1024 + c];
    pb[1] += x * Wb[1 * 1024 + c];
    pb[2] += x * Wb[2 * 1024 + c];
    pb[3] += x * Wb[3 * 1024 + c];
  }
#pragma unroll
  for (int off = 32; off; off >>= 1) {
    pb[0] += __shfl_xor(pb[0], off);
    pb[1] += __shfl_xor(pb[1], off);
    pb[2] += __shfl_xor(pb[2], off);
    pb[3] += __shfl_xor(pb[3], off);
  }
  if (lane == 0) {
    s_red[0][wv] = pb[0]; s_red[1][wv] = pb[1];
    s_red[2][wv] = pb[2]; s_red[3][wv] = pb[3];
  }
  __syncthreads();

  float xq[4], xk[4], xv[4];
#pragma unroll
  for (int i = 0; i < 4; ++i) {
    int c = wv * 256 + lane + i * 64;
    float aq = 0.f, ak = 0.f, av = 0.f;
#pragma unroll
    for (int j = 0; j < 4; ++j) {
      int ls = l - 3 + j;
      if (ls >= 0) {
        size_t ro = (size_t)(b * 2048 + ls) * 3072 + c;
        aq = fmaf(qkv[ro], qw[c * 4 + j], aq);
        ak = fmaf(qkv[ro + 1024], kw[c * 4 + j], ak);
        av = fmaf(qkv[ro + 2048], vw[c * 4 + j], av);
      }
    }
    xq[i] = aq / (1.f + expf(-aq));
    xk[i] = ak / (1.f + expf(-ak));
    xv[i] = av / (1.f + expf(-av));
  }

  float sq = 0.f, sk = 0.f;
#pragma unroll
  for (int i = 0; i < 4; ++i) { sq += xq[i] * xq[i]; sk += xk[i] * xk[i]; }
#pragma unroll
  for (int off = 32; off; off >>= 1) {
    sq += __shfl_xor(sq, off);
    sk += __shfl_xor(sk, off);
  }
  float rq = rsqrtf(sq + 1e-6f);
  float rk = rsqrtf(sk + 1e-6f);
  float bsum = s_red[wv][0] + s_red[wv][1] + s_red[wv][2] + s_red[wv][3];
  float betaw = 1.f / (1.f + expf(-bsum));
  if (lane == 0) beta[(size_t)bid * 4 + wv] = betaw;

  const int chk = l >> 5, pos = l & 31;
  size_t cbase = ((size_t)((b * 4 + wv) * 64 + chk) * 32 + pos) * 256;
#pragma unroll
  for (int i = 0; i < 4; ++i) {
    int d = lane + i * 64;
    qn[cbase + d] = xq[i] * rq;
    kn[cbase + d] = xk[i] * rk;
    vpath[row * 1024 + wv * 256 + d] = xv[i];
  }
}

// -------------------- K3 (MFMA rewrite): per-chunk A, (I+A)^-1, u/w transform
// Exports identical layouts to R6:
//  qb/wb: 32x256 bf16, rows 512B, byte^=((row&15)<<4) swizzle
//  knTp:  [chunk][256][32] bf16 (transposed, linear)
//  attnb: [chunk][mt2][lane64][8] bf16 A-fragment order
//  u:     [chunk][slice16][mt2][lane64][4] f32  (direct D-frag dumps)
__global__ __launch_bounds__(256, 2)
void k3_chunk(const float* __restrict__ qn, const float* __restrict__ kn,
              const float* __restrict__ vpath, const float* __restrict__ beta,
              float* __restrict__ u, bf16* __restrict__ qb,
              bf16* __restrict__ wb, bf16* __restrict__ knTp,
              bf16* __restrict__ attnb) {
  // LDS layout (aliased, 64256 B total -> 2 blocks/CU):
  //  [0,16384)      kn_b   32 rows x 512B, swizzled      (live: whole kernel)
  //  [16384,32768)  q_b    (live until attn MFMA) -> kbT [256][40] after
  //  [32768,49152)  kb_b   (live until A MFMA)    -> vbT tail
  //  [36864,57344)  vbT    [256][40]
  //  [57344,59904)  T_b    32 x 80B
  //  [59904,64128)  s_A    f32 [32][33]
  //  [64128,64256)  s_beta
  __shared__ __align__(16) char sm[64256];
  bf16* s_knb = (bf16*)(sm);
  bf16* s_qbt = (bf16*)(sm + 16384);
  bf16* s_kbb = (bf16*)(sm + 32768);
  bf16* s_kbT = (bf16*)(sm + 16384);
  bf16* s_vbT = (bf16*)(sm + 36864);
  bf16* s_T   = (bf16*)(sm + 57344);
  float (*s_A)[33] = (float(*)[33])(sm + 59904);
  float* s_beta = (float*)(sm + 64128);

  const int bid = blockIdx.x;
  const int bh = bid >> 6, chk = bid & 63;
  const int b = bh >> 2, h = bh & 3;
  const int t = threadIdx.x;
  const int w = t >> 6, l = t & 63, lr = l & 15, lg = l >> 4;
  const size_t base = (size_t)bid * 8192;

  if (t < 32)
    s_beta[t] = beta[((size_t)(b * 2048 + chk * 32 + t)) * 4 + h];
  __syncthreads();

  // ---- step 1: load row-major f32, build bf16 LDS tiles + qb export.
  // iteration i handles row i, this thread owns column d = t.
  float vv[32], kbr[32];
#pragma unroll
  for (int i = 0; i < 32; ++i) {
    float qv = qn[base + i * 256 + t];
    float kv = kn[base + i * 256 + t];
    float be = s_beta[i];
    vv[i]  = vpath[((size_t)(b * 2048 + chk * 32 + i)) * 1024 + h * 256 + t] * be;
    kbr[i] = kv * be;
    const int sw = (2 * t) ^ ((i & 15) << 4);
    *(bf16*)((char*)s_knb + i * 512 + sw) = (bf16)kv;
    *(bf16*)((char*)s_qbt + i * 512 + sw) = (bf16)qv;
    *(bf16*)((char*)s_kbb + i * 512 + sw) = (bf16)kbr[i];
    *(bf16*)((char*)qb + (size_t)bid * 16384 + i * 512 + sw) = (bf16)qv;
  }
  __syncthreads();

  // ---- knT export (coalesced via LDS) + MFMA set 1: A = kb@kn^T, attn = q@kn^T
#pragma unroll
  for (int i = 0; i < 32; ++i) {
    int d = (i << 3) + (t >> 5);
    int r = t & 31;
    bf16 kv = *(const bf16*)((char*)s_knb + r * 512 + ((2 * d) ^ ((r & 15) << 4)));
    knTp[base + d * 32 + r] = kv;
  }
  {
    const int am = w & 1, an = w >> 1;
    f32x4 accA = (f32x4){0.f, 0.f, 0.f, 0.f};
    f32x4 accT = (f32x4){0.f, 0.f, 0.f, 0.f};
#pragma unroll
    for (int kb = 0; kb < 8; ++kb) {
      const int swz = (kb * 64 + lg * 16) ^ (lr << 4);
      bf16x8 aKB = *(const bf16x8*)((char*)s_kbb + (am * 16 + lr) * 512 + swz);
      bf16x8 aQ  = *(const bf16x8*)((char*)s_qbt + (am * 16 + lr) * 512 + swz);
      bf16x8 bKN = *(const bf16x8*)((char*)s_knb + (an * 16 + lr) * 512 + swz);
      accA = MFMA16(aKB, bKN, accA);
      accT = MFMA16(aQ,  bKN, accT);
    }
#pragma unroll
    for (int j = 0; j < 4; ++j) {
      int R = am * 16 + lg * 4 + j, C = an * 16 + lr;
      s_A[R][C] = (R > C) ? -accA[j] : 0.f;
      float at = (R >= C) ? accT[j] : 0.f;
      *(bf16*)((char*)attnb + (size_t)bid * 2048 + am * 1024 +
               ((lg * 4 + j) + ((C >> 3) << 4)) * 16 + (C & 7) * 2) = (bf16)at;
    }
  }
  __syncthreads();

  // ---- inversion (wave 0 only, lockstep => no barriers) ...
  if (w == 0) {
    for (int i = 1; i < 32; ++i) {
      float s = 0.f;
      if (l < i) {
        for (int j = 0; j < 32; ++j) s = fmaf(s_A[i][j], s_A[j][l], s);
        s_A[i][l] += s;
      }
    }
  }
  // ... while all waves build vbT / kbT (wave 0 after its inversion)
#pragma unroll
  for (int i = 0; i < 32; i += 2) {
    *(unsigned*)((char*)s_vbT + t * 80 + i * 2) = pack2(vv[i], vv[i + 1]);
    *(unsigned*)((char*)s_kbT + t * 80 + i * 2) = pack2(kbr[i], kbr[i + 1]);
  }
  __syncthreads();

  // ---- T -> bf16 tile (rows 80B)
  {
    int r = t >> 3, c0 = (t & 7) * 4;
    float v0 = (r == c0)     ? 1.f : (r > c0     ? s_A[r][c0]     : 0.f);
    float v1 = (r == c0 + 1) ? 1.f : (r > c0 + 1 ? s_A[r][c0 + 1] : 0.f);
    float v2 = (r == c0 + 2) ? 1.f : (r > c0 + 2 ? s_A[r][c0 + 2] : 0.f);
    float v3 = (r == c0 + 3) ? 1.f : (r > c0 + 3 ? s_A[r][c0 + 3] : 0.f);
    *(unsigned*)((char*)s_T + r * 80 + c0 * 2)     = pack2(v0, v1);
    *(unsigned*)((char*)s_T + r * 80 + c0 * 2 + 4) = pack2(v2, v3);
  }
  __syncthreads();

  // ---- MFMA set 2: u = T@vb (f32 out), w = -(T@kb) (bf16 out)
  {
    bf16x8 aT0 = *(const bf16x8*)((char*)s_T + lr * 80 + lg * 16);
    bf16x8 aT1 = *(const bf16x8*)((char*)s_T + (16 + lr) * 80 + lg * 16);
#pragma unroll
    for (int nt = 0; nt < 4; ++nt) {
      const int n = w * 4 + nt;
      bf16x8 bV = *(const bf16x8*)((char*)s_vbT + (n * 16 + lr) * 80 + lg * 16);
      bf16x8 bK = *(const bf16x8*)((char*)s_kbT + (n * 16 + lr) * 80 + lg * 16);
      f32x4 u0 = (f32x4){0.f, 0.f, 0.f, 0.f};
      f32x4 u1 = (f32x4){0.f, 0.f, 0.f, 0.f};
      f32x4 w0 = (f32x4){0.f, 0.f, 0.f, 0.f};
      f32x4 w1 = (f32x4){0.f, 0.f, 0.f, 0.f};
      u0 = MFMA16(aT0, bV, u0);
      u1 = MFMA16(aT1, bV, u1);
      w0 = MFMA16(aT0, bK, w0);
      w1 = MFMA16(aT1, bK, w1);
      *(f32x4*)((char*)u + (size_t)bid * 32768 + n * 2048 + l * 16)        = u0;
      *(f32x4*)((char*)u + (size_t)bid * 32768 + n * 2048 + 1024 + l * 16) = u1;
#pragma unroll
      for (int j = 0; j < 4; ++j) {
        int C = n * 16 + lr;
        int R0 = lg * 4 + j;
        int R1 = 16 + lg * 4 + j;
        *(bf16*)((char*)wb + (size_t)bid * 16384 + R0 * 512 +
                 ((2 * C) ^ ((R0 & 15) << 4))) = (bf16)(-w0[j]);
        *(bf16*)((char*)wb + (size_t)bid * 16384 + R1 * 512 +
                 ((2 * C) ^ ((R1 & 15) << 4))) = (bf16)(-w1[j]);
      }
    }
  }
}

// ---------------- K4: MFMA chunk scan. 128 blocks = 8 bh x 16 col-slices(16).
// ONE wave per block: S/tmp/O wave-private => NO barriers.
__global__ __launch_bounds__(64, 1)
void k4_scan_mfma(const bf16* __restrict__ qb, const bf16* __restrict__ wbp,
                  const bf16* __restrict__ knTp, const bf16* __restrict__ attnb,
                  const float* __restrict__ u, float* __restrict__ delta) {
  __shared__ __align__(16) bf16 s_w[2][32 * 256];   // 512B rows, swizzled
  __shared__ __align__(16) bf16 s_q[2][32 * 256];
  __shared__ __align__(16) bf16 s_kT[2][256 * 32];  // [buf][d][32] 64B rows
  __shared__ __align__(16) float s_u[2][512];       // [buf][mt][lane][4]
  __shared__ __align__(16) bf16 s_at[2][1024];      // [buf][mt][lane][8]
  __shared__ __align__(16) bf16 s_S[16 * 264];      // [col][264] 528B stride
  __shared__ __align__(16) bf16 s_tT[16 * 40];      // [col][40] 80B stride
  const int l = threadIdx.x;
  const int lr = l & 15, lg = l >> 4;
  const int bh = blockIdx.x & 7;        // same-bh blocks share an XCD L2
  const int slice = blockIdx.x >> 3;    // 0..15
  const int b = bh >> 2, h = bh & 3;
  const int chb = bh * 64;

  for (int i = l; i < 16 * 264 / 2; i += 64) ((unsigned*)s_S)[i] = 0u;
  f32x4 S[16];
#pragma unroll
  for (int dt = 0; dt < 16; ++dt) S[dt] = (f32x4){0.f, 0.f, 0.f, 0.f};

  auto stage = [&](int ck, int bf) {
    const char* gw = (const char*)wbp  + (size_t)ck * 16384;
    const char* gq = (const char*)qb   + (size_t)ck * 16384;
    const char* gk = (const char*)knTp + (size_t)ck * 16384;
    const char* gu = (const char*)u + (size_t)ck * 32768 + slice * 2048;
    const char* ga = (const char*)attnb + (size_t)ck * 2048;
    char* dw = (char*)&s_w[bf][0];
    char* dq = (char*)&s_q[bf][0];
    char* dk = (char*)&s_kT[bf][0];
    char* du = (char*)&s_u[bf][0];
    char* da = (char*)&s_at[bf][0];
#pragma unroll
    for (int i = 0; i < 16; ++i) GLD16(gw + i * 1024 + l * 16, dw + i * 1024);
#pragma unroll
    for (int i = 0; i < 16; ++i) GLD16(gq + i * 1024 + l * 16, dq + i * 1024);
#pragma unroll
    for (int i = 0; i < 16; ++i) GLD16(gk + i * 1024 + l * 16, dk + i * 1024);
#pragma unroll
    for (int i = 0; i < 2; ++i)  GLD16(gu + i * 1024 + l * 16, du + i * 1024);
#pragma unroll
    for (int i = 0; i < 2; ++i)  GLD16(ga + i * 1024 + l * 16, da + i * 1024);
  };

  stage(chb, 0);
  asm volatile("s_waitcnt vmcnt(0)" ::: "memory");
  __builtin_amdgcn_sched_barrier(0);

#pragma clang loop unroll(disable)
  for (int t = 0; t < 64; ++t) {
    const int bc = t & 1;
    asm volatile("s_waitcnt vmcnt(0)" ::: "memory");
    __builtin_amdgcn_sched_barrier(0);
    if (t < 63) stage(chb + t + 1, bc ^ 1);

    // ---- phase 1: tmp = u + (-W)@S ; O1 = Q@S  (K = 256)
    const char* pw = (const char*)&s_w[bc][0];
    const char* pq = (const char*)&s_q[bc][0];
    f32x4 t0 = *(const f32x4*)(&s_u[bc][0] + l * 4);
    f32x4 t1 = *(const f32x4*)(&s_u[bc][0] + 256 + l * 4);
    bf16x8 atA0 = *(const bf16x8*)((const char*)&s_at[bc][0] + l * 16);
    bf16x8 atA1 = *(const bf16x8*)((const char*)&s_at[bc][0] + 1024 + l * 16);
    f32x4 o0 = (f32x4){0.f, 0.f, 0.f, 0.f};
    f32x4 o1 = (f32x4){0.f, 0.f, 0.f, 0.f};
#pragma unroll
    for (int kb = 0; kb < 8; ++kb) {
      const int sw = (kb * 64 + lg * 16) ^ (lr << 4);
      bf16x8 sB  = *(const bf16x8*)((const char*)s_S + lr * 528 + kb * 64 + lg * 16);
      bf16x8 aw0 = *(const bf16x8*)(pw + lr * 512 + sw);
      bf16x8 aw1 = *(const bf16x8*)(pw + (16 + lr) * 512 + sw);
      bf16x8 aq0 = *(const bf16x8*)(pq + lr * 512 + sw);
      bf16x8 aq1 = *(const bf16x8*)(pq + (16 + lr) * 512 + sw);
      t0 = MFMA16(aw0, sB, t0);
      t1 = MFMA16(aw1, sB, t1);
      o0 = MFMA16(aq0, sB, o0);
      o1 = MFMA16(aq1, sB, o1);
    }
    *(unsigned*)((char*)s_tT + lr * 80 + lg * 8)          = pack2(t0[0], t0[1]);
    *(unsigned*)((char*)s_tT + lr * 80 + lg * 8 + 4)      = pack2(t0[2], t0[3]);
    *(unsigned*)((char*)s_tT + lr * 80 + 32 + lg * 8)     = pack2(t1[0], t1[1]);
    *(unsigned*)((char*)s_tT + lr * 80 + 32 + lg * 8 + 4) = pack2(t1[2], t1[3]);

    // ---- phase 2: O = O1 + attn @ tmp ; store delta
    bf16x8 tB = *(const bf16x8*)((const char*)s_tT + lr * 80 + lg * 16);
    o0 = MFMA16(atA0, tB, o0);
    o1 = MFMA16(atA1, tB, o1);
    {
      size_t col = h * 256 + slice * 16 + lr;
#pragma unroll
      for (int j = 0; j < 4; ++j) {
        int r0 = t * 32 + lg * 4 + j;
        delta[((size_t)(b * 2048 + r0)) * 1024 + col] = o0[j];
        delta[((size_t)(b * 2048 + r0 + 16)) * 1024 + col] = o1[j];
      }
    }

    // ---- phase 3: S += K^T @ tmp ; refresh bf16 shadow
    const char* pk = (const char*)&s_kT[bc][0];
#pragma unroll
    for (int dt = 0; dt < 16; ++dt) {
      bf16x8 aK = *(const bf16x8*)(pk + (dt * 16 + lr) * 64 + lg * 16);
      S[dt] = MFMA16(aK, tB, S[dt]);
    }
#pragma unroll
    for (int dt = 0; dt < 16; ++dt) {
      *(unsigned*)((char*)s_S + lr * 528 + dt * 32 + lg * 8)     = pack2(S[dt][0], S[dt][1]);
      *(unsigned*)((char*)s_S + lr * 528 + dt * 32 + lg * 8 + 4) = pack2(S[dt][2], S[dt][3]);
    }
  }
}

// ------------------- K5: FIR short(3)/long(63), taps in registers, v in LDS
__global__ __launch_bounds__(256)
void k5_fir(const float* __restrict__ vpath, const float* __restrict__ wsrt,
            const float* __restrict__ wlng, float* __restrict__ shortp,
            float* __restrict__ longp) {
  __shared__ float s_v[126][128];
  const int c0 = blockIdx.x * 128;
  const int l0 = blockIdx.y * 64;
  const int b  = blockIdx.z;
  const int t  = threadIdx.x;

  for (int i = 0; i < 63; ++i) {
    int idx = t + i * 256;
    int rr = idx >> 7, cc2 = idx & 127;
    int gl = l0 - 62 + rr;
    s_v[rr][cc2] = (gl >= 0)
        ? vpath[((size_t)(b * 2048 + gl)) * 1024 + c0 + cc2] : 0.f;
  }

  const int cc = t & 127, lh = t >> 7;
  float wl[63];
#pragma unroll
  for (int j = 0; j < 63; ++j)
    wl[j] = wlng[(size_t)(c0 + cc) * 63 + j];
  float ws0 = wsrt[(size_t)(c0 + cc) * 3 + 0];
  float ws1 = wsrt[(size_t)(c0 + cc) * 3 + 1];
  float ws2 = wsrt[(size_t)(c0 + cc) * 3 + 2];
  __syncthreads();

  for (int m = 0; m < 32; ++m) {
    int ll = lh * 32 + m;
    float accL = 0.f;
#pragma unroll
    for (int j = 0; j < 63; ++j)
      accL = fmaf(s_v[ll + j][cc], wl[j], accL);
    float accS = s_v[ll + 60][cc] * ws0;
    accS = fmaf(s_v[ll + 61][cc], ws1, accS);
    accS = fmaf(s_v[ll + 62][cc], ws2, accS);
    size_t o = ((size_t)(b * 2048 + l0 + ll)) * 1024 + c0 + cc;
    longp[o] = accL;
    shortp[o] = accS;
  }
}

// --------------------- K6: path stats + gate_in build (bf16, padded to 1088)
__global__ __launch_bounds__(256)
void k6_gatein(const float* __restrict__ hs, const float* __restrict__ shortp,
               const float* __restrict__ longp, const float* __restrict__ delta,
               const float* __restrict__ vpath, bf16* __restrict__ gate_in) {
  const size_t row = blockIdx.x;
  const int t = threadIdx.x, wv = t >> 6, lane = t & 63;
  bf16* gr = gate_in + row * 1088;
#pragma unroll
  for (int i = 0; i < 2; ++i) {
    int c2 = (t + i * 256) * 2;
    float a = hs[row * 1024 + c2];
    float b = hs[row * 1024 + c2 + 1];
    *(unsigned*)(gr + c2) = pack2(a, b);
  }
  if (t < 16) *(unsigned*)(gr + 1056 + t * 2) = 0u;
  const float* paths[4] = {shortp, longp, delta, vpath};
#pragma unroll
  for (int p = 0; p < 4; ++p) {
    float s = 0.f, sq = 0.f;
#pragma unroll
    for (int i = 0; i < 4; ++i) {
      int c = wv * 256 + lane + i * 64;
      float x = paths[p][row * 1024 + c];
      s += x; sq += x * x;
    }
#pragma unroll
    for (int off = 32; off; off >>= 1) {
      s += __shfl_xor(s, off);
      sq += __shfl_xor(sq, off);
    }
    if (lane == 0) {
      float mean = s * (1.f / 256.f);
      float var = sq * (1.f / 256.f) - mean * mean;
      *(unsigned*)(gr + 1024 + p * 8 + wv * 2) = pack2(mean, var);
    }
  }
}

// ------------------------------- K8: logits GEMV + softmax + floor + renorm
__global__ __launch_bounds__(256)
void k8_probs(const float* __restrict__ hmid, const float* __restrict__ w2,
              const float* __restrict__ bias, const float* __restrict__ log_temp,
              const float* __restrict__ floor_raw, float* __restrict__ probs) {
  const int t = threadIdx.x, wv = t >> 6, lane = t & 63;
  const size_t row = (size_t)blockIdx.x * 4 + wv;
  float acc[16];
#pragma unroll
  for (int o = 0; o < 16; ++o) acc[o] = 0.f;
  for (int it = 0; it < 32; ++it) {
    int c = lane + it * 64;
    float x = hmid[row * 2048 + c];
#pragma unroll
    for (int o = 0; o < 16; ++o)
      acc[o] = fmaf(x, w2[o * 2048 + c], acc[o]);
  }
#pragma unroll
  for (int off = 32; off; off >>= 1)
#pragma unroll
    for (int o = 0; o < 16; ++o) acc[o] += __shfl_xor(acc[o], off);

  if (lane == 0) {
    for (int h2 = 0; h2 < 4; ++h2) {
      float temp = log1pf(expf(log_temp[h2])) + 1e-4f;
      float li[4], m = -1e30f;
#pragma unroll
      for (int p = 0; p < 4; ++p) {
        li[p] = (acc[h2 * 4 + p] + bias[h2 * 4 + p]) / temp;
        m = fmaxf(m, li[p]);
      }
      float sum = 0.f;
#pragma unroll
      for (int p = 0; p < 4; ++p) { li[p] = expf(li[p] - m); sum += li[p]; }
      float pr[4], s2 = 0.f;
#pragma unroll
      for (int p = 0; p < 4; ++p) {
        float fv = 0.05f / (1.f + expf(-floor_raw[h2 * 4 + p]));
        pr[p] = fmaxf(li[p] / sum, fv);
        s2 += pr[p];
      }
#pragma unroll
      for (int p = 0; p < 4; ++p)
        probs[row * 16 + h2 * 4 + p] = pr[p] / s2;
    }
  }
}

// ------------------------------- K9: mix paths + RMS-norm (bf16 out for GEMM)
__global__ __launch_bounds__(256)
void k9_mix(const float* __restrict__ shortp, const float* __restrict__ longp,
            const float* __restrict__ delta, const float* __restrict__ vpath,
            const float* __restrict__ probs, const float* __restrict__ onorm,
            bf16* __restrict__ mixed) {
  const size_t row = blockIdx.x;
  const int t = threadIdx.x, wv = t >> 6, lane = t & 63;
  float p0 = probs[row * 16 + wv * 4 + 0];
  float p1 = probs[row * 16 + wv * 4 + 1];
  float p2 = probs[row * 16 + wv * 4 + 2];
  float p3 = probs[row * 16 + wv * 4 + 3];
  float m[4];
  float sq = 0.f;
#pragma unroll
  for (int i = 0; i < 4; ++i) {
    int c = wv * 256 + lane + i * 64;
    size_t o = row * 1024 + c;
    float x = p0 * shortp[o] + p1 * longp[o] + p2 * delta[o] + p3 * vpath[o];
    m[i] = x;
    sq += x * x;
  }
#pragma unroll
  for (int off = 32; off; off >>= 1) sq += __shfl_xor(sq, off);
  float sc = rsqrtf(sq * (1.f / 256.f) + 1e-5f);
#pragma unroll
  for (int i = 0; i < 4; ++i) {
    int d = lane + i * 64;
    mixed[row * 1024 + wv * 256 + d] = (bf16)(m[i] * sc * onorm[d]);
  }
}

// ---------------------------------------------------------------- launcher
extern "C" void kernel_launch(void* const* d_in, const int* in_sizes, int n_in,
                              void* d_out, int out_size, void* d_ws,
                              size_t ws_size, hipStream_t stream) {
  const float* hs   = (const float*)d_in[0];
  const float* Wq   = (const float*)d_in[1];
  const float* Wk   = (const float*)d_in[2];
  const float* Wv   = (const float*)d_in[3];
  const float* Wb   = (const float*)d_in[4];
  const float* qw   = (const float*)d_in[5];
  const float* kw   = (const float*)d_in[6];
  const float* vw   = (const float*)d_in[7];
  const float* fsw  = (const float*)d_in[8];
  const float* flw  = (const float*)d_in[9];
  const float* gw1  = (const float*)d_in[10];
  const float* gb1  = (const float*)d_in[11];
  const float* gw2  = (const float*)d_in[12];
  const float* ltmp = (const float*)d_in[13];
  const float* bbias= (const float*)d_in[14];
  const float* frw  = (const float*)d_in[15];
  const float* onw  = (const float*)d_in[16];
  const float* Wo   = (const float*)d_in[17];
  float* out = (float*)d_out;

  float* f = (float*)d_ws;
  const size_t BLD = 4194304;  // B*L*D
  float* qkv     = f + 0 * BLD;                 // [4096][3072] fused
  float* qn      = f + 3 * BLD;
  float* kn      = f + 4 * BLD;
  float* vpath   = f + 5 * BLD;
  float* shortp  = f + 6 * BLD;
  float* longp   = f + 7 * BLD;
  float* gate_f  = f + 8 * BLD;
  float* probs   = gate_f + 4325376;
  float* beta    = probs + 65536;

  bf16* hsb  = (bf16*)gate_f;
  bf16* ginb = (bf16*)gate_f;
  bf16* gw1b = (bf16*)gate_f + 4456448;
  bf16* wob  = (bf16*)gate_f + 4456448 + 2228224;
  bf16* wqb  = (bf16*)kn;                       // wq/wk/wv contiguous here
  bf16* wkb  = wqb + 1048576;
  bf16* wvb  = wkb + 1048576;

  float* u_f32 = f + 0 * BLD;                   // over dead qkv (q third)
  bf16*  qbb   = (bf16*)shortp;
  bf16*  wbb   = qbb + 512 * 8192;
  bf16*  knTb  = (bf16*)longp;                  // 512*8192 bf16
  bf16*  attnb = knTb + 512 * 8192;
  float* delta = f + 2 * BLD;                   // over dead qkv (v third)
  float* hmid  = qn;
  bf16*  mixb  = (bf16*)(f + 1 * BLD);          // over dead qkv (k third)

  kcvt<<<2048, 256, 0, stream>>>(hs, hsb, 4194304);
  kcvt4<<<2048, 256, 0, stream>>>(Wq, Wk, Wv, Wo, wqb, wkb, wvb, wob);
  kcvt_pad<<<2048, 256, 0, stream>>>(gw1, gw1b, 1056, 1088);

  // fused QKV projection: C[4096][3072]
  gemm_bf16<0><<<dim3(24, 32), 256, 0, stream>>>(hsb, wqb, nullptr, qkv, 4096, 3072, 1024);

  k2_conv<<<4096, 256, 0, stream>>>(hs, qkv, qw, kw, vw, Wb,
                                    qn, kn, vpath, beta);
  k3_chunk<<<512, 256, 0, stream>>>(qn, kn, vpath, beta, u_f32, qbb, wbb,
                                    knTb, attnb);
  k4_scan_mfma<<<128, 64, 0, stream>>>(qbb, wbb, knTb, attnb, u_f32, delta);
  k5_fir<<<dim3(8, 32, 2), 256, 0, stream>>>(vpath, fsw, flw, shortp, longp);
  k6_gatein<<<4096, 256, 0, stream>>>(hs, shortp, longp, delta, vpath, ginb);
  gemm_bf16<1><<<dim3(16, 32), 256, 0, stream>>>(ginb, gw1b, gb1, hmid, 4096, 2048, 1088);
  k8_probs<<<1024, 256, 0, stream>>>(hmid, gw2, bbias, ltmp, frw, probs);
  k9_mix<<<4096, 256, 0, stream>>>(shortp, longp, delta, vpath, probs, onw, mixb);
  gemm_bf16<0><<<dim3(8, 32), 256, 0, stream>>>(mixb, wob, nullptr, out, 4096, 1024, 1024);
}